// Round 4
// baseline (1150.627 us; speedup 1.0000x reference)
//
#include <hip/hip_runtime.h>
#include <hip/hip_bf16.h>

// Problem dims (fixed)
#define Nn   512
#define NN   262144        // N*N positions
#define EDG  16384

typedef unsigned short u16;
typedef short v8s __attribute__((ext_vector_type(8)));   // 8 bf16 lanes (4 VGPR)
typedef float v4f __attribute__((ext_vector_type(4)));

__device__ __forceinline__ float b2f(u16 u) {
    union { unsigned int i; float f; } v; v.i = ((unsigned int)u) << 16; return v.f;
}
__device__ __forceinline__ u16 f2b(float f) {
    union { float f; unsigned int i; } v; v.f = f;
    unsigned int r = (v.i + 0x7FFFu + ((v.i >> 16) & 1u)) >> 16;
    return (u16)r;
}

// ---------------------------------------------------------------------------
// Sentinel: diagnostic constant output (host-side guard fired)
__global__ void sentinel_kernel(float* __restrict__ out, float val) {
    if (threadIdx.x < 10) out[threadIdx.x] = val;
}

// ---------------------------------------------------------------------------
// K0: convert the 6 conv weight tensors (fp32) into one bf16 arena.
// Segments: [0,2048) c0m1, [2048,4096) c0m2, [4096,10240) c0m4,
//           [10240,18432) cm1, [18432,26624) cm2, [26624,43008) cm4.
__global__ void cvt_weights(const float* __restrict__ s0, const float* __restrict__ s1,
                            const float* __restrict__ s2, const float* __restrict__ s3,
                            const float* __restrict__ s4, const float* __restrict__ s5,
                            u16* __restrict__ dst) {
    int t = blockIdx.x * 256 + threadIdx.x;
    if (t >= 43008) return;
    float v;
    if      (t < 2048)  v = s0[t];
    else if (t < 4096)  v = s1[t - 2048];
    else if (t < 10240) v = s2[t - 4096];
    else if (t < 18432) v = s3[t - 10240];
    else if (t < 26624) v = s4[t - 18432];
    else                v = s5[t - 26624];
    dst[t] = f2b(v);
}

// ---------------------------------------------------------------------------
// K1: scatter edges into A (fp32, pos-major [p][32]); x is fp32 [512][16]
__global__ void scatter_edges(const float* __restrict__ x, const int* __restrict__ ei,
                              float* __restrict__ A) {
    int t = blockIdx.x * 256 + threadIdx.x;
    if (t >= EDG * 32) return;
    int e = t >> 5, c = t & 31;
    int s = ei[e], d = ei[EDG + e];
    float v = (c < 16) ? x[s * 16 + c] : x[d * 16 + (c - 16)];
    atomicAdd(A + ((size_t)s * Nn + d) * 32 + c, v);
}

// ---------------------------------------------------------------------------
// K2: A fp32 -> u0 bf16 pos-major [p][32]; per-channel totals
__global__ __launch_bounds__(256) void finalize_u0(const float* __restrict__ A,
                                                   u16* __restrict__ u0,
                                                   float* __restrict__ total) {
    int t = threadIdx.x;
    int p = blockIdx.x * 256 + t;
    const float* Ar = A + (size_t)p * 32;
    float v[32];
#pragma unroll
    for (int c = 0; c < 32; ++c) v[c] = Ar[c];
#pragma unroll
    for (int c4 = 0; c4 < 8; ++c4) {
        ushort4 o = { f2b(v[c4*4]), f2b(v[c4*4+1]), f2b(v[c4*4+2]), f2b(v[c4*4+3]) };
        *(ushort4*)(u0 + (size_t)p * 32 + c4 * 4) = o;
    }
    __shared__ float red[4][32];
    int wv = t >> 6;
#pragma unroll
    for (int c = 0; c < 32; ++c) {
        float r = v[c];
        for (int off = 32; off > 0; off >>= 1) r += __shfl_down(r, off);
        if ((t & 63) == 0) red[wv][c] = r;
    }
    __syncthreads();
    if (t < 32) atomicAdd(total + t, red[0][t] + red[1][t] + red[2][t] + red[3][t]);
}

// ---------------------------------------------------------------------------
// K3: trace[c] = sum_i u[i*513][c]  (u pos-major [p][C]); trace must be pre-zeroed
__global__ void trace_kernel(const u16* __restrict__ u, int C, float* __restrict__ trace) {
    __shared__ float red[64];
    int t = threadIdx.x;
    if (t < 64) red[t] = 0.f;
    __syncthreads();
    int tpr = C >> 2;               // threads per row (4 channels each)
    int g = t / tpr;
    int ng = 256 / tpr;
    int c4 = (t % tpr) * 4;
    float s0 = 0.f, s1 = 0.f, s2 = 0.f, s3 = 0.f;
    for (int i = blockIdx.x * 64 + g; i < blockIdx.x * 64 + 64; i += ng) {
        ushort4 w = *(const ushort4*)(u + (size_t)i * 513 * C + c4);
        s0 += b2f(w.x); s1 += b2f(w.y); s2 += b2f(w.z); s3 += b2f(w.w);
    }
    atomicAdd(&red[c4 + 0], s0); atomicAdd(&red[c4 + 1], s1);
    atomicAdd(&red[c4 + 2], s2); atomicAdd(&red[c4 + 3], s3);
    __syncthreads();
    if (t < C) atomicAdd(trace + t, red[t]);
}

// ---------------------------------------------------------------------------
// K4: extractor MLP (fp32 weights), accumulate into out_acc[64]. 1 block, 64 threads.
__global__ void extractor_acc(const float* __restrict__ trace, const float* __restrict__ total,
                              int C, const float* __restrict__ w1, const float* __restrict__ b1,
                              const float* __restrict__ w2, const float* __restrict__ w3,
                              float* __restrict__ out_acc) {
    __shared__ float xo[64];
    int t = threadIdx.x;
    const float inv_n = 1.f / 512.f;
    const float inv_off = 1.f / (512.f * 511.f);
    float s1 = b1[t];
    for (int c = 0; c < C; ++c) s1 += (trace[c] * inv_n) * w1[t * C + c];
    float s2 = 0.f;
    for (int c = 0; c < C; ++c) s2 += ((total[c] - trace[c]) * inv_off) * w2[t * C + c];
    float o = s1 + s2;
    xo[t] = o;
    __syncthreads();
    float s3 = 0.f;
    for (int f = 0; f < 64; ++f) s3 += fmaxf(xo[f], 0.f) * w3[t * 64 + f];
    out_acc[t] += o + s3;
}

// ---------------------------------------------------------------------------
// K5: 1x1 conv via MFMA.  dst[h][p] = sum_c src[pr(p)][c]*w[h][c] + bias[h]
// src pos-major bf16 (K-innermost B operand), w bf16 row-major [64][K] (A operand),
// bias fp32. tr0 != 0: read src0 at transposed grid position (j,i).
// Supports concat of two sources (m4): K = c0 + c1, all multiples of 32.
__global__ __launch_bounds__(256) void conv_mfma(const u16* __restrict__ src0, int c0,
                                                 const u16* __restrict__ src1, int c1,
                                                 const u16* __restrict__ w,
                                                 const float* __restrict__ bias,
                                                 u16* __restrict__ dst, int tr0) {
    const int K = c0 + c1;
    const int nkk = K >> 5;
    const int lane = threadIdx.x & 63;
    const int wave = threadIdx.x >> 6;
    const int l15 = lane & 15, quad = lane >> 4;
    const int pbase = blockIdx.x * 256 + wave * 64;

    v8s af[4][4];
    for (int kk = 0; kk < nkk; ++kk)
#pragma unroll
        for (int mt = 0; mt < 4; ++mt)
            af[mt][kk] = *reinterpret_cast<const v8s*>(w + (mt * 16 + l15) * K + kk * 32 + quad * 8);

    v4f acc[4][4];
#pragma unroll
    for (int mt = 0; mt < 4; ++mt)
#pragma unroll
        for (int nt = 0; nt < 4; ++nt) acc[mt][nt] = (v4f){0.f, 0.f, 0.f, 0.f};

#pragma unroll
    for (int nt = 0; nt < 4; ++nt) {
        const int p = pbase + nt * 16 + l15;
        const int pr = tr0 ? (((p & 511) << 9) | (p >> 9)) : p;
        for (int kk = 0; kk < nkk; ++kk) {
            const int cg = kk * 32 + quad * 8;
            const u16* sp = (cg < c0) ? (src0 + (size_t)pr * c0 + cg)
                                      : (src1 + (size_t)pr * c1 + (cg - c0));
            v8s b = *reinterpret_cast<const v8s*>(sp);
#pragma unroll
            for (int mt = 0; mt < 4; ++mt)
                acc[mt][nt] = __builtin_amdgcn_mfma_f32_16x16x32_bf16(af[mt][kk], b, acc[mt][nt], 0, 0, 0);
        }
    }
#pragma unroll
    for (int mt = 0; mt < 4; ++mt)
#pragma unroll
        for (int r = 0; r < 4; ++r) {
            const int h = mt * 16 + quad * 4 + r;
            const float bv = bias[h];
#pragma unroll
            for (int nt = 0; nt < 4; ++nt) {
                const int p = pbase + nt * 16 + l15;
                dst[(size_t)h * NN + p] = f2b(acc[mt][nt][r] + bv);
            }
        }
}

// ---------------------------------------------------------------------------
// K7: batched per-channel GEMM: mult[h] = o1[h] (512x512, [i][k]) * o2t[h]^T ([j][k])
__global__ __launch_bounds__(256) void bmm_mfma(const u16* __restrict__ Aall,
                                                const u16* __restrict__ Ball,
                                                u16* __restrict__ Call) {
    const int h = blockIdx.y;
    const int tx = blockIdx.x & 3, ty = blockIdx.x >> 2;
    const int lane = threadIdx.x & 63;
    const int wave = threadIdx.x >> 6;
    const int wr = wave >> 1, wc = wave & 1;
    const int l15 = lane & 15, quad = lane >> 4;
    const int ibase = ty * 128 + wr * 64, jbase = tx * 128 + wc * 64;
    const u16* Ap = Aall + (size_t)h * NN;
    const u16* Bp = Ball + (size_t)h * NN;
    const u16* ar[4]; const u16* br[4];
#pragma unroll
    for (int mt = 0; mt < 4; ++mt) ar[mt] = Ap + (ibase + mt * 16 + l15) * 512 + quad * 8;
#pragma unroll
    for (int nt = 0; nt < 4; ++nt) br[nt] = Bp + (jbase + nt * 16 + l15) * 512 + quad * 8;

    v4f acc[4][4];
#pragma unroll
    for (int mt = 0; mt < 4; ++mt)
#pragma unroll
        for (int nt = 0; nt < 4; ++nt) acc[mt][nt] = (v4f){0.f, 0.f, 0.f, 0.f};

    for (int kk = 0; kk < 16; ++kk) {
        v8s a[4], b[4];
#pragma unroll
        for (int mt = 0; mt < 4; ++mt) a[mt] = *reinterpret_cast<const v8s*>(ar[mt] + kk * 32);
#pragma unroll
        for (int nt = 0; nt < 4; ++nt) b[nt] = *reinterpret_cast<const v8s*>(br[nt] + kk * 32);
#pragma unroll
        for (int mt = 0; mt < 4; ++mt)
#pragma unroll
            for (int nt = 0; nt < 4; ++nt)
                acc[mt][nt] = __builtin_amdgcn_mfma_f32_16x16x32_bf16(a[mt], b[nt], acc[mt][nt], 0, 0, 0);
    }
    u16* Cp = Call + (size_t)h * NN;
#pragma unroll
    for (int mt = 0; mt < 4; ++mt)
#pragma unroll
        for (int r = 0; r < 4; ++r) {
            const int i = ibase + mt * 16 + quad * 4 + r;
#pragma unroll
            for (int nt = 0; nt < 4; ++nt) {
                const int j = jbase + nt * 16 + l15;
                Cp[i * 512 + j] = f2b(acc[mt][nt][r]);
            }
        }
}

// ---------------------------------------------------------------------------
// K8: channel-major [64][NN] -> pos-major [NN][64] transpose (64p x 64h tiles)
__global__ __launch_bounds__(256) void cm_to_pm(const u16* __restrict__ src, u16* __restrict__ dst) {
    __shared__ u16 tile[64][65];
    int t = threadIdx.x;
    int p0 = blockIdx.x * 64;
    int pl = t & 63, hg = t >> 6;
    for (int r = 0; r < 16; ++r) {
        int h = hg * 16 + r;
        tile[h][pl] = src[(size_t)h * NN + p0 + pl];
    }
    __syncthreads();
#pragma unroll
    for (int pass = 0; pass < 4; ++pass) {
        int pl2 = (t >> 4) + pass * 16;
        int h4 = (t & 15) * 4;
        ushort4 v = { tile[h4][pl2], tile[h4+1][pl2], tile[h4+2][pl2], tile[h4+3][pl2] };
        *(ushort4*)(dst + (size_t)(p0 + pl2) * 64 + h4) = v;
    }
}

// ---------------------------------------------------------------------------
// K9: per-channel sum / sumsq over channel-major rows
__global__ __launch_bounds__(256) void row_stats(const u16* __restrict__ src,
                                                 float* __restrict__ sum, float* __restrict__ sq) {
    int c = blockIdx.y, t = threadIdx.x;
    size_t base = (size_t)c * NN + (size_t)blockIdx.x * 32768;
    float s = 0.f, s2 = 0.f;
    for (int i = 0; i < 32; ++i) {
        ushort4 w = *(const ushort4*)(src + base + (size_t)i * 1024 + t * 4);
        float a0 = b2f(w.x), a1 = b2f(w.y), a2 = b2f(w.z), a3 = b2f(w.w);
        s += a0 + a1 + a2 + a3;
        s2 += a0 * a0 + a1 * a1 + a2 * a2 + a3 * a3;
    }
    for (int off = 32; off > 0; off >>= 1) { s += __shfl_down(s, off); s2 += __shfl_down(s2, off); }
    __shared__ float r1[4], r2[4];
    if ((t & 63) == 0) { r1[t >> 6] = s; r2[t >> 6] = s2; }
    __syncthreads();
    if (t == 0) {
        atomicAdd(sum + c, r1[0] + r1[1] + r1[2] + r1[3]);
        atomicAdd(sq + c, r2[0] + r2[1] + r2[2] + r2[3]);
    }
}

// ---------------------------------------------------------------------------
// K11: BN scale/shift from stats (fp32 gamma/beta); zero total & trace for next stage
__global__ void bn_finalize(const float* __restrict__ sum, const float* __restrict__ sq,
                            const float* __restrict__ g, const float* __restrict__ b,
                            float* __restrict__ scale, float* __restrict__ shift,
                            float* __restrict__ total, float* __restrict__ trace) {
    int t = threadIdx.x;   // 64
    float mean = sum[t] * (1.f / 262144.f);
    float var = sq[t] * (1.f / 262144.f) - mean * mean;
    float sc = g[t] * rsqrtf(fmaxf(var, 0.f) + 1e-5f);
    scale[t] = sc;
    shift[t] = b[t] - mean * sc;
    total[t] = 0.f;
    trace[t] = 0.f;
}

// ---------------------------------------------------------------------------
// K10: normalize u_raw (cm) -> u (pos-major); per-channel totals
__global__ __launch_bounds__(256) void norm_tr(const u16* __restrict__ raw,
                                               const float* __restrict__ scale,
                                               const float* __restrict__ shift,
                                               u16* __restrict__ u,
                                               float* __restrict__ total) {
    __shared__ u16 tile[64][65];
    __shared__ float red[64][4];
    int t = threadIdx.x;
    int p0 = blockIdx.x * 64;
    int pl = t & 63, hg = t >> 6;
    for (int r = 0; r < 16; ++r) {
        int h = hg * 16 + r;
        float v = b2f(raw[(size_t)h * NN + p0 + pl]) * scale[h] + shift[h];
        tile[h][pl] = f2b(v);
    }
    __syncthreads();
    {
        int h = t >> 2, q = t & 3;
        float s = 0.f;
        for (int i = 0; i < 16; ++i) s += b2f(tile[h][q * 16 + i]);
        red[h][q] = s;
    }
    __syncthreads();
    if (t < 64) atomicAdd(total + t, red[t][0] + red[t][1] + red[t][2] + red[t][3]);
#pragma unroll
    for (int pass = 0; pass < 4; ++pass) {
        int pl2 = (t >> 4) + pass * 16;
        int h4 = (t & 15) * 4;
        ushort4 v = { tile[h4][pl2], tile[h4+1][pl2], tile[h4+2][pl2], tile[h4+3][pl2] };
        *(ushort4*)(u + (size_t)(p0 + pl2) * 64 + h4) = v;
    }
}

// ---------------------------------------------------------------------------
// K12: head (fp32 weights/out): relu/3, after_conv residual, final linear, log_softmax
__global__ void head(const float* __restrict__ out_acc, const float* __restrict__ acw,
                     const float* __restrict__ acb, const float* __restrict__ flw,
                     const float* __restrict__ flb, float* __restrict__ out) {
    __shared__ float x[64], x2[64], l[10];
    int t = threadIdx.x;  // 64
    x[t] = fmaxf(out_acc[t], 0.f) * (1.f / 3.f);
    __syncthreads();
    float y = acb[t];
    for (int f = 0; f < 64; ++f) y += x[f] * acw[t * 64 + f];
    x2[t] = x[t] + fmaxf(y, 0.f);
    __syncthreads();
    if (t < 10) {
        float s = flb[t];
        for (int f = 0; f < 64; ++f) s += x2[f] * flw[t * 64 + f];
        l[t] = s;
    }
    __syncthreads();
    if (t == 0) {
        float m = l[0];
        for (int i = 1; i < 10; ++i) m = fmaxf(m, l[i]);
        float se = 0.f;
        for (int i = 0; i < 10; ++i) se += expf(l[i] - m);
        float ls = m + logf(se);
        for (int i = 0; i < 10; ++i) out[i] = l[i] - ls;
    }
}

// ---------------------------------------------------------------------------
extern "C" void kernel_launch(void* const* d_in, const int* in_sizes, int n_in,
                              void* d_out, int out_size, void* d_ws, size_t ws_size,
                              hipStream_t stream) {
    float* out = (float*)d_out;

    // --- Guard 1: input signature must match the reference exactly ---
    static const int exp_sizes[28] = {
        8192, 32768,                 // x, edge_index
        2048, 64, 2048, 4096,        // np1_w, np1_b, np2_w, np3_w
        2048, 64, 2048, 64, 6144, 64,// c0_m1_w..c0_m4_b
        8192, 128, 8192, 128, 16384, 128, // cm1..cm4
        192, 192,                    // bn_g, bn_b
        12288, 192, 12288, 12288,    // fe1_w, fe1_b, fe2_w, fe3_w
        4096, 64, 640, 10            // ac_w, ac_b, fl_w, fl_b
    };
    bool ok = (n_in == 28);
    if (ok) for (int i = 0; i < 28; ++i) if (in_sizes[i] != exp_sizes[i]) ok = false;
    if (!ok) { sentinel_kernel<<<1, 64, 0, stream>>>(out, -5.0f); return; }

    // --- Guard 2: workspace: 4 KB control + 88 KB weight arena + 4 regions ---
    const size_t RSZ = (size_t)NN * 64 * 2;            // 33.55 MB per region
    const size_t BIG_OFF = 4096 + 90112;               // control + arena (43008*2 rounded)
    if (ws_size < BIG_OFF + 4 * RSZ) {
        sentinel_kernel<<<1, 64, 0, stream>>>(out, -7.0f);
        return;
    }

    const float* x     = (const float*)d_in[0];
    const int*   ei    = (const int*)d_in[1];
    const float* np1w  = (const float*)d_in[2];
    const float* np1b  = (const float*)d_in[3];
    const float* np2w  = (const float*)d_in[4];
    const float* np3w  = (const float*)d_in[5];
    const float* c0m1w = (const float*)d_in[6];
    const float* c0m1b = (const float*)d_in[7];
    const float* c0m2w = (const float*)d_in[8];
    const float* c0m2b = (const float*)d_in[9];
    const float* c0m4w = (const float*)d_in[10];
    const float* c0m4b = (const float*)d_in[11];
    const float* cm1w  = (const float*)d_in[12];
    const float* cm1b  = (const float*)d_in[13];
    const float* cm2w  = (const float*)d_in[14];
    const float* cm2b  = (const float*)d_in[15];
    const float* cm4w  = (const float*)d_in[16];
    const float* cm4b  = (const float*)d_in[17];
    const float* bng   = (const float*)d_in[18];
    const float* bnb   = (const float*)d_in[19];
    const float* fe1w  = (const float*)d_in[20];
    const float* fe1b  = (const float*)d_in[21];
    const float* fe2w  = (const float*)d_in[22];
    const float* fe3w  = (const float*)d_in[23];
    const float* acw   = (const float*)d_in[24];
    const float* acb   = (const float*)d_in[25];
    const float* flw   = (const float*)d_in[26];
    const float* flb   = (const float*)d_in[27];

    char* ws = (char*)d_ws;
    float* small = (float*)ws;
    float* ssum  = small;
    float* ssq   = small + 64;
    float* scl   = small + 128;
    float* shf   = small + 192;
    float* trace = small + 256;
    float* total = small + 320;
    float* oacc  = small + 384;

    u16* arena = (u16*)(ws + 4096);          // bf16 conv weights, 43008 elements

    char* big = ws + BIG_OFF;
    u16*   u      = (u16*)(big + 0 * RSZ);   // R1: u pos-major (layer state)
    u16*   o1     = (u16*)(big + 1 * RSZ);   // R2: o1 cm -> later multpm
    u16*   multpm = (u16*)(big + 1 * RSZ);
    u16*   o2t    = (u16*)(big + 2 * RSZ);   // R3: o2t cm -> later uraw
    u16*   uraw   = (u16*)(big + 2 * RSZ);
    float* Abuf   = (float*)(big + 3 * RSZ); // R4: A fp32 staging -> later multcm
    u16*   multcm = (u16*)(big + 3 * RSZ);

    hipMemsetAsync(small, 0, 448 * 4, stream);
    hipMemsetAsync(Abuf, 0, (size_t)NN * 32 * 4, stream);

    cvt_weights<<<168, 256, 0, stream>>>(c0m1w, c0m2w, c0m4w, cm1w, cm2w, cm4w, arena);
    scatter_edges<<<2048, 256, 0, stream>>>(x, ei, Abuf);
    finalize_u0<<<1024, 256, 0, stream>>>(Abuf, u, total);
    trace_kernel<<<8, 256, 0, stream>>>(u, 32, trace);
    extractor_acc<<<1, 64, 0, stream>>>(trace, total, 32, np1w, np1b, np2w, np3w, oacc);

    for (int l = 0; l < 3; ++l) {
        int Cin = (l == 0) ? 32 : 64;
        const u16 *w1b, *w2b, *w4b;
        const float *b1, *b2, *b4;
        if (l == 0) {
            w1b = arena;            b1 = c0m1b;
            w2b = arena + 2048;     b2 = c0m2b;
            w4b = arena + 4096;     b4 = c0m4b;
        } else {
            int m = l - 1;
            w1b = arena + 10240 + m * 4096;  b1 = cm1b + m * 64;
            w2b = arena + 18432 + m * 4096;  b2 = cm2b + m * 64;
            w4b = arena + 26624 + m * 8192;  b4 = cm4b + m * 64;
        }
        // o1[h][i*512+k]; o2t[h][j*512+k] via transposed-position read of u
        conv_mfma<<<1024, 256, 0, stream>>>(u, Cin, (const u16*)nullptr, 0, w1b, b1, o1, 0);
        conv_mfma<<<1024, 256, 0, stream>>>(u, Cin, (const u16*)nullptr, 0, w2b, b2, o2t, 1);
        bmm_mfma<<<dim3(16, 64), 256, 0, stream>>>(o1, o2t, multcm);     // R2,R3 -> R4
        cm_to_pm<<<4096, 256, 0, stream>>>(multcm, multpm);              // R4 -> R2 (o1 dead)
        // m4: concat([mult, u]) @ w4^T + b4 -> u_raw cm (R2,R1 -> R3, o2t dead)
        conv_mfma<<<1024, 256, 0, stream>>>(multpm, 64, u, Cin, w4b, b4, uraw, 0);
        hipMemsetAsync(ssum, 0, 128 * 4, stream);   // zero ssum+ssq
        row_stats<<<dim3(8, 64), 256, 0, stream>>>(uraw, ssum, ssq);
        bn_finalize<<<1, 64, 0, stream>>>(ssum, ssq, bng + l * 64, bnb + l * 64, scl, shf, total, trace);
        norm_tr<<<4096, 256, 0, stream>>>(uraw, scl, shf, u, total);     // R3 -> R1
        trace_kernel<<<8, 256, 0, stream>>>(u, 64, trace);
        extractor_acc<<<1, 64, 0, stream>>>(trace, total, 64,
                                            fe1w + l * 4096, fe1b + l * 64,
                                            fe2w + l * 4096, fe3w + l * 4096, oacc);
    }
    head<<<1, 64, 0, stream>>>(oacc, acw, acb, flw, flb, out);
}

// Round 5
// 1025.491 us; speedup vs baseline: 1.1220x; 1.1220x over previous
//
#include <hip/hip_runtime.h>
#include <hip/hip_bf16.h>

// Problem dims (fixed)
#define Nn   512
#define NN   262144        // N*N positions
#define EDG  16384

typedef unsigned short u16;
typedef short v8s __attribute__((ext_vector_type(8)));   // 8 bf16 lanes (4 VGPR)
typedef float v4f __attribute__((ext_vector_type(4)));
typedef u16 u16x8 __attribute__((ext_vector_type(8)));

__device__ __forceinline__ float b2f(u16 u) {
    union { unsigned int i; float f; } v; v.i = ((unsigned int)u) << 16; return v.f;
}
__device__ __forceinline__ u16 f2b(float f) {
    union { float f; unsigned int i; } v; v.f = f;
    unsigned int r = (v.i + 0x7FFFu + ((v.i >> 16) & 1u)) >> 16;
    return (u16)r;
}

// ---------------------------------------------------------------------------
// Sentinel: diagnostic constant output (host-side guard fired)
__global__ void sentinel_kernel(float* __restrict__ out, float val) {
    if (threadIdx.x < 10) out[threadIdx.x] = val;
}

// ---------------------------------------------------------------------------
// K0: convert the 6 conv weight tensors (fp32) into one bf16 arena.
__global__ void cvt_weights(const float* __restrict__ s0, const float* __restrict__ s1,
                            const float* __restrict__ s2, const float* __restrict__ s3,
                            const float* __restrict__ s4, const float* __restrict__ s5,
                            u16* __restrict__ dst) {
    int t = blockIdx.x * 256 + threadIdx.x;
    if (t >= 43008) return;
    float v;
    if      (t < 2048)  v = s0[t];
    else if (t < 4096)  v = s1[t - 2048];
    else if (t < 10240) v = s2[t - 4096];
    else if (t < 18432) v = s3[t - 10240];
    else if (t < 26624) v = s4[t - 18432];
    else                v = s5[t - 26624];
    dst[t] = f2b(v);
}

// ---------------------------------------------------------------------------
// K1: scatter edges into A (fp32, pos-major [p][32]); x is fp32 [512][16]
__global__ void scatter_edges(const float* __restrict__ x, const int* __restrict__ ei,
                              float* __restrict__ A) {
    int t = blockIdx.x * 256 + threadIdx.x;
    if (t >= EDG * 32) return;
    int e = t >> 5, c = t & 31;
    int s = ei[e], d = ei[EDG + e];
    float v = (c < 16) ? x[s * 16 + c] : x[d * 16 + (c - 16)];
    atomicAdd(A + ((size_t)s * Nn + d) * 32 + c, v);
}

// ---------------------------------------------------------------------------
// K2: A fp32 -> u0 bf16 pos-major [p][32]; per-channel totals (atomic, layer-0 only)
__global__ __launch_bounds__(256) void finalize_u0(const float* __restrict__ A,
                                                   u16* __restrict__ u0,
                                                   float* __restrict__ total) {
    int t = threadIdx.x;
    int p = blockIdx.x * 256 + t;
    const float* Ar = A + (size_t)p * 32;
    float v[32];
#pragma unroll
    for (int c = 0; c < 32; ++c) v[c] = Ar[c];
#pragma unroll
    for (int c4 = 0; c4 < 8; ++c4) {
        ushort4 o = { f2b(v[c4*4]), f2b(v[c4*4+1]), f2b(v[c4*4+2]), f2b(v[c4*4+3]) };
        *(ushort4*)(u0 + (size_t)p * 32 + c4 * 4) = o;
    }
    __shared__ float red[4][32];
    int wv = t >> 6;
#pragma unroll
    for (int c = 0; c < 32; ++c) {
        float r = v[c];
        for (int off = 32; off > 0; off >>= 1) r += __shfl_down(r, off);
        if ((t & 63) == 0) red[wv][c] = r;
    }
    __syncthreads();
    if (t < 32) atomicAdd(total + t, red[0][t] + red[1][t] + red[2][t] + red[3][t]);
}

// ---------------------------------------------------------------------------
// K3: trace[c] = sum_i u[i*513][c]  (u pos-major [p][C]); layer-0 only (pre-zeroed)
__global__ void trace_kernel(const u16* __restrict__ u, int C, float* __restrict__ trace) {
    __shared__ float red[64];
    int t = threadIdx.x;
    if (t < 64) red[t] = 0.f;
    __syncthreads();
    int tpr = C >> 2;
    int g = t / tpr;
    int ng = 256 / tpr;
    int c4 = (t % tpr) * 4;
    float s0 = 0.f, s1 = 0.f, s2 = 0.f, s3 = 0.f;
    for (int i = blockIdx.x * 64 + g; i < blockIdx.x * 64 + 64; i += ng) {
        ushort4 w = *(const ushort4*)(u + (size_t)i * 513 * C + c4);
        s0 += b2f(w.x); s1 += b2f(w.y); s2 += b2f(w.z); s3 += b2f(w.w);
    }
    atomicAdd(&red[c4 + 0], s0); atomicAdd(&red[c4 + 1], s1);
    atomicAdd(&red[c4 + 2], s2); atomicAdd(&red[c4 + 3], s3);
    __syncthreads();
    if (t < C) atomicAdd(trace + t, red[t]);
}

// ---------------------------------------------------------------------------
// K3b: trace of raw (channel-major) activation; single block, no atomics.
__global__ void trace_raw_cm(const u16* __restrict__ uraw, float* __restrict__ trraw) {
    __shared__ float red[4][64];
    int t = threadIdx.x;
    int c = t & 63, g = t >> 6;
    float s = 0.f;
    const u16* base = uraw + (size_t)c * NN;
    for (int i = g * 128; i < g * 128 + 128; ++i) s += b2f(base[i * 513]);
    red[g][c] = s;
    __syncthreads();
    if (t < 64) trraw[t] = red[0][t] + red[1][t] + red[2][t] + red[3][t];
}

// ---------------------------------------------------------------------------
// K4: extractor MLP (fp32 weights), accumulate into out_acc[64]. 1 block, 64 threads.
__global__ void extractor_acc(const float* __restrict__ trace, const float* __restrict__ total,
                              int C, const float* __restrict__ w1, const float* __restrict__ b1,
                              const float* __restrict__ w2, const float* __restrict__ w3,
                              float* __restrict__ out_acc) {
    __shared__ float xo[64];
    int t = threadIdx.x;
    const float inv_n = 1.f / 512.f;
    const float inv_off = 1.f / (512.f * 511.f);
    float s1 = b1[t];
    for (int c = 0; c < C; ++c) s1 += (trace[c] * inv_n) * w1[t * C + c];
    float s2 = 0.f;
    for (int c = 0; c < C; ++c) s2 += ((total[c] - trace[c]) * inv_off) * w2[t * C + c];
    float o = s1 + s2;
    xo[t] = o;
    __syncthreads();
    float s3 = 0.f;
    for (int f = 0; f < 64; ++f) s3 += fmaxf(xo[f], 0.f) * w3[t * 64 + f];
    out_acc[t] += o + s3;
}

// ---------------------------------------------------------------------------
// K5: 1x1 conv via MFMA.  dst[h][p] = sum_c src[pr(p)][c]*w[h][c] + bias[h]
__global__ __launch_bounds__(256) void conv_mfma(const u16* __restrict__ src0, int c0,
                                                 const u16* __restrict__ src1, int c1,
                                                 const u16* __restrict__ w,
                                                 const float* __restrict__ bias,
                                                 u16* __restrict__ dst, int tr0) {
    const int K = c0 + c1;
    const int nkk = K >> 5;
    const int lane = threadIdx.x & 63;
    const int wave = threadIdx.x >> 6;
    const int l15 = lane & 15, quad = lane >> 4;
    const int pbase = blockIdx.x * 256 + wave * 64;

    v8s af[4][4];
    for (int kk = 0; kk < nkk; ++kk)
#pragma unroll
        for (int mt = 0; mt < 4; ++mt)
            af[mt][kk] = *reinterpret_cast<const v8s*>(w + (mt * 16 + l15) * K + kk * 32 + quad * 8);

    v4f acc[4][4];
#pragma unroll
    for (int mt = 0; mt < 4; ++mt)
#pragma unroll
        for (int nt = 0; nt < 4; ++nt) acc[mt][nt] = (v4f){0.f, 0.f, 0.f, 0.f};

#pragma unroll
    for (int nt = 0; nt < 4; ++nt) {
        const int p = pbase + nt * 16 + l15;
        const int pr = tr0 ? (((p & 511) << 9) | (p >> 9)) : p;
        for (int kk = 0; kk < nkk; ++kk) {
            const int cg = kk * 32 + quad * 8;
            const u16* sp = (cg < c0) ? (src0 + (size_t)pr * c0 + cg)
                                      : (src1 + (size_t)pr * c1 + (cg - c0));
            v8s b = *reinterpret_cast<const v8s*>(sp);
#pragma unroll
            for (int mt = 0; mt < 4; ++mt)
                acc[mt][nt] = __builtin_amdgcn_mfma_f32_16x16x32_bf16(af[mt][kk], b, acc[mt][nt], 0, 0, 0);
        }
    }
#pragma unroll
    for (int mt = 0; mt < 4; ++mt)
#pragma unroll
        for (int r = 0; r < 4; ++r) {
            const int h = mt * 16 + quad * 4 + r;
            const float bv = bias[h];
#pragma unroll
            for (int nt = 0; nt < 4; ++nt) {
                const int p = pbase + nt * 16 + l15;
                dst[(size_t)h * NN + p] = f2b(acc[mt][nt][r] + bv);
            }
        }
}

// ---------------------------------------------------------------------------
// K7: batched per-channel GEMM: mult[h] = o1[h] (512x512, [i][k]) * o2t[h]^T ([j][k])
__global__ __launch_bounds__(256) void bmm_mfma(const u16* __restrict__ Aall,
                                                const u16* __restrict__ Ball,
                                                u16* __restrict__ Call) {
    const int h = blockIdx.y;
    const int tx = blockIdx.x & 3, ty = blockIdx.x >> 2;
    const int lane = threadIdx.x & 63;
    const int wave = threadIdx.x >> 6;
    const int wr = wave >> 1, wc = wave & 1;
    const int l15 = lane & 15, quad = lane >> 4;
    const int ibase = ty * 128 + wr * 64, jbase = tx * 128 + wc * 64;
    const u16* Ap = Aall + (size_t)h * NN;
    const u16* Bp = Ball + (size_t)h * NN;
    const u16* ar[4]; const u16* br[4];
#pragma unroll
    for (int mt = 0; mt < 4; ++mt) ar[mt] = Ap + (ibase + mt * 16 + l15) * 512 + quad * 8;
#pragma unroll
    for (int nt = 0; nt < 4; ++nt) br[nt] = Bp + (jbase + nt * 16 + l15) * 512 + quad * 8;

    v4f acc[4][4];
#pragma unroll
    for (int mt = 0; mt < 4; ++mt)
#pragma unroll
        for (int nt = 0; nt < 4; ++nt) acc[mt][nt] = (v4f){0.f, 0.f, 0.f, 0.f};

    for (int kk = 0; kk < 16; ++kk) {
        v8s a[4], b[4];
#pragma unroll
        for (int mt = 0; mt < 4; ++mt) a[mt] = *reinterpret_cast<const v8s*>(ar[mt] + kk * 32);
#pragma unroll
        for (int nt = 0; nt < 4; ++nt) b[nt] = *reinterpret_cast<const v8s*>(br[nt] + kk * 32);
#pragma unroll
        for (int mt = 0; mt < 4; ++mt)
#pragma unroll
            for (int nt = 0; nt < 4; ++nt)
                acc[mt][nt] = __builtin_amdgcn_mfma_f32_16x16x32_bf16(a[mt], b[nt], acc[mt][nt], 0, 0, 0);
    }
    u16* Cp = Call + (size_t)h * NN;
#pragma unroll
    for (int mt = 0; mt < 4; ++mt)
#pragma unroll
        for (int r = 0; r < 4; ++r) {
            const int i = ibase + mt * 16 + quad * 4 + r;
#pragma unroll
            for (int nt = 0; nt < 4; ++nt) {
                const int j = jbase + nt * 16 + l15;
                Cp[i * 512 + j] = f2b(acc[mt][nt][r]);
            }
        }
}

// ---------------------------------------------------------------------------
// K8: channel-major [64][NN] -> pos-major [NN][64] transpose, optional BN affine.
// Tile 64c x 256p. Phase 1: coalesced 16B/lane global reads -> LDS cm (pad 258).
// Phase 2: b32 pair reads (2-way = free), affine, contiguous 8KB/wave pm writes.
__global__ __launch_bounds__(256) void transpose_cm_pm(const u16* __restrict__ src,
                                                       u16* __restrict__ dst,
                                                       const float* __restrict__ scale,
                                                       const float* __restrict__ shift,
                                                       int affine) {
    __shared__ u16 L[64 * 258];
    __shared__ float sc[64], sh[64];
    int t = threadIdx.x;
    int p0 = blockIdx.x * 256;
    if (affine && t < 64) { sc[t] = scale[t]; sh[t] = shift[t]; }
    int o = t & 31;          // 16B chunk within row
    int cb = t >> 5;         // 0..7
#pragma unroll
    for (int r = 0; r < 8; ++r) {
        int c = r * 8 + cb;
        const u16* gp = src + (size_t)c * NN + p0 + o * 8;
        ushort4 a = *(const ushort4*)(gp);
        ushort4 b = *(const ushort4*)(gp + 4);
        u16* Lp = L + c * 258 + o * 8;
        *(ushort4*)(Lp) = a;
        *(ushort4*)(Lp + 4) = b;
    }
    __syncthreads();
    int pp = t >> 1;             // 0..127 (position pair)
    int ch = (t & 1) * 32;       // channel half
    u16 o0[32], o1[32];
#pragma unroll
    for (int i = 0; i < 32; ++i) {
        unsigned int w = *(const unsigned int*)(L + (ch + i) * 258 + 2 * pp);
        u16 lo = (u16)(w & 0xFFFFu), hi = (u16)(w >> 16);
        if (affine) {
            float s = sc[ch + i], f = sh[ch + i];
            o0[i] = f2b(b2f(lo) * s + f);
            o1[i] = f2b(b2f(hi) * s + f);
        } else { o0[i] = lo; o1[i] = hi; }
    }
    u16* d0 = dst + (size_t)(p0 + 2 * pp) * 64 + ch;
    u16* d1 = d0 + 64;
#pragma unroll
    for (int k = 0; k < 4; ++k) {
        u16x8 v0 = { o0[k*8], o0[k*8+1], o0[k*8+2], o0[k*8+3], o0[k*8+4], o0[k*8+5], o0[k*8+6], o0[k*8+7] };
        u16x8 v1 = { o1[k*8], o1[k*8+1], o1[k*8+2], o1[k*8+3], o1[k*8+4], o1[k*8+5], o1[k*8+6], o1[k*8+7] };
        *(u16x8*)(d0 + k * 8) = v0;
        *(u16x8*)(d1 + k * 8) = v1;
    }
}

// ---------------------------------------------------------------------------
// K9: per-channel sum / sumsq over channel-major rows
__global__ __launch_bounds__(256) void row_stats(const u16* __restrict__ src,
                                                 float* __restrict__ sum, float* __restrict__ sq) {
    int c = blockIdx.y, t = threadIdx.x;
    size_t base = (size_t)c * NN + (size_t)blockIdx.x * 32768;
    float s = 0.f, s2 = 0.f;
    for (int i = 0; i < 32; ++i) {
        ushort4 w = *(const ushort4*)(src + base + (size_t)i * 1024 + t * 4);
        float a0 = b2f(w.x), a1 = b2f(w.y), a2 = b2f(w.z), a3 = b2f(w.w);
        s += a0 + a1 + a2 + a3;
        s2 += a0 * a0 + a1 * a1 + a2 * a2 + a3 * a3;
    }
    for (int off = 32; off > 0; off >>= 1) { s += __shfl_down(s, off); s2 += __shfl_down(s2, off); }
    __shared__ float r1[4], r2[4];
    if ((t & 63) == 0) { r1[t >> 6] = s; r2[t >> 6] = s2; }
    __syncthreads();
    if (t == 0) {
        atomicAdd(sum + c, r1[0] + r1[1] + r1[2] + r1[3]);
        atomicAdd(sq + c, r2[0] + r2[1] + r2[2] + r2[3]);
    }
}

// ---------------------------------------------------------------------------
// K11: BN scale/shift from stats; ALSO analytic normalized totals & trace
// (normalize is affine: total = sc*sum_raw + NN*sh; trace = sc*trace_raw + 512*sh)
__global__ void bn_finalize(const float* __restrict__ ssum, const float* __restrict__ ssq,
                            const float* __restrict__ trraw,
                            const float* __restrict__ g, const float* __restrict__ b,
                            float* __restrict__ scale, float* __restrict__ shift,
                            float* __restrict__ total, float* __restrict__ trace) {
    int t = threadIdx.x;   // 64
    float mean = ssum[t] * (1.f / 262144.f);
    float var = ssq[t] * (1.f / 262144.f) - mean * mean;
    float sc = g[t] * rsqrtf(fmaxf(var, 0.f) + 1e-5f);
    float sh = b[t] - mean * sc;
    scale[t] = sc;
    shift[t] = sh;
    total[t] = sc * ssum[t] + 262144.f * sh;
    trace[t] = sc * trraw[t] + 512.f * sh;
}

// ---------------------------------------------------------------------------
// K12: head (fp32 weights/out): relu/3, after_conv residual, final linear, log_softmax
__global__ void head(const float* __restrict__ out_acc, const float* __restrict__ acw,
                     const float* __restrict__ acb, const float* __restrict__ flw,
                     const float* __restrict__ flb, float* __restrict__ out) {
    __shared__ float x[64], x2[64], l[10];
    int t = threadIdx.x;  // 64
    x[t] = fmaxf(out_acc[t], 0.f) * (1.f / 3.f);
    __syncthreads();
    float y = acb[t];
    for (int f = 0; f < 64; ++f) y += x[f] * acw[t * 64 + f];
    x2[t] = x[t] + fmaxf(y, 0.f);
    __syncthreads();
    if (t < 10) {
        float s = flb[t];
        for (int f = 0; f < 64; ++f) s += x2[f] * flw[t * 64 + f];
        l[t] = s;
    }
    __syncthreads();
    if (t == 0) {
        float m = l[0];
        for (int i = 1; i < 10; ++i) m = fmaxf(m, l[i]);
        float se = 0.f;
        for (int i = 0; i < 10; ++i) se += expf(l[i] - m);
        float ls = m + logf(se);
        for (int i = 0; i < 10; ++i) out[i] = l[i] - ls;
    }
}

// ---------------------------------------------------------------------------
extern "C" void kernel_launch(void* const* d_in, const int* in_sizes, int n_in,
                              void* d_out, int out_size, void* d_ws, size_t ws_size,
                              hipStream_t stream) {
    float* out = (float*)d_out;

    static const int exp_sizes[28] = {
        8192, 32768,
        2048, 64, 2048, 4096,
        2048, 64, 2048, 64, 6144, 64,
        8192, 128, 8192, 128, 16384, 128,
        192, 192,
        12288, 192, 12288, 12288,
        4096, 64, 640, 10
    };
    bool ok = (n_in == 28);
    if (ok) for (int i = 0; i < 28; ++i) if (in_sizes[i] != exp_sizes[i]) ok = false;
    if (!ok) { sentinel_kernel<<<1, 64, 0, stream>>>(out, -5.0f); return; }

    const size_t RSZ = (size_t)NN * 64 * 2;            // 33.55 MB per region
    const size_t BIG_OFF = 4096 + 90112;               // control + bf16 weight arena
    if (ws_size < BIG_OFF + 4 * RSZ) {
        sentinel_kernel<<<1, 64, 0, stream>>>(out, -7.0f);
        return;
    }

    const float* x     = (const float*)d_in[0];
    const int*   ei    = (const int*)d_in[1];
    const float* np1w  = (const float*)d_in[2];
    const float* np1b  = (const float*)d_in[3];
    const float* np2w  = (const float*)d_in[4];
    const float* np3w  = (const float*)d_in[5];
    const float* c0m1b = (const float*)d_in[7];
    const float* c0m2b = (const float*)d_in[9];
    const float* c0m4b = (const float*)d_in[11];
    const float* cm1b  = (const float*)d_in[13];
    const float* cm2b  = (const float*)d_in[15];
    const float* cm4b  = (const float*)d_in[17];
    const float* bng   = (const float*)d_in[18];
    const float* bnb   = (const float*)d_in[19];
    const float* fe1w  = (const float*)d_in[20];
    const float* fe1b  = (const float*)d_in[21];
    const float* fe2w  = (const float*)d_in[22];
    const float* fe3w  = (const float*)d_in[23];
    const float* acw   = (const float*)d_in[24];
    const float* acb   = (const float*)d_in[25];
    const float* flw   = (const float*)d_in[26];
    const float* flb   = (const float*)d_in[27];

    char* ws = (char*)d_ws;
    float* small = (float*)ws;
    float* ssum  = small;
    float* ssq   = small + 64;
    float* scl   = small + 128;
    float* shf   = small + 192;
    float* trace = small + 256;
    float* total = small + 320;
    float* oacc  = small + 384;
    float* trraw = small + 448;

    u16* arena = (u16*)(ws + 4096);          // bf16 conv weights, 43008 elements

    char* big = ws + BIG_OFF;
    u16*   u      = (u16*)(big + 0 * RSZ);   // R1: u pos-major (layer state)
    u16*   o1     = (u16*)(big + 1 * RSZ);   // R2: o1 cm -> later multpm
    u16*   multpm = (u16*)(big + 1 * RSZ);
    u16*   o2t    = (u16*)(big + 2 * RSZ);   // R3: o2t cm -> later uraw
    u16*   uraw   = (u16*)(big + 2 * RSZ);
    float* Abuf   = (float*)(big + 3 * RSZ); // R4: A fp32 staging -> later multcm
    u16*   multcm = (u16*)(big + 3 * RSZ);

    hipMemsetAsync(small, 0, 512 * 4, stream);
    hipMemsetAsync(Abuf, 0, (size_t)NN * 32 * 4, stream);

    cvt_weights<<<168, 256, 0, stream>>>((const float*)d_in[6], (const float*)d_in[8],
                                         (const float*)d_in[10], (const float*)d_in[12],
                                         (const float*)d_in[14], (const float*)d_in[16], arena);
    scatter_edges<<<2048, 256, 0, stream>>>(x, ei, Abuf);
    finalize_u0<<<1024, 256, 0, stream>>>(Abuf, u, total);
    trace_kernel<<<8, 256, 0, stream>>>(u, 32, trace);
    extractor_acc<<<1, 64, 0, stream>>>(trace, total, 32, np1w, np1b, np2w, np3w, oacc);

    for (int l = 0; l < 3; ++l) {
        int Cin = (l == 0) ? 32 : 64;
        const u16 *w1b, *w2b, *w4b;
        const float *b1, *b2, *b4;
        if (l == 0) {
            w1b = arena;            b1 = c0m1b;
            w2b = arena + 2048;     b2 = c0m2b;
            w4b = arena + 4096;     b4 = c0m4b;
        } else {
            int m = l - 1;
            w1b = arena + 10240 + m * 4096;  b1 = cm1b + m * 64;
            w2b = arena + 18432 + m * 4096;  b2 = cm2b + m * 64;
            w4b = arena + 26624 + m * 8192;  b4 = cm4b + m * 64;
        }
        conv_mfma<<<1024, 256, 0, stream>>>(u, Cin, (const u16*)nullptr, 0, w1b, b1, o1, 0);
        conv_mfma<<<1024, 256, 0, stream>>>(u, Cin, (const u16*)nullptr, 0, w2b, b2, o2t, 1);
        bmm_mfma<<<dim3(16, 64), 256, 0, stream>>>(o1, o2t, multcm);         // R2,R3 -> R4
        transpose_cm_pm<<<1024, 256, 0, stream>>>(multcm, multpm, nullptr, nullptr, 0); // R4 -> R2
        conv_mfma<<<1024, 256, 0, stream>>>(multpm, 64, u, Cin, w4b, b4, uraw, 0);      // R2,R1 -> R3
        hipMemsetAsync(ssum, 0, 128 * 4, stream);
        row_stats<<<dim3(8, 64), 256, 0, stream>>>(uraw, ssum, ssq);
        trace_raw_cm<<<1, 256, 0, stream>>>(uraw, trraw);
        bn_finalize<<<1, 64, 0, stream>>>(ssum, ssq, trraw, bng + l * 64, bnb + l * 64,
                                          scl, shf, total, trace);
        transpose_cm_pm<<<1024, 256, 0, stream>>>(uraw, u, scl, shf, 1);     // R3 -> R1
        extractor_acc<<<1, 64, 0, stream>>>(trace, total, 64,
                                            fe1w + l * 4096, fe1b + l * 64,
                                            fe2w + l * 4096, fe3w + l * 4096, oacc);
    }
    head<<<1, 64, 0, stream>>>(oacc, acw, acb, flw, flb, out);
}

// Round 6
// 823.371 us; speedup vs baseline: 1.3975x; 1.2455x over previous
//
#include <hip/hip_runtime.h>
#include <hip/hip_bf16.h>

// Problem dims (fixed)
#define Nn   512
#define NN   262144        // N*N positions
#define EDG  16384

typedef unsigned short u16;
typedef short v8s __attribute__((ext_vector_type(8)));   // 8 bf16 lanes (4 VGPR)
typedef float v4f __attribute__((ext_vector_type(4)));
typedef u16 u16x8 __attribute__((ext_vector_type(8)));

__device__ __forceinline__ float b2f(u16 u) {
    union { unsigned int i; float f; } v; v.i = ((unsigned int)u) << 16; return v.f;
}
__device__ __forceinline__ u16 f2b(float f) {
    union { float f; unsigned int i; } v; v.f = f;
    unsigned int r = (v.i + 0x7FFFu + ((v.i >> 16) & 1u)) >> 16;
    return (u16)r;
}

// ---------------------------------------------------------------------------
__global__ void sentinel_kernel(float* __restrict__ out, float val) {
    if (threadIdx.x < 10) out[threadIdx.x] = val;
}

// ---------------------------------------------------------------------------
// K0: convert the 6 conv weight tensors (fp32) into one bf16 arena.
__global__ void cvt_weights(const float* __restrict__ s0, const float* __restrict__ s1,
                            const float* __restrict__ s2, const float* __restrict__ s3,
                            const float* __restrict__ s4, const float* __restrict__ s5,
                            u16* __restrict__ dst) {
    int t = blockIdx.x * 256 + threadIdx.x;
    if (t >= 43008) return;
    float v;
    if      (t < 2048)  v = s0[t];
    else if (t < 4096)  v = s1[t - 2048];
    else if (t < 10240) v = s2[t - 4096];
    else if (t < 18432) v = s3[t - 10240];
    else if (t < 26624) v = s4[t - 18432];
    else                v = s5[t - 26624];
    dst[t] = f2b(v);
}

// ---------------------------------------------------------------------------
// K1: scatter edges into A (fp32, pos-major [p][32]); x is fp32 [512][16]
__global__ void scatter_edges(const float* __restrict__ x, const int* __restrict__ ei,
                              float* __restrict__ A) {
    int t = blockIdx.x * 256 + threadIdx.x;
    if (t >= EDG * 32) return;
    int e = t >> 5, c = t & 31;
    int s = ei[e], d = ei[EDG + e];
    float v = (c < 16) ? x[s * 16 + c] : x[d * 16 + (c - 16)];
    atomicAdd(A + ((size_t)s * Nn + d) * 32 + c, v);
}

// ---------------------------------------------------------------------------
// K2: A fp32 -> u0 bf16 pos-major [p][32]; per-channel totals (atomic, layer-0 only)
__global__ __launch_bounds__(256) void finalize_u0(const float* __restrict__ A,
                                                   u16* __restrict__ u0,
                                                   float* __restrict__ total) {
    int t = threadIdx.x;
    int p = blockIdx.x * 256 + t;
    const float* Ar = A + (size_t)p * 32;
    float v[32];
#pragma unroll
    for (int c = 0; c < 32; ++c) v[c] = Ar[c];
#pragma unroll
    for (int c4 = 0; c4 < 8; ++c4) {
        ushort4 o = { f2b(v[c4*4]), f2b(v[c4*4+1]), f2b(v[c4*4+2]), f2b(v[c4*4+3]) };
        *(ushort4*)(u0 + (size_t)p * 32 + c4 * 4) = o;
    }
    __shared__ float red[4][32];
    int wv = t >> 6;
#pragma unroll
    for (int c = 0; c < 32; ++c) {
        float r = v[c];
        for (int off = 32; off > 0; off >>= 1) r += __shfl_down(r, off);
        if ((t & 63) == 0) red[wv][c] = r;
    }
    __syncthreads();
    if (t < 32) atomicAdd(total + t, red[0][t] + red[1][t] + red[2][t] + red[3][t]);
}

// ---------------------------------------------------------------------------
// K3: trace[c] = sum_i u[i*513][c]  (u pos-major [p][C]); layer-0 only (pre-zeroed)
__global__ void trace_kernel(const u16* __restrict__ u, int C, float* __restrict__ trace) {
    __shared__ float red[64];
    int t = threadIdx.x;
    if (t < 64) red[t] = 0.f;
    __syncthreads();
    int tpr = C >> 2;
    int g = t / tpr;
    int ng = 256 / tpr;
    int c4 = (t % tpr) * 4;
    float s0 = 0.f, s1 = 0.f, s2 = 0.f, s3 = 0.f;
    for (int i = blockIdx.x * 64 + g; i < blockIdx.x * 64 + 64; i += ng) {
        ushort4 w = *(const ushort4*)(u + (size_t)i * 513 * C + c4);
        s0 += b2f(w.x); s1 += b2f(w.y); s2 += b2f(w.z); s3 += b2f(w.w);
    }
    atomicAdd(&red[c4 + 0], s0); atomicAdd(&red[c4 + 1], s1);
    atomicAdd(&red[c4 + 2], s2); atomicAdd(&red[c4 + 3], s3);
    __syncthreads();
    if (t < C) atomicAdd(trace + t, red[t]);
}

// ---------------------------------------------------------------------------
// K3b: trace of raw (channel-major) activation; 64 blocks (one per channel).
__global__ void trace_raw_cm(const u16* __restrict__ uraw, float* __restrict__ trraw) {
    int c = blockIdx.x, t = threadIdx.x;
    const u16* base = uraw + (size_t)c * NN;
    float s = b2f(base[(size_t)(2 * t) * 513]) + b2f(base[(size_t)(2 * t + 1) * 513]);
    for (int off = 32; off > 0; off >>= 1) s += __shfl_down(s, off);
    __shared__ float r[4];
    if ((t & 63) == 0) r[t >> 6] = s;
    __syncthreads();
    if (t == 0) trraw[c] = r[0] + r[1] + r[2] + r[3];
}

// ---------------------------------------------------------------------------
// K4: extractor MLP (fp32 weights), accumulate into out_acc[64]. 1 block, 64 threads.
__global__ void extractor_acc(const float* __restrict__ trace, const float* __restrict__ total,
                              int C, const float* __restrict__ w1, const float* __restrict__ b1,
                              const float* __restrict__ w2, const float* __restrict__ w3,
                              float* __restrict__ out_acc) {
    __shared__ float xo[64];
    int t = threadIdx.x;
    const float inv_n = 1.f / 512.f;
    const float inv_off = 1.f / (512.f * 511.f);
    float s1 = b1[t];
    for (int c = 0; c < C; ++c) s1 += (trace[c] * inv_n) * w1[t * C + c];
    float s2 = 0.f;
    for (int c = 0; c < C; ++c) s2 += ((total[c] - trace[c]) * inv_off) * w2[t * C + c];
    float o = s1 + s2;
    xo[t] = o;
    __syncthreads();
    float s3 = 0.f;
    for (int f = 0; f < 64; ++f) s3 += fmaxf(xo[f], 0.f) * w3[t * 64 + f];
    out_acc[t] += o + s3;
}

// ---------------------------------------------------------------------------
// K5: 1x1 conv via MFMA.  dst[h][p] = sum_c src[pr(p)][c]*w[h][c] + bias[h]
__global__ __launch_bounds__(256) void conv_mfma(const u16* __restrict__ src0, int c0,
                                                 const u16* __restrict__ src1, int c1,
                                                 const u16* __restrict__ w,
                                                 const float* __restrict__ bias,
                                                 u16* __restrict__ dst, int tr0) {
    const int K = c0 + c1;
    const int nkk = K >> 5;
    const int lane = threadIdx.x & 63;
    const int wave = threadIdx.x >> 6;
    const int l15 = lane & 15, quad = lane >> 4;
    const int pbase = blockIdx.x * 256 + wave * 64;

    v8s af[4][4];
    for (int kk = 0; kk < nkk; ++kk)
#pragma unroll
        for (int mt = 0; mt < 4; ++mt)
            af[mt][kk] = *reinterpret_cast<const v8s*>(w + (mt * 16 + l15) * K + kk * 32 + quad * 8);

    v4f acc[4][4];
#pragma unroll
    for (int mt = 0; mt < 4; ++mt)
#pragma unroll
        for (int nt = 0; nt < 4; ++nt) acc[mt][nt] = (v4f){0.f, 0.f, 0.f, 0.f};

#pragma unroll
    for (int nt = 0; nt < 4; ++nt) {
        const int p = pbase + nt * 16 + l15;
        const int pr = tr0 ? (((p & 511) << 9) | (p >> 9)) : p;
        for (int kk = 0; kk < nkk; ++kk) {
            const int cg = kk * 32 + quad * 8;
            const u16* sp = (cg < c0) ? (src0 + (size_t)pr * c0 + cg)
                                      : (src1 + (size_t)pr * c1 + (cg - c0));
            v8s b = *reinterpret_cast<const v8s*>(sp);
#pragma unroll
            for (int mt = 0; mt < 4; ++mt)
                acc[mt][nt] = __builtin_amdgcn_mfma_f32_16x16x32_bf16(af[mt][kk], b, acc[mt][nt], 0, 0, 0);
        }
    }
#pragma unroll
    for (int mt = 0; mt < 4; ++mt)
#pragma unroll
        for (int r = 0; r < 4; ++r) {
            const int h = mt * 16 + quad * 4 + r;
            const float bv = bias[h];
#pragma unroll
            for (int nt = 0; nt < 4; ++nt) {
                const int p = pbase + nt * 16 + l15;
                dst[(size_t)h * NN + p] = f2b(acc[mt][nt][r] + bv);
            }
        }
}

// ---------------------------------------------------------------------------
// K7 v2: batched per-channel GEMM, LDS-staged.
// mult[h] = o1[h] (512x512, [i][k]) * o2t[h]^T ([j][k]).
// Block = 128x128 tile of channel h; K chunked BK=64; padded LDS (stride 72)
// gives conflict-free ds_read_b128 fragments; register-prefetch pipeline.
__global__ __launch_bounds__(256) void bmm_mfma(const u16* __restrict__ Aall,
                                                const u16* __restrict__ Ball,
                                                u16* __restrict__ Call) {
    __shared__ u16 LA[128 * 72];
    __shared__ u16 LB[128 * 72];
    const int h = blockIdx.y;
    const int tx = blockIdx.x & 3, ty = blockIdx.x >> 2;
    const int t = threadIdx.x;
    const int lane = t & 63, wave = t >> 6;
    const int wr = wave >> 1, wc = wave & 1;
    const int l15 = lane & 15, quad = lane >> 4;
    const u16* Ap = Aall + (size_t)h * NN + (size_t)ty * 128 * 512;
    const u16* Bp = Ball + (size_t)h * NN + (size_t)tx * 128 * 512;

    const int srow = t >> 3;          // 0..31 (row group per stage iter)
    const int scol = (t & 7) * 8;     // 16B chunk within 64-elem row

    v4f acc[4][4];
#pragma unroll
    for (int mt = 0; mt < 4; ++mt)
#pragma unroll
        for (int nt = 0; nt < 4; ++nt) acc[mt][nt] = (v4f){0.f, 0.f, 0.f, 0.f};

    v8s ra[4], rb[4];
#pragma unroll
    for (int i = 0; i < 4; ++i) {
        int row = i * 32 + srow;
        ra[i] = *(const v8s*)(Ap + (size_t)row * 512 + scol);
        rb[i] = *(const v8s*)(Bp + (size_t)row * 512 + scol);
    }

    for (int ck = 0; ck < 8; ++ck) {
#pragma unroll
        for (int i = 0; i < 4; ++i) {
            int row = i * 32 + srow;
            *(v8s*)(LA + row * 72 + scol) = ra[i];
            *(v8s*)(LB + row * 72 + scol) = rb[i];
        }
        __syncthreads();
        if (ck < 7) {
            const int k0 = (ck + 1) * 64;
#pragma unroll
            for (int i = 0; i < 4; ++i) {
                int row = i * 32 + srow;
                ra[i] = *(const v8s*)(Ap + (size_t)row * 512 + k0 + scol);
                rb[i] = *(const v8s*)(Bp + (size_t)row * 512 + k0 + scol);
            }
        }
#pragma unroll
        for (int kk = 0; kk < 2; ++kk) {
            v8s a[4], b[4];
#pragma unroll
            for (int mt = 0; mt < 4; ++mt)
                a[mt] = *(const v8s*)(LA + (wr * 64 + mt * 16 + l15) * 72 + kk * 32 + quad * 8);
#pragma unroll
            for (int nt = 0; nt < 4; ++nt)
                b[nt] = *(const v8s*)(LB + (wc * 64 + nt * 16 + l15) * 72 + kk * 32 + quad * 8);
#pragma unroll
            for (int mt = 0; mt < 4; ++mt)
#pragma unroll
                for (int nt = 0; nt < 4; ++nt)
                    acc[mt][nt] = __builtin_amdgcn_mfma_f32_16x16x32_bf16(a[mt], b[nt], acc[mt][nt], 0, 0, 0);
        }
        __syncthreads();
    }

    u16* Cp = Call + (size_t)h * NN;
#pragma unroll
    for (int mt = 0; mt < 4; ++mt)
#pragma unroll
        for (int r = 0; r < 4; ++r) {
            const int i = ty * 128 + wr * 64 + mt * 16 + quad * 4 + r;
#pragma unroll
            for (int nt = 0; nt < 4; ++nt) {
                const int j = tx * 128 + wc * 64 + nt * 16 + l15;
                Cp[i * 512 + j] = f2b(acc[mt][nt][r]);
            }
        }
}

// ---------------------------------------------------------------------------
// K8: channel-major [64][NN] -> pos-major [NN][64] transpose, optional BN affine.
__global__ __launch_bounds__(256) void transpose_cm_pm(const u16* __restrict__ src,
                                                       u16* __restrict__ dst,
                                                       const float* __restrict__ scale,
                                                       const float* __restrict__ shift,
                                                       int affine) {
    __shared__ u16 L[64 * 258];
    __shared__ float sc[64], sh[64];
    int t = threadIdx.x;
    int p0 = blockIdx.x * 256;
    if (affine && t < 64) { sc[t] = scale[t]; sh[t] = shift[t]; }
    int o = t & 31;
    int cb = t >> 5;
#pragma unroll
    for (int r = 0; r < 8; ++r) {
        int c = r * 8 + cb;
        const u16* gp = src + (size_t)c * NN + p0 + o * 8;
        ushort4 a = *(const ushort4*)(gp);
        ushort4 b = *(const ushort4*)(gp + 4);
        u16* Lp = L + c * 258 + o * 8;
        *(ushort4*)(Lp) = a;
        *(ushort4*)(Lp + 4) = b;
    }
    __syncthreads();
    int pp = t >> 1;
    int ch = (t & 1) * 32;
    u16 o0[32], o1[32];
#pragma unroll
    for (int i = 0; i < 32; ++i) {
        unsigned int w = *(const unsigned int*)(L + (ch + i) * 258 + 2 * pp);
        u16 lo = (u16)(w & 0xFFFFu), hi = (u16)(w >> 16);
        if (affine) {
            float s = sc[ch + i], f = sh[ch + i];
            o0[i] = f2b(b2f(lo) * s + f);
            o1[i] = f2b(b2f(hi) * s + f);
        } else { o0[i] = lo; o1[i] = hi; }
    }
    u16* d0 = dst + (size_t)(p0 + 2 * pp) * 64 + ch;
    u16* d1 = d0 + 64;
#pragma unroll
    for (int k = 0; k < 4; ++k) {
        u16x8 v0 = { o0[k*8], o0[k*8+1], o0[k*8+2], o0[k*8+3], o0[k*8+4], o0[k*8+5], o0[k*8+6], o0[k*8+7] };
        u16x8 v1 = { o1[k*8], o1[k*8+1], o1[k*8+2], o1[k*8+3], o1[k*8+4], o1[k*8+5], o1[k*8+6], o1[k*8+7] };
        *(u16x8*)(d0 + k * 8) = v0;
        *(u16x8*)(d1 + k * 8) = v1;
    }
}

// ---------------------------------------------------------------------------
// K9: per-channel sum/sumsq partials (no atomics): sp[c*8+bx], sqp[c*8+bx]
__global__ __launch_bounds__(256) void row_stats(const u16* __restrict__ src,
                                                 float* __restrict__ sp, float* __restrict__ sqp) {
    int c = blockIdx.y, t = threadIdx.x;
    size_t base = (size_t)c * NN + (size_t)blockIdx.x * 32768;
    float s = 0.f, s2 = 0.f;
    for (int i = 0; i < 32; ++i) {
        ushort4 w = *(const ushort4*)(src + base + (size_t)i * 1024 + t * 4);
        float a0 = b2f(w.x), a1 = b2f(w.y), a2 = b2f(w.z), a3 = b2f(w.w);
        s += a0 + a1 + a2 + a3;
        s2 += a0 * a0 + a1 * a1 + a2 * a2 + a3 * a3;
    }
    for (int off = 32; off > 0; off >>= 1) { s += __shfl_down(s, off); s2 += __shfl_down(s2, off); }
    __shared__ float r1[4], r2[4];
    if ((t & 63) == 0) { r1[t >> 6] = s; r2[t >> 6] = s2; }
    __syncthreads();
    if (t == 0) {
        sp[c * 8 + blockIdx.x]  = r1[0] + r1[1] + r1[2] + r1[3];
        sqp[c * 8 + blockIdx.x] = r2[0] + r2[1] + r2[2] + r2[3];
    }
}

// ---------------------------------------------------------------------------
// K11: BN scale/shift from partial stats; analytic normalized totals & trace.
__global__ void bn_finalize(const float* __restrict__ sp, const float* __restrict__ sqp,
                            const float* __restrict__ trraw,
                            const float* __restrict__ g, const float* __restrict__ b,
                            float* __restrict__ scale, float* __restrict__ shift,
                            float* __restrict__ total, float* __restrict__ trace) {
    int t = threadIdx.x;   // 64
    float s = 0.f, q = 0.f;
#pragma unroll
    for (int i = 0; i < 8; ++i) { s += sp[t * 8 + i]; q += sqp[t * 8 + i]; }
    float mean = s * (1.f / 262144.f);
    float var = q * (1.f / 262144.f) - mean * mean;
    float sc = g[t] * rsqrtf(fmaxf(var, 0.f) + 1e-5f);
    float sh = b[t] - mean * sc;
    scale[t] = sc;
    shift[t] = sh;
    total[t] = sc * s + 262144.f * sh;
    trace[t] = sc * trraw[t] + 512.f * sh;
}

// ---------------------------------------------------------------------------
// K12: head (fp32 weights/out)
__global__ void head(const float* __restrict__ out_acc, const float* __restrict__ acw,
                     const float* __restrict__ acb, const float* __restrict__ flw,
                     const float* __restrict__ flb, float* __restrict__ out) {
    __shared__ float x[64], x2[64], l[10];
    int t = threadIdx.x;  // 64
    x[t] = fmaxf(out_acc[t], 0.f) * (1.f / 3.f);
    __syncthreads();
    float y = acb[t];
    for (int f = 0; f < 64; ++f) y += x[f] * acw[t * 64 + f];
    x2[t] = x[t] + fmaxf(y, 0.f);
    __syncthreads();
    if (t < 10) {
        float s = flb[t];
        for (int f = 0; f < 64; ++f) s += x2[f] * flw[t * 64 + f];
        l[t] = s;
    }
    __syncthreads();
    if (t == 0) {
        float m = l[0];
        for (int i = 1; i < 10; ++i) m = fmaxf(m, l[i]);
        float se = 0.f;
        for (int i = 0; i < 10; ++i) se += expf(l[i] - m);
        float ls = m + logf(se);
        for (int i = 0; i < 10; ++i) out[i] = l[i] - ls;
    }
}

// ---------------------------------------------------------------------------
extern "C" void kernel_launch(void* const* d_in, const int* in_sizes, int n_in,
                              void* d_out, int out_size, void* d_ws, size_t ws_size,
                              hipStream_t stream) {
    float* out = (float*)d_out;

    static const int exp_sizes[28] = {
        8192, 32768,
        2048, 64, 2048, 4096,
        2048, 64, 2048, 64, 6144, 64,
        8192, 128, 8192, 128, 16384, 128,
        192, 192,
        12288, 192, 12288, 12288,
        4096, 64, 640, 10
    };
    bool ok = (n_in == 28);
    if (ok) for (int i = 0; i < 28; ++i) if (in_sizes[i] != exp_sizes[i]) ok = false;
    if (!ok) { sentinel_kernel<<<1, 64, 0, stream>>>(out, -5.0f); return; }

    const size_t RSZ = (size_t)NN * 64 * 2;            // 33.55 MB per region
    const size_t BIG_OFF = 8192 + 90112;               // control (8KB) + bf16 weight arena
    if (ws_size < BIG_OFF + 4 * RSZ) {
        sentinel_kernel<<<1, 64, 0, stream>>>(out, -7.0f);
        return;
    }

    const float* x     = (const float*)d_in[0];
    const int*   ei    = (const int*)d_in[1];
    const float* np1w  = (const float*)d_in[2];
    const float* np1b  = (const float*)d_in[3];
    const float* np2w  = (const float*)d_in[4];
    const float* np3w  = (const float*)d_in[5];
    const float* c0m1b = (const float*)d_in[7];
    const float* c0m2b = (const float*)d_in[9];
    const float* c0m4b = (const float*)d_in[11];
    const float* cm1b  = (const float*)d_in[13];
    const float* cm2b  = (const float*)d_in[15];
    const float* cm4b  = (const float*)d_in[17];
    const float* bng   = (const float*)d_in[18];
    const float* bnb   = (const float*)d_in[19];
    const float* fe1w  = (const float*)d_in[20];
    const float* fe1b  = (const float*)d_in[21];
    const float* fe2w  = (const float*)d_in[22];
    const float* fe3w  = (const float*)d_in[23];
    const float* acw   = (const float*)d_in[24];
    const float* acb   = (const float*)d_in[25];
    const float* flw   = (const float*)d_in[26];
    const float* flb   = (const float*)d_in[27];

    char* ws = (char*)d_ws;
    float* small = (float*)ws;
    float* scl   = small + 128;
    float* shf   = small + 192;
    float* trace = small + 256;
    float* total = small + 320;
    float* oacc  = small + 384;
    float* trraw = small + 448;
    float* spart = small + 512;    // 512 floats
    float* sqpart= small + 1024;   // 512 floats

    u16* arena = (u16*)(ws + 8192);          // bf16 conv weights, 43008 elements

    char* big = ws + BIG_OFF;
    u16*   u      = (u16*)(big + 0 * RSZ);   // R1: u pos-major (layer state)
    u16*   o1     = (u16*)(big + 1 * RSZ);   // R2: o1 cm -> later multpm
    u16*   multpm = (u16*)(big + 1 * RSZ);
    u16*   o2t    = (u16*)(big + 2 * RSZ);   // R3: o2t cm -> later uraw
    u16*   uraw   = (u16*)(big + 2 * RSZ);
    float* Abuf   = (float*)(big + 3 * RSZ); // R4: A fp32 staging -> later multcm
    u16*   multcm = (u16*)(big + 3 * RSZ);

    hipMemsetAsync(small, 0, 512 * 4, stream);
    hipMemsetAsync(Abuf, 0, (size_t)NN * 32 * 4, stream);

    cvt_weights<<<168, 256, 0, stream>>>((const float*)d_in[6], (const float*)d_in[8],
                                         (const float*)d_in[10], (const float*)d_in[12],
                                         (const float*)d_in[14], (const float*)d_in[16], arena);
    scatter_edges<<<2048, 256, 0, stream>>>(x, ei, Abuf);
    finalize_u0<<<1024, 256, 0, stream>>>(Abuf, u, total);
    trace_kernel<<<8, 256, 0, stream>>>(u, 32, trace);
    extractor_acc<<<1, 64, 0, stream>>>(trace, total, 32, np1w, np1b, np2w, np3w, oacc);

    for (int l = 0; l < 3; ++l) {
        int Cin = (l == 0) ? 32 : 64;
        const u16 *w1b, *w2b, *w4b;
        const float *b1, *b2, *b4;
        if (l == 0) {
            w1b = arena;            b1 = c0m1b;
            w2b = arena + 2048;     b2 = c0m2b;
            w4b = arena + 4096;     b4 = c0m4b;
        } else {
            int m = l - 1;
            w1b = arena + 10240 + m * 4096;  b1 = cm1b + m * 64;
            w2b = arena + 18432 + m * 4096;  b2 = cm2b + m * 64;
            w4b = arena + 26624 + m * 8192;  b4 = cm4b + m * 64;
        }
        conv_mfma<<<1024, 256, 0, stream>>>(u, Cin, (const u16*)nullptr, 0, w1b, b1, o1, 0);
        conv_mfma<<<1024, 256, 0, stream>>>(u, Cin, (const u16*)nullptr, 0, w2b, b2, o2t, 1);
        bmm_mfma<<<dim3(16, 64), 256, 0, stream>>>(o1, o2t, multcm);         // R2,R3 -> R4
        transpose_cm_pm<<<1024, 256, 0, stream>>>(multcm, multpm, nullptr, nullptr, 0); // R4 -> R2
        conv_mfma<<<1024, 256, 0, stream>>>(multpm, 64, u, Cin, w4b, b4, uraw, 0);      // R2,R1 -> R3
        row_stats<<<dim3(8, 64), 256, 0, stream>>>(uraw, spart, sqpart);
        trace_raw_cm<<<64, 256, 0, stream>>>(uraw, trraw);
        bn_finalize<<<1, 64, 0, stream>>>(spart, sqpart, trraw, bng + l * 64, bnb + l * 64,
                                          scl, shf, total, trace);
        transpose_cm_pm<<<1024, 256, 0, stream>>>(uraw, u, scl, shf, 1);     // R3 -> R1
        extractor_acc<<<1, 64, 0, stream>>>(trace, total, 64,
                                            fe1w + l * 4096, fe1b + l * 64,
                                            fe2w + l * 4096, fe3w + l * 4096, oacc);
    }
    head<<<1, 64, 0, stream>>>(oacc, acw, acb, flw, flb, out);
}

// Round 7
// 816.269 us; speedup vs baseline: 1.4096x; 1.0087x over previous
//
#include <hip/hip_runtime.h>
#include <hip/hip_bf16.h>

// Problem dims (fixed)
#define Nn   512
#define NN   262144        // N*N positions
#define EDG  16384

typedef unsigned short u16;
typedef short v8s __attribute__((ext_vector_type(8)));   // 8 bf16 lanes (4 VGPR)
typedef float v4f __attribute__((ext_vector_type(4)));
typedef u16 u16x8 __attribute__((ext_vector_type(8)));

__device__ __forceinline__ float b2f(u16 u) {
    union { unsigned int i; float f; } v; v.i = ((unsigned int)u) << 16; return v.f;
}
__device__ __forceinline__ u16 f2b(float f) {
    union { float f; unsigned int i; } v; v.f = f;
    unsigned int r = (v.i + 0x7FFFu + ((v.i >> 16) & 1u)) >> 16;
    return (u16)r;
}

// ---------------------------------------------------------------------------
__global__ void sentinel_kernel(float* __restrict__ out, float val) {
    if (threadIdx.x < 10) out[threadIdx.x] = val;
}

// ---------------------------------------------------------------------------
// K0: convert the 6 conv weight tensors (fp32) into one bf16 arena.
__global__ void cvt_weights(const float* __restrict__ s0, const float* __restrict__ s1,
                            const float* __restrict__ s2, const float* __restrict__ s3,
                            const float* __restrict__ s4, const float* __restrict__ s5,
                            u16* __restrict__ dst) {
    int t = blockIdx.x * 256 + threadIdx.x;
    if (t >= 43008) return;
    float v;
    if      (t < 2048)  v = s0[t];
    else if (t < 4096)  v = s1[t - 2048];
    else if (t < 10240) v = s2[t - 4096];
    else if (t < 18432) v = s3[t - 10240];
    else if (t < 26624) v = s4[t - 18432];
    else                v = s5[t - 26624];
    dst[t] = f2b(v);
}

// ---------------------------------------------------------------------------
// K1: scatter edges into A (fp32, pos-major [p][32]); x is fp32 [512][16]
__global__ void scatter_edges(const float* __restrict__ x, const int* __restrict__ ei,
                              float* __restrict__ A) {
    int t = blockIdx.x * 256 + threadIdx.x;
    if (t >= EDG * 32) return;
    int e = t >> 5, c = t & 31;
    int s = ei[e], d = ei[EDG + e];
    float v = (c < 16) ? x[s * 16 + c] : x[d * 16 + (c - 16)];
    atomicAdd(A + ((size_t)s * Nn + d) * 32 + c, v);
}

// ---------------------------------------------------------------------------
// K2: A fp32 pos-major [p][32] -> u0 CHANNEL-MAJOR bf16 [32][NN]; per-channel totals.
// LDS transpose epilogue -> full 512B row writes.
__global__ __launch_bounds__(256) void finalize_u0(const float* __restrict__ A,
                                                   u16* __restrict__ u0,
                                                   float* __restrict__ total) {
    __shared__ u16 L[32 * 258];
    __shared__ float red[4][32];
    int t = threadIdx.x;
    int p0 = blockIdx.x * 256;
    const float* Ar = A + (size_t)(p0 + t) * 32;
    float v[32];
#pragma unroll
    for (int c = 0; c < 32; ++c) v[c] = Ar[c];
#pragma unroll
    for (int c = 0; c < 32; ++c) L[c * 258 + t] = f2b(v[c]);
    int wv = t >> 6;
#pragma unroll
    for (int c = 0; c < 32; ++c) {
        float r = v[c];
        for (int off = 32; off > 0; off >>= 1) r += __shfl_down(r, off);
        if ((t & 63) == 0) red[wv][c] = r;
    }
    __syncthreads();
    if (t < 32) atomicAdd(total + t, red[0][t] + red[1][t] + red[2][t] + red[3][t]);
    int off = (t & 31) * 8, rb = t >> 5;
#pragma unroll
    for (int pass = 0; pass < 4; ++pass) {
        int c = pass * 8 + rb;
        u16x8 w = *(const u16x8*)(L + c * 258 + off);
        *(u16x8*)(u0 + (size_t)c * NN + p0 + off) = w;
    }
}

// ---------------------------------------------------------------------------
// K3: trace of channel-major activation; grid = C blocks (one per channel).
__global__ void trace_raw_cm(const u16* __restrict__ ucm, float* __restrict__ trraw) {
    int c = blockIdx.x, t = threadIdx.x;
    const u16* base = ucm + (size_t)c * NN;
    float s = b2f(base[(size_t)(2 * t) * 513]) + b2f(base[(size_t)(2 * t + 1) * 513]);
    for (int off = 32; off > 0; off >>= 1) s += __shfl_down(s, off);
    __shared__ float r[4];
    if ((t & 63) == 0) r[t >> 6] = s;
    __syncthreads();
    if (t == 0) trraw[c] = r[0] + r[1] + r[2] + r[3];
}

// ---------------------------------------------------------------------------
// K4: extractor MLP (fp32 weights), accumulate into out_acc[64]. 1 block, 64 threads.
__global__ void extractor_acc(const float* __restrict__ trace, const float* __restrict__ total,
                              int C, const float* __restrict__ w1, const float* __restrict__ b1,
                              const float* __restrict__ w2, const float* __restrict__ w3,
                              float* __restrict__ out_acc) {
    __shared__ float xo[64];
    int t = threadIdx.x;
    const float inv_n = 1.f / 512.f;
    const float inv_off = 1.f / (512.f * 511.f);
    float s1 = b1[t];
    for (int c = 0; c < C; ++c) s1 += (trace[c] * inv_n) * w1[t * C + c];
    float s2 = 0.f;
    for (int c = 0; c < C; ++c) s2 += ((total[c] - trace[c]) * inv_off) * w2[t * C + c];
    float o = s1 + s2;
    xo[t] = o;
    __syncthreads();
    float s3 = 0.f;
    for (int f = 0; f < 64; ++f) s3 += fmaxf(xo[f], 0.f) * w3[t * 64 + f];
    out_acc[t] += o + s3;
}

// ---------------------------------------------------------------------------
// K5 v3: 1x1 conv via MFMA, channel-major in AND out.
// dst[h][p] = sum_c w[h][c] * src_cat[c][p] (+affine on src rows) + bias[h]
// src_cat = concat(src0 [C0 rows], src1 [C1 rows]); affine sc/sh nullable per src.
// Block = 256 positions, all 64 h out. Staging: coalesced 512B cm-row reads ->
// LDS [64][258] (chunked over K, 64 ch/chunk). B-frags: conflict-free scalar
// LDS gathers. Epilogue: LDS transpose -> full 512B cm row writes.
__global__ __launch_bounds__(256) void conv_cm(const u16* __restrict__ src0, int C0,
                                               const float* __restrict__ sc0, const float* __restrict__ sh0,
                                               const u16* __restrict__ src1, int C1,
                                               const float* __restrict__ sc1, const float* __restrict__ sh1,
                                               const u16* __restrict__ w, const float* __restrict__ bias,
                                               u16* __restrict__ dst) {
    __shared__ u16 L[64 * 258];
    const int K = C0 + C1;
    const int t = threadIdx.x;
    const int p0 = blockIdx.x * 256;
    const int lane = t & 63, wave = t >> 6;
    const int l15 = lane & 15, quad = lane >> 4;
    const int pl = wave * 64;
    const int off = (t & 31) * 8;
    const int rb = t >> 5;

    const int nkk = K >> 5;
    v8s af[4][4];
    for (int kk = 0; kk < nkk; ++kk)
#pragma unroll
        for (int mt = 0; mt < 4; ++mt)
            af[mt][kk] = *reinterpret_cast<const v8s*>(w + (mt * 16 + l15) * K + kk * 32 + quad * 8);

    v4f acc[4][4];
#pragma unroll
    for (int mt = 0; mt < 4; ++mt)
#pragma unroll
        for (int nt = 0; nt < 4; ++nt) acc[mt][nt] = (v4f){0.f, 0.f, 0.f, 0.f};

    const int nchunk = (K + 63) >> 6;
    for (int kc = 0; kc < nchunk; ++kc) {
        const int cbase = kc * 64;
        const int rows = (K - cbase < 64) ? (K - cbase) : 64;
        for (int c = rb; c < rows; c += 8) {
            const int cg = cbase + c;
            const u16* gp; const float* scp; const float* shp; int ci;
            if (cg < C0) { ci = cg;      gp = src0 + (size_t)ci * NN + p0 + off; scp = sc0; shp = sh0; }
            else         { ci = cg - C0; gp = src1 + (size_t)ci * NN + p0 + off; scp = sc1; shp = sh1; }
            u16x8 v = *(const u16x8*)gp;
            if (scp) {
                const float s = scp[ci], f = shp[ci];
                u16x8 o;
#pragma unroll
                for (int j = 0; j < 8; ++j) o[j] = f2b(b2f(v[j]) * s + f);
                v = o;
            }
            *(u16x8*)(L + c * 258 + off) = v;
        }
        __syncthreads();
        const int nkl = rows >> 5;   // 1 or 2
#pragma unroll
        for (int nt = 0; nt < 4; ++nt) {
            const int p = pl + nt * 16 + l15;
            for (int kl = 0; kl < nkl; ++kl) {
                const int cg = kl * 32 + quad * 8;
                v8s b;
#pragma unroll
                for (int j = 0; j < 8; ++j) b[j] = (short)L[(cg + j) * 258 + p];
                const int kkg = kc * 2 + kl;
#pragma unroll
                for (int mt = 0; mt < 4; ++mt)
                    acc[mt][nt] = __builtin_amdgcn_mfma_f32_16x16x32_bf16(af[mt][kkg], b, acc[mt][nt], 0, 0, 0);
            }
        }
        __syncthreads();
    }

    // Epilogue: acc -> LDS [64 h][258] -> coalesced cm row writes
#pragma unroll
    for (int mt = 0; mt < 4; ++mt)
#pragma unroll
        for (int r = 0; r < 4; ++r) {
            const int h = mt * 16 + quad * 4 + r;
            const float bv = bias[h];
#pragma unroll
            for (int nt = 0; nt < 4; ++nt)
                L[h * 258 + pl + nt * 16 + l15] = f2b(acc[mt][nt][r] + bv);
        }
    __syncthreads();
#pragma unroll
    for (int cc = 0; cc < 8; ++cc) {
        const int h = cc * 8 + rb;
        u16x8 v = *(const u16x8*)(L + h * 258 + off);
        *(u16x8*)(dst + (size_t)h * NN + p0 + off) = v;
    }
}

// ---------------------------------------------------------------------------
// K7: batched per-channel GEMM, LDS-staged (unchanged from r6, proven).
__global__ __launch_bounds__(256) void bmm_mfma(const u16* __restrict__ Aall,
                                                const u16* __restrict__ Ball,
                                                u16* __restrict__ Call) {
    __shared__ u16 LA[128 * 72];
    __shared__ u16 LB[128 * 72];
    const int h = blockIdx.y;
    const int tx = blockIdx.x & 3, ty = blockIdx.x >> 2;
    const int t = threadIdx.x;
    const int lane = t & 63, wave = t >> 6;
    const int wr = wave >> 1, wc = wave & 1;
    const int l15 = lane & 15, quad = lane >> 4;
    const u16* Ap = Aall + (size_t)h * NN + (size_t)ty * 128 * 512;
    const u16* Bp = Ball + (size_t)h * NN + (size_t)tx * 128 * 512;

    const int srow = t >> 3;
    const int scol = (t & 7) * 8;

    v4f acc[4][4];
#pragma unroll
    for (int mt = 0; mt < 4; ++mt)
#pragma unroll
        for (int nt = 0; nt < 4; ++nt) acc[mt][nt] = (v4f){0.f, 0.f, 0.f, 0.f};

    v8s ra[4], rb[4];
#pragma unroll
    for (int i = 0; i < 4; ++i) {
        int row = i * 32 + srow;
        ra[i] = *(const v8s*)(Ap + (size_t)row * 512 + scol);
        rb[i] = *(const v8s*)(Bp + (size_t)row * 512 + scol);
    }

    for (int ck = 0; ck < 8; ++ck) {
#pragma unroll
        for (int i = 0; i < 4; ++i) {
            int row = i * 32 + srow;
            *(v8s*)(LA + row * 72 + scol) = ra[i];
            *(v8s*)(LB + row * 72 + scol) = rb[i];
        }
        __syncthreads();
        if (ck < 7) {
            const int k0 = (ck + 1) * 64;
#pragma unroll
            for (int i = 0; i < 4; ++i) {
                int row = i * 32 + srow;
                ra[i] = *(const v8s*)(Ap + (size_t)row * 512 + k0 + scol);
                rb[i] = *(const v8s*)(Bp + (size_t)row * 512 + k0 + scol);
            }
        }
#pragma unroll
        for (int kk = 0; kk < 2; ++kk) {
            v8s a[4], b[4];
#pragma unroll
            for (int mt = 0; mt < 4; ++mt)
                a[mt] = *(const v8s*)(LA + (wr * 64 + mt * 16 + l15) * 72 + kk * 32 + quad * 8);
#pragma unroll
            for (int nt = 0; nt < 4; ++nt)
                b[nt] = *(const v8s*)(LB + (wc * 64 + nt * 16 + l15) * 72 + kk * 32 + quad * 8);
#pragma unroll
            for (int mt = 0; mt < 4; ++mt)
#pragma unroll
                for (int nt = 0; nt < 4; ++nt)
                    acc[mt][nt] = __builtin_amdgcn_mfma_f32_16x16x32_bf16(a[mt], b[nt], acc[mt][nt], 0, 0, 0);
        }
        __syncthreads();
    }

    u16* Cp = Call + (size_t)h * NN;
#pragma unroll
    for (int mt = 0; mt < 4; ++mt)
#pragma unroll
        for (int r = 0; r < 4; ++r) {
            const int i = ty * 128 + wr * 64 + mt * 16 + quad * 4 + r;
#pragma unroll
            for (int nt = 0; nt < 4; ++nt) {
                const int j = tx * 128 + wc * 64 + nt * 16 + l15;
                Cp[i * 512 + j] = f2b(acc[mt][nt][r]);
            }
        }
}

// ---------------------------------------------------------------------------
// K8 v3: per-channel 512x512 position transpose within cm, optional affine.
// dst[ch][j*512+i] = aff(src[ch][i*512+j]). 64x64 tiles; both sides coalesced.
__global__ __launch_bounds__(256) void transpose_T(const u16* __restrict__ src,
                                                   u16* __restrict__ dst,
                                                   const float* __restrict__ scale,
                                                   const float* __restrict__ shift) {
    __shared__ u16 L[64 * 66];
    const int ch = blockIdx.y;
    const int ti = blockIdx.x & 7, tj = blockIdx.x >> 3;
    const int i0 = ti * 64, j0 = tj * 64;
    const int t = threadIdx.x;
    float s = 1.f, f = 0.f;
    if (scale) { s = scale[ch]; f = shift[ch]; }
    const size_t cb = (size_t)ch * NN;
    {
        int i = t >> 2, o = (t & 3) * 16;
        const u16* gp = src + cb + (size_t)(i0 + i) * 512 + j0 + o;
        u16x8 a = *(const u16x8*)gp;
        u16x8 b = *(const u16x8*)(gp + 8);
        if (scale) {
#pragma unroll
            for (int j = 0; j < 8; ++j) { a[j] = f2b(b2f(a[j]) * s + f); b[j] = f2b(b2f(b[j]) * s + f); }
        }
        *(u16x8*)(L + i * 66 + o) = a;
        *(u16x8*)(L + i * 66 + o + 8) = b;
    }
    __syncthreads();
    {
        int j = t >> 2, o = (t & 3) * 16;
        u16 v[16];
#pragma unroll
        for (int k = 0; k < 16; ++k) v[k] = L[(o + k) * 66 + j];
        u16* gp = dst + cb + (size_t)(j0 + j) * 512 + i0 + o;
        u16x8 v0 = { v[0], v[1], v[2], v[3], v[4], v[5], v[6], v[7] };
        u16x8 v1 = { v[8], v[9], v[10], v[11], v[12], v[13], v[14], v[15] };
        *(u16x8*)(gp) = v0;
        *(u16x8*)(gp + 8) = v1;
    }
}

// ---------------------------------------------------------------------------
// K9: per-channel sum/sumsq partials (no atomics): sp[c*8+bx], sqp[c*8+bx]
__global__ __launch_bounds__(256) void row_stats(const u16* __restrict__ src,
                                                 float* __restrict__ sp, float* __restrict__ sqp) {
    int c = blockIdx.y, t = threadIdx.x;
    size_t base = (size_t)c * NN + (size_t)blockIdx.x * 32768;
    float s = 0.f, s2 = 0.f;
    for (int i = 0; i < 32; ++i) {
        ushort4 w = *(const ushort4*)(src + base + (size_t)i * 1024 + t * 4);
        float a0 = b2f(w.x), a1 = b2f(w.y), a2 = b2f(w.z), a3 = b2f(w.w);
        s += a0 + a1 + a2 + a3;
        s2 += a0 * a0 + a1 * a1 + a2 * a2 + a3 * a3;
    }
    for (int off = 32; off > 0; off >>= 1) { s += __shfl_down(s, off); s2 += __shfl_down(s2, off); }
    __shared__ float r1[4], r2[4];
    if ((t & 63) == 0) { r1[t >> 6] = s; r2[t >> 6] = s2; }
    __syncthreads();
    if (t == 0) {
        sp[c * 8 + blockIdx.x]  = r1[0] + r1[1] + r1[2] + r1[3];
        sqp[c * 8 + blockIdx.x] = r2[0] + r2[1] + r2[2] + r2[3];
    }
}

// ---------------------------------------------------------------------------
// K11: BN scale/shift from partial stats; analytic normalized totals & trace.
__global__ void bn_finalize(const float* __restrict__ sp, const float* __restrict__ sqp,
                            const float* __restrict__ trraw,
                            const float* __restrict__ g, const float* __restrict__ b,
                            float* __restrict__ scale, float* __restrict__ shift,
                            float* __restrict__ total, float* __restrict__ trace) {
    int t = threadIdx.x;   // 64
    float s = 0.f, q = 0.f;
#pragma unroll
    for (int i = 0; i < 8; ++i) { s += sp[t * 8 + i]; q += sqp[t * 8 + i]; }
    float mean = s * (1.f / 262144.f);
    float var = q * (1.f / 262144.f) - mean * mean;
    float sc = g[t] * rsqrtf(fmaxf(var, 0.f) + 1e-5f);
    float sh = b[t] - mean * sc;
    scale[t] = sc;
    shift[t] = sh;
    total[t] = sc * s + 262144.f * sh;
    trace[t] = sc * trraw[t] + 512.f * sh;
}

// ---------------------------------------------------------------------------
// K12: head (fp32 weights/out)
__global__ void head(const float* __restrict__ out_acc, const float* __restrict__ acw,
                     const float* __restrict__ acb, const float* __restrict__ flw,
                     const float* __restrict__ flb, float* __restrict__ out) {
    __shared__ float x[64], x2[64], l[10];
    int t = threadIdx.x;  // 64
    x[t] = fmaxf(out_acc[t], 0.f) * (1.f / 3.f);
    __syncthreads();
    float y = acb[t];
    for (int f = 0; f < 64; ++f) y += x[f] * acw[t * 64 + f];
    x2[t] = x[t] + fmaxf(y, 0.f);
    __syncthreads();
    if (t < 10) {
        float s = flb[t];
        for (int f = 0; f < 64; ++f) s += x2[f] * flw[t * 64 + f];
        l[t] = s;
    }
    __syncthreads();
    if (t == 0) {
        float m = l[0];
        for (int i = 1; i < 10; ++i) m = fmaxf(m, l[i]);
        float se = 0.f;
        for (int i = 0; i < 10; ++i) se += expf(l[i] - m);
        float ls = m + logf(se);
        for (int i = 0; i < 10; ++i) out[i] = l[i] - ls;
    }
}

// ---------------------------------------------------------------------------
extern "C" void kernel_launch(void* const* d_in, const int* in_sizes, int n_in,
                              void* d_out, int out_size, void* d_ws, size_t ws_size,
                              hipStream_t stream) {
    float* out = (float*)d_out;

    static const int exp_sizes[28] = {
        8192, 32768,
        2048, 64, 2048, 4096,
        2048, 64, 2048, 64, 6144, 64,
        8192, 128, 8192, 128, 16384, 128,
        192, 192,
        12288, 192, 12288, 12288,
        4096, 64, 640, 10
    };
    bool ok = (n_in == 28);
    if (ok) for (int i = 0; i < 28; ++i) if (in_sizes[i] != exp_sizes[i]) ok = false;
    if (!ok) { sentinel_kernel<<<1, 64, 0, stream>>>(out, -5.0f); return; }

    const size_t RSZ = (size_t)NN * 64 * 2;            // 33.55 MB per region
    const size_t BIG_OFF = 8192 + 90112;               // control (8KB) + bf16 weight arena
    if (ws_size < BIG_OFF + 4 * RSZ) {
        sentinel_kernel<<<1, 64, 0, stream>>>(out, -7.0f);
        return;
    }

    const float* x     = (const float*)d_in[0];
    const int*   ei    = (const int*)d_in[1];
    const float* np1w  = (const float*)d_in[2];
    const float* np1b  = (const float*)d_in[3];
    const float* np2w  = (const float*)d_in[4];
    const float* np3w  = (const float*)d_in[5];
    const float* c0m1b = (const float*)d_in[7];
    const float* c0m2b = (const float*)d_in[9];
    const float* c0m4b = (const float*)d_in[11];
    const float* cm1b  = (const float*)d_in[13];
    const float* cm2b  = (const float*)d_in[15];
    const float* cm4b  = (const float*)d_in[17];
    const float* bng   = (const float*)d_in[18];
    const float* bnb   = (const float*)d_in[19];
    const float* fe1w  = (const float*)d_in[20];
    const float* fe1b  = (const float*)d_in[21];
    const float* fe2w  = (const float*)d_in[22];
    const float* fe3w  = (const float*)d_in[23];
    const float* acw   = (const float*)d_in[24];
    const float* acb   = (const float*)d_in[25];
    const float* flw   = (const float*)d_in[26];
    const float* flb   = (const float*)d_in[27];

    char* ws = (char*)d_ws;
    float* small = (float*)ws;
    float* scl   = small + 128;
    float* shf   = small + 192;
    float* trace = small + 256;
    float* total = small + 320;
    float* oacc  = small + 384;
    float* trraw = small + 448;
    float* spart = small + 512;    // 512 floats
    float* sqpart= small + 1024;   // 512 floats

    u16* arena = (u16*)(ws + 8192);          // bf16 conv weights, 43008 elements

    char* big = ws + BIG_OFF;
    u16* S0 = (u16*)(big + 0 * RSZ);
    u16* S1 = (u16*)(big + 1 * RSZ);
    u16* S2 = (u16*)(big + 2 * RSZ);
    u16* S3 = (u16*)(big + 3 * RSZ);
    float* Abuf = (float*)S2;                // fp32 staging, dead after finalize

    hipMemsetAsync(small, 0, 512 * 4, stream);
    hipMemsetAsync(Abuf, 0, (size_t)NN * 32 * 4, stream);

    cvt_weights<<<168, 256, 0, stream>>>((const float*)d_in[6], (const float*)d_in[8],
                                         (const float*)d_in[10], (const float*)d_in[12],
                                         (const float*)d_in[14], (const float*)d_in[16], arena);
    scatter_edges<<<2048, 256, 0, stream>>>(x, ei, Abuf);
    finalize_u0<<<1024, 256, 0, stream>>>(Abuf, S0, total);          // u0 cm -> S0
    transpose_T<<<dim3(64, 32), 256, 0, stream>>>(S0, S1, nullptr, nullptr);  // u0T -> S1
    trace_raw_cm<<<32, 256, 0, stream>>>(S0, trraw);
    extractor_acc<<<1, 64, 0, stream>>>(trraw, total, 32, np1w, np1b, np2w, np3w, oacc);

    // slot schedule per layer: {u, uT, o1dst, o2dst, multdst, urawdst, uTdst}
    u16* U[3]  = { S0, S2, S1 };
    u16* UT[3] = { S1, S3, S0 };
    u16* O1[3] = { S2, S0, S2 };
    u16* O2[3] = { S3, S1, S3 };
    u16* MU[3] = { S1, S3, S0 };   // bmm dst = uT slot (dead after conv2)
    u16* UR[3] = { S2, S1, S2 };   // conv4 dst = o1 or o2 slot (dead)
    u16* UTn[3]= { S3, S0, nullptr };

    const float *aff_s = nullptr, *aff_h = nullptr;  // affine for current u (prev layer BN)

    for (int l = 0; l < 3; ++l) {
        int Cin = (l == 0) ? 32 : 64;
        const u16 *w1b, *w2b, *w4b;
        const float *b1, *b2, *b4;
        if (l == 0) {
            w1b = arena;            b1 = c0m1b;
            w2b = arena + 2048;     b2 = c0m2b;
            w4b = arena + 4096;     b4 = c0m4b;
        } else {
            int m = l - 1;
            w1b = arena + 10240 + m * 4096;  b1 = cm1b + m * 64;
            w2b = arena + 18432 + m * 4096;  b2 = cm2b + m * 64;
            w4b = arena + 26624 + m * 8192;  b4 = cm4b + m * 64;
        }
        // conv1: u (aff) -> o1 cm
        conv_cm<<<1024, 256, 0, stream>>>(U[l], Cin, aff_s, aff_h,
                                          (const u16*)nullptr, 0, nullptr, nullptr,
                                          w1b, b1, O1[l]);
        // conv2: uT (already normalized) -> o2t cm
        conv_cm<<<1024, 256, 0, stream>>>(UT[l], Cin, nullptr, nullptr,
                                          (const u16*)nullptr, 0, nullptr, nullptr,
                                          w2b, b2, O2[l]);
        bmm_mfma<<<dim3(16, 64), 256, 0, stream>>>(O1[l], O2[l], MU[l]);
        // conv4: concat(mult [64, no aff], u [Cin, aff]) -> uraw cm
        conv_cm<<<1024, 256, 0, stream>>>(MU[l], 64, nullptr, nullptr,
                                          U[l], Cin, aff_s, aff_h,
                                          w4b, b4, UR[l]);
        row_stats<<<dim3(8, 64), 256, 0, stream>>>(UR[l], spart, sqpart);
        trace_raw_cm<<<64, 256, 0, stream>>>(UR[l], trraw);
        bn_finalize<<<1, 64, 0, stream>>>(spart, sqpart, trraw, bng + l * 64, bnb + l * 64,
                                          scl, shf, total, trace);
        if (l < 2)
            transpose_T<<<dim3(64, 64), 256, 0, stream>>>(UR[l], UTn[l], scl, shf);
        extractor_acc<<<1, 64, 0, stream>>>(trace, total, 64,
                                            fe1w + l * 4096, fe1b + l * 64,
                                            fe2w + l * 4096, fe3w + l * 4096, oacc);
        aff_s = scl; aff_h = shf;   // next layer's u = this layer's uraw + affine
    }
    head<<<1, 64, 0, stream>>>(oacc, acw, acb, flw, flb, out);
}

// Round 8
// 616.758 us; speedup vs baseline: 1.8656x; 1.3235x over previous
//
#include <hip/hip_runtime.h>
#include <hip/hip_bf16.h>

// Problem dims (fixed)
#define Nn   512
#define NN   262144        // N*N positions
#define EDG  16384

typedef unsigned short u16;
typedef short v8s __attribute__((ext_vector_type(8)));   // 8 bf16 lanes (4 VGPR)
typedef float v4f __attribute__((ext_vector_type(4)));
typedef u16 u16x8 __attribute__((ext_vector_type(8)));

__device__ __forceinline__ float b2f(u16 u) {
    union { unsigned int i; float f; } v; v.i = ((unsigned int)u) << 16; return v.f;
}
__device__ __forceinline__ u16 f2b(float f) {
    union { float f; unsigned int i; } v; v.f = f;
    unsigned int r = (v.i + 0x7FFFu + ((v.i >> 16) & 1u)) >> 16;
    return (u16)r;
}

// ---------------------------------------------------------------------------
__global__ void sentinel_kernel(float* __restrict__ out, float val) {
    if (threadIdx.x < 10) out[threadIdx.x] = val;
}

// ---------------------------------------------------------------------------
// K0: convert the 6 conv weight tensors (fp32) into one bf16 arena.
__global__ void cvt_weights(const float* __restrict__ s0, const float* __restrict__ s1,
                            const float* __restrict__ s2, const float* __restrict__ s3,
                            const float* __restrict__ s4, const float* __restrict__ s5,
                            u16* __restrict__ dst) {
    int t = blockIdx.x * 256 + threadIdx.x;
    if (t >= 43008) return;
    float v;
    if      (t < 2048)  v = s0[t];
    else if (t < 4096)  v = s1[t - 2048];
    else if (t < 10240) v = s2[t - 4096];
    else if (t < 18432) v = s3[t - 10240];
    else if (t < 26624) v = s4[t - 18432];
    else                v = s5[t - 26624];
    dst[t] = f2b(v);
}

// ---------------------------------------------------------------------------
// K1: scatter edges into A (fp32, pos-major [p][32]); x is fp32 [512][16]
__global__ void scatter_edges(const float* __restrict__ x, const int* __restrict__ ei,
                              float* __restrict__ A) {
    int t = blockIdx.x * 256 + threadIdx.x;
    if (t >= EDG * 32) return;
    int e = t >> 5, c = t & 31;
    int s = ei[e], d = ei[EDG + e];
    float v = (c < 16) ? x[s * 16 + c] : x[d * 16 + (c - 16)];
    atomicAdd(A + ((size_t)s * Nn + d) * 32 + c, v);
}

// ---------------------------------------------------------------------------
// K2: A fp32 pos-major [p][32] -> u0 CHANNEL-MAJOR bf16 [32][NN]; per-channel totals.
__global__ __launch_bounds__(256) void finalize_u0(const float* __restrict__ A,
                                                   u16* __restrict__ u0,
                                                   float* __restrict__ total) {
    __shared__ u16 L[32 * 258];
    __shared__ float red[4][32];
    int t = threadIdx.x;
    int p0 = blockIdx.x * 256;
    const float* Ar = A + (size_t)(p0 + t) * 32;
    float v[32];
#pragma unroll
    for (int c = 0; c < 32; ++c) v[c] = Ar[c];
#pragma unroll
    for (int c = 0; c < 32; ++c) L[c * 258 + t] = f2b(v[c]);
    int wv = t >> 6;
#pragma unroll
    for (int c = 0; c < 32; ++c) {
        float r = v[c];
        for (int off = 32; off > 0; off >>= 1) r += __shfl_down(r, off);
        if ((t & 63) == 0) red[wv][c] = r;
    }
    __syncthreads();
    if (t < 32) atomicAdd(total + t, red[0][t] + red[1][t] + red[2][t] + red[3][t]);
    int off = (t & 31) * 8, rb = t >> 5;
#pragma unroll
    for (int pass = 0; pass < 4; ++pass) {
        int c = pass * 8 + rb;
        u16x8 w = *(const u16x8*)(L + c * 258 + off);
        *(u16x8*)(u0 + (size_t)c * NN + p0 + off) = w;
    }
}

// ---------------------------------------------------------------------------
// K3: trace of channel-major activation (plain store); grid = C blocks.
__global__ void trace_raw_cm(const u16* __restrict__ ucm, float* __restrict__ trraw) {
    int c = blockIdx.x, t = threadIdx.x;
    const u16* base = ucm + (size_t)c * NN;
    float s = b2f(base[(size_t)(2 * t) * 513]) + b2f(base[(size_t)(2 * t + 1) * 513]);
    for (int off = 32; off > 0; off >>= 1) s += __shfl_down(s, off);
    __shared__ float r[4];
    if ((t & 63) == 0) r[t >> 6] = s;
    __syncthreads();
    if (t == 0) trraw[c] = r[0] + r[1] + r[2] + r[3];
}

// ---------------------------------------------------------------------------
// K4: extractor MLP (fp32 weights), accumulate into out_acc[64]. 1 block, 64 threads.
__global__ void extractor_acc(const float* __restrict__ trace, const float* __restrict__ total,
                              int C, const float* __restrict__ w1, const float* __restrict__ b1,
                              const float* __restrict__ w2, const float* __restrict__ w3,
                              float* __restrict__ out_acc) {
    __shared__ float xo[64];
    int t = threadIdx.x;
    const float inv_n = 1.f / 512.f;
    const float inv_off = 1.f / (512.f * 511.f);
    float s1 = b1[t];
    for (int c = 0; c < C; ++c) s1 += (trace[c] * inv_n) * w1[t * C + c];
    float s2 = 0.f;
    for (int c = 0; c < C; ++c) s2 += ((total[c] - trace[c]) * inv_off) * w2[t * C + c];
    float o = s1 + s2;
    xo[t] = o;
    __syncthreads();
    float s3 = 0.f;
    for (int f = 0; f < 64; ++f) s3 += fmaxf(xo[f], 0.f) * w3[t * 64 + f];
    out_acc[t] += o + s3;
}

// ---------------------------------------------------------------------------
// K5: merged conv1+conv2. src cm [C][NN] (+optional affine), two weight sets,
// two cm outputs. Block = 128 positions; double-buffered 32-ch chunks.
__global__ __launch_bounds__(256) void conv12(
    const u16* __restrict__ src, int C,
    const float* __restrict__ sc, const float* __restrict__ sh,
    const u16* __restrict__ w1, const float* __restrict__ b1,
    const u16* __restrict__ w2, const float* __restrict__ b2,
    u16* __restrict__ dst1, u16* __restrict__ dst2)
{
    __shared__ u16 LS[8320];   // 2 x [32][130] chunk bufs == [64][130] epilogue
    const int t = threadIdx.x;
    const int P0 = blockIdx.x * 128;
    const int lane = t & 63, wave = t >> 6;
    const int l15 = lane & 15, quad = lane >> 4;
    const int pw = wave * 32;
    const int sr = t >> 4;          // 0..15
    const int so = (t & 15) * 8;
    const int nchunk = C >> 5;

    v4f acc[2][4][2];
#pragma unroll
    for (int s = 0; s < 2; ++s)
#pragma unroll
        for (int mt = 0; mt < 4; ++mt)
#pragma unroll
            for (int nt = 0; nt < 2; ++nt) acc[s][mt][nt] = (v4f){0.f, 0.f, 0.f, 0.f};

    u16x8 pf[2];
#pragma unroll
    for (int ps = 0; ps < 2; ++ps)
        pf[ps] = *(const u16x8*)(src + (size_t)(ps * 16 + sr) * NN + P0 + so);
#pragma unroll
    for (int ps = 0; ps < 2; ++ps) {
        int c = ps * 16 + sr;
        u16x8 v = pf[ps];
        if (sc) {
            float s = sc[c], f = sh[c];
#pragma unroll
            for (int j = 0; j < 8; ++j) v[j] = f2b(b2f(v[j]) * s + f);
        }
        *(u16x8*)(LS + c * 130 + so) = v;
    }
    __syncthreads();
    for (int kc = 0; kc < nchunk; ++kc) {
        if (kc + 1 < nchunk) {
#pragma unroll
            for (int ps = 0; ps < 2; ++ps)
                pf[ps] = *(const u16x8*)(src + (size_t)((kc + 1) * 32 + ps * 16 + sr) * NN + P0 + so);
        }
        v8s af1[4], af2[4];
#pragma unroll
        for (int mt = 0; mt < 4; ++mt) {
            af1[mt] = *(const v8s*)(w1 + (mt * 16 + l15) * C + kc * 32 + quad * 8);
            af2[mt] = *(const v8s*)(w2 + (mt * 16 + l15) * C + kc * 32 + quad * 8);
        }
        const u16* Lb = LS + (kc & 1) * 4160;
#pragma unroll
        for (int nt = 0; nt < 2; ++nt) {
            const int p = pw + nt * 16 + l15;
            v8s b;
#pragma unroll
            for (int j = 0; j < 8; ++j) b[j] = (short)Lb[(quad * 8 + j) * 130 + p];
#pragma unroll
            for (int mt = 0; mt < 4; ++mt) {
                acc[0][mt][nt] = __builtin_amdgcn_mfma_f32_16x16x32_bf16(af1[mt], b, acc[0][mt][nt], 0, 0, 0);
                acc[1][mt][nt] = __builtin_amdgcn_mfma_f32_16x16x32_bf16(af2[mt], b, acc[1][mt][nt], 0, 0, 0);
            }
        }
        if (kc + 1 < nchunk) {
            u16* Ln = LS + ((kc + 1) & 1) * 4160;
#pragma unroll
            for (int ps = 0; ps < 2; ++ps) {
                int c = ps * 16 + sr;
                int cg = (kc + 1) * 32 + c;
                u16x8 v = pf[ps];
                if (sc) {
                    float s = sc[cg], f = sh[cg];
#pragma unroll
                    for (int j = 0; j < 8; ++j) v[j] = f2b(b2f(v[j]) * s + f);
                }
                *(u16x8*)(Ln + c * 130 + so) = v;
            }
            __syncthreads();
        }
    }
#pragma unroll
    for (int s = 0; s < 2; ++s) {
        __syncthreads();
        const float* bb = s ? b2 : b1;
#pragma unroll
        for (int mt = 0; mt < 4; ++mt)
#pragma unroll
            for (int r = 0; r < 4; ++r) {
                const int h = mt * 16 + quad * 4 + r;
                const float bv = bb[h];
#pragma unroll
                for (int nt = 0; nt < 2; ++nt)
                    LS[h * 130 + pw + nt * 16 + l15] = f2b(acc[s][mt][nt][r] + bv);
            }
        __syncthreads();
        u16* dd = s ? dst2 : dst1;
#pragma unroll
        for (int ps = 0; ps < 4; ++ps) {
            int h = ps * 16 + sr;
            u16x8 v = *(const u16x8*)(LS + h * 130 + so);
            __builtin_nontemporal_store(v, (u16x8*)(dd + (size_t)h * NN + P0 + so));
        }
    }
}

// ---------------------------------------------------------------------------
// K6: m4 conv: concat(mult[64], u[C] w/affine) -> uraw cm, FUSED BN stats + trace.
__global__ __launch_bounds__(256) void conv4(
    const u16* __restrict__ mult, const u16* __restrict__ u, int C,
    const float* __restrict__ sc, const float* __restrict__ sh,
    const u16* __restrict__ w, const float* __restrict__ bias,
    u16* __restrict__ dst,
    float* __restrict__ gsum, float* __restrict__ gsq, float* __restrict__ gtr)
{
    __shared__ u16 LS[8320];
    __shared__ float R1[64][4], R2[64][4];
    const int t = threadIdx.x;
    const int P0 = blockIdx.x * 128;
    const int lane = t & 63, wave = t >> 6;
    const int l15 = lane & 15, quad = lane >> 4;
    const int pw = wave * 32;
    const int sr = t >> 4;
    const int so = (t & 15) * 8;
    const int K = 64 + C;
    const int nchunk = K >> 5;

    v4f acc[4][2];
#pragma unroll
    for (int mt = 0; mt < 4; ++mt)
#pragma unroll
        for (int nt = 0; nt < 2; ++nt) acc[mt][nt] = (v4f){0.f, 0.f, 0.f, 0.f};

    u16x8 pf[2];
#pragma unroll
    for (int ps = 0; ps < 2; ++ps) {
        int cg = ps * 16 + sr;      // chunk 0 is always mult rows
        pf[ps] = *(const u16x8*)(mult + (size_t)cg * NN + P0 + so);
    }
#pragma unroll
    for (int ps = 0; ps < 2; ++ps)
        *(u16x8*)(LS + (ps * 16 + sr) * 130 + so) = pf[ps];
    __syncthreads();
    for (int kc = 0; kc < nchunk; ++kc) {
        if (kc + 1 < nchunk) {
#pragma unroll
            for (int ps = 0; ps < 2; ++ps) {
                int cg = (kc + 1) * 32 + ps * 16 + sr;
                const u16* gp = (cg < 64) ? (mult + (size_t)cg * NN + P0 + so)
                                          : (u + (size_t)(cg - 64) * NN + P0 + so);
                pf[ps] = *(const u16x8*)gp;
            }
        }
        v8s af[4];
#pragma unroll
        for (int mt = 0; mt < 4; ++mt)
            af[mt] = *(const v8s*)(w + (mt * 16 + l15) * K + kc * 32 + quad * 8);
        const u16* Lb = LS + (kc & 1) * 4160;
#pragma unroll
        for (int nt = 0; nt < 2; ++nt) {
            const int p = pw + nt * 16 + l15;
            v8s b;
#pragma unroll
            for (int j = 0; j < 8; ++j) b[j] = (short)Lb[(quad * 8 + j) * 130 + p];
#pragma unroll
            for (int mt = 0; mt < 4; ++mt)
                acc[mt][nt] = __builtin_amdgcn_mfma_f32_16x16x32_bf16(af[mt], b, acc[mt][nt], 0, 0, 0);
        }
        if (kc + 1 < nchunk) {
            u16* Ln = LS + ((kc + 1) & 1) * 4160;
#pragma unroll
            for (int ps = 0; ps < 2; ++ps) {
                int c = ps * 16 + sr;
                int cg = (kc + 1) * 32 + c;
                u16x8 v = pf[ps];
                if (cg >= 64 && sc) {
                    float s = sc[cg - 64], f = sh[cg - 64];
#pragma unroll
                    for (int j = 0; j < 8; ++j) v[j] = f2b(b2f(v[j]) * s + f);
                }
                *(u16x8*)(Ln + c * 130 + so) = v;
            }
            __syncthreads();
        }
    }
    __syncthreads();
#pragma unroll
    for (int mt = 0; mt < 4; ++mt)
#pragma unroll
        for (int r = 0; r < 4; ++r) {
            const int h = mt * 16 + quad * 4 + r;
            const float bv = bias[h];
#pragma unroll
            for (int nt = 0; nt < 2; ++nt)
                LS[h * 130 + pw + nt * 16 + l15] = f2b(acc[mt][nt][r] + bv);
        }
    __syncthreads();
    {   // fused stats partials
        int c = t >> 2, q = t & 3;
        const u16* row = LS + c * 130 + q * 32;
        float s = 0.f, s2 = 0.f;
#pragma unroll
        for (int i = 0; i < 32; ++i) { float v = b2f(row[i]); s += v; s2 += v * v; }
        R1[c][q] = s; R2[c][q] = s2;
    }
    __syncthreads();
    {
        int i = P0 >> 9, j0 = P0 & 511;
        if (t < 64) {
            atomicAdd(gsum + t, R1[t][0] + R1[t][1] + R1[t][2] + R1[t][3]);
            atomicAdd(gsq + t, R2[t][0] + R2[t][1] + R2[t][2] + R2[t][3]);
            if (j0 <= i && i < j0 + 128) atomicAdd(gtr + t, b2f(LS[t * 130 + (i - j0)]));
        }
    }
#pragma unroll
    for (int ps = 0; ps < 4; ++ps) {
        int h = ps * 16 + sr;
        u16x8 v = *(const u16x8*)(LS + h * 130 + so);
        __builtin_nontemporal_store(v, (u16x8*)(dst + (size_t)h * NN + P0 + so));
    }
}

// ---------------------------------------------------------------------------
// K7: batched per-channel GEMM, B taken in NATURAL cm layout [k][j].
// mult[h][i][j] = sum_k o1[h][i*512+k] * o2[h][k*512+j].
__global__ __launch_bounds__(256) void bmm_mfma(const u16* __restrict__ Aall,
                                                const u16* __restrict__ Ball,
                                                u16* __restrict__ Call) {
    __shared__ u16 LA[128 * 72];
    __shared__ u16 LB[64 * 130];
    const int h = blockIdx.y;
    const int tx = blockIdx.x & 3, ty = blockIdx.x >> 2;
    const int t = threadIdx.x;
    const int lane = t & 63, wave = t >> 6;
    const int wr = wave >> 1, wc = wave & 1;
    const int l15 = lane & 15, quad = lane >> 4;
    const u16* Ap = Aall + (size_t)h * NN + (size_t)ty * 128 * 512;
    const u16* Bp = Ball + (size_t)h * NN + tx * 128;

    const int srow = t >> 3;          // A: 0..31
    const int scol = (t & 7) * 8;
    const int bkr = t >> 4;           // B: 0..15
    const int bjg = (t & 15) * 8;

    v4f acc[4][4];
#pragma unroll
    for (int mt = 0; mt < 4; ++mt)
#pragma unroll
        for (int nt = 0; nt < 4; ++nt) acc[mt][nt] = (v4f){0.f, 0.f, 0.f, 0.f};

    v8s ra[4], rb[4];
#pragma unroll
    for (int i = 0; i < 4; ++i) {
        ra[i] = *(const v8s*)(Ap + (size_t)(i * 32 + srow) * 512 + scol);
        rb[i] = *(const v8s*)(Bp + (size_t)(i * 16 + bkr) * 512 + bjg);
    }

    for (int ck = 0; ck < 8; ++ck) {
#pragma unroll
        for (int i = 0; i < 4; ++i) {
            *(v8s*)(LA + (i * 32 + srow) * 72 + scol) = ra[i];
            *(v8s*)(LB + (i * 16 + bkr) * 130 + bjg) = rb[i];
        }
        __syncthreads();
        if (ck < 7) {
            const int k0 = (ck + 1) * 64;
#pragma unroll
            for (int i = 0; i < 4; ++i) {
                ra[i] = *(const v8s*)(Ap + (size_t)(i * 32 + srow) * 512 + k0 + scol);
                rb[i] = *(const v8s*)(Bp + (size_t)(k0 + i * 16 + bkr) * 512 + bjg);
            }
        }
#pragma unroll
        for (int kk = 0; kk < 2; ++kk) {
            v8s a[4], b[4];
#pragma unroll
            for (int mt = 0; mt < 4; ++mt)
                a[mt] = *(const v8s*)(LA + (wr * 64 + mt * 16 + l15) * 72 + kk * 32 + quad * 8);
#pragma unroll
            for (int nt = 0; nt < 4; ++nt) {
                const int j = wc * 64 + nt * 16 + l15;
#pragma unroll
                for (int jj = 0; jj < 8; ++jj)
                    b[nt][jj] = (short)LB[(kk * 32 + quad * 8 + jj) * 130 + j];
            }
#pragma unroll
            for (int mt = 0; mt < 4; ++mt)
#pragma unroll
                for (int nt = 0; nt < 4; ++nt)
                    acc[mt][nt] = __builtin_amdgcn_mfma_f32_16x16x32_bf16(a[mt], b[nt], acc[mt][nt], 0, 0, 0);
        }
        __syncthreads();
    }

    u16* Cp = Call + (size_t)h * NN;
#pragma unroll
    for (int mt = 0; mt < 4; ++mt)
#pragma unroll
        for (int r = 0; r < 4; ++r) {
            const int i = ty * 128 + wr * 64 + mt * 16 + quad * 4 + r;
#pragma unroll
            for (int nt = 0; nt < 4; ++nt) {
                const int j = tx * 128 + wc * 64 + nt * 16 + l15;
                Cp[i * 512 + j] = f2b(acc[mt][nt][r]);
            }
        }
}

// ---------------------------------------------------------------------------
// K11: BN scale/shift from fused raw stats; analytic normalized totals & trace;
// zeroes the accumulators for the next layer.
__global__ void bn_finalize(float* __restrict__ gsum, float* __restrict__ gsq,
                            float* __restrict__ gtr,
                            const float* __restrict__ g, const float* __restrict__ b,
                            float* __restrict__ scale, float* __restrict__ shift,
                            float* __restrict__ total, float* __restrict__ trace) {
    int t = threadIdx.x;   // 64
    float s = gsum[t], q = gsq[t], tr = gtr[t];
    float mean = s * (1.f / 262144.f);
    float var = q * (1.f / 262144.f) - mean * mean;
    float sc = g[t] * rsqrtf(fmaxf(var, 0.f) + 1e-5f);
    float sh = b[t] - mean * sc;
    scale[t] = sc;
    shift[t] = sh;
    total[t] = sc * s + 262144.f * sh;
    trace[t] = sc * tr + 512.f * sh;
    gsum[t] = 0.f; gsq[t] = 0.f; gtr[t] = 0.f;
}

// ---------------------------------------------------------------------------
// K12: head (fp32 weights/out)
__global__ void head(const float* __restrict__ out_acc, const float* __restrict__ acw,
                     const float* __restrict__ acb, const float* __restrict__ flw,
                     const float* __restrict__ flb, float* __restrict__ out) {
    __shared__ float x[64], x2[64], l[10];
    int t = threadIdx.x;  // 64
    x[t] = fmaxf(out_acc[t], 0.f) * (1.f / 3.f);
    __syncthreads();
    float y = acb[t];
    for (int f = 0; f < 64; ++f) y += x[f] * acw[t * 64 + f];
    x2[t] = x[t] + fmaxf(y, 0.f);
    __syncthreads();
    if (t < 10) {
        float s = flb[t];
        for (int f = 0; f < 64; ++f) s += x2[f] * flw[t * 64 + f];
        l[t] = s;
    }
    __syncthreads();
    if (t == 0) {
        float m = l[0];
        for (int i = 1; i < 10; ++i) m = fmaxf(m, l[i]);
        float se = 0.f;
        for (int i = 0; i < 10; ++i) se += expf(l[i] - m);
        float ls = m + logf(se);
        for (int i = 0; i < 10; ++i) out[i] = l[i] - ls;
    }
}

// ---------------------------------------------------------------------------
extern "C" void kernel_launch(void* const* d_in, const int* in_sizes, int n_in,
                              void* d_out, int out_size, void* d_ws, size_t ws_size,
                              hipStream_t stream) {
    float* out = (float*)d_out;

    static const int exp_sizes[28] = {
        8192, 32768,
        2048, 64, 2048, 4096,
        2048, 64, 2048, 64, 6144, 64,
        8192, 128, 8192, 128, 16384, 128,
        192, 192,
        12288, 192, 12288, 12288,
        4096, 64, 640, 10
    };
    bool ok = (n_in == 28);
    if (ok) for (int i = 0; i < 28; ++i) if (in_sizes[i] != exp_sizes[i]) ok = false;
    if (!ok) { sentinel_kernel<<<1, 64, 0, stream>>>(out, -5.0f); return; }

    const size_t RSZ = (size_t)NN * 64 * 2;            // 33.55 MB per region
    const size_t BIG_OFF = 8192 + 90112;               // control (8KB) + bf16 weight arena
    if (ws_size < BIG_OFF + 4 * RSZ) {
        sentinel_kernel<<<1, 64, 0, stream>>>(out, -7.0f);
        return;
    }

    const float* x     = (const float*)d_in[0];
    const int*   ei    = (const int*)d_in[1];
    const float* np1w  = (const float*)d_in[2];
    const float* np1b  = (const float*)d_in[3];
    const float* np2w  = (const float*)d_in[4];
    const float* np3w  = (const float*)d_in[5];
    const float* c0m1b = (const float*)d_in[7];
    const float* c0m2b = (const float*)d_in[9];
    const float* c0m4b = (const float*)d_in[11];
    const float* cm1b  = (const float*)d_in[13];
    const float* cm2b  = (const float*)d_in[15];
    const float* cm4b  = (const float*)d_in[17];
    const float* bng   = (const float*)d_in[18];
    const float* bnb   = (const float*)d_in[19];
    const float* fe1w  = (const float*)d_in[20];
    const float* fe1b  = (const float*)d_in[21];
    const float* fe2w  = (const float*)d_in[22];
    const float* fe3w  = (const float*)d_in[23];
    const float* acw   = (const float*)d_in[24];
    const float* acb   = (const float*)d_in[25];
    const float* flw   = (const float*)d_in[26];
    const float* flb   = (const float*)d_in[27];

    char* ws = (char*)d_ws;
    float* small = (float*)ws;
    float* scl   = small;          // 64
    float* shf   = small + 64;
    float* trace = small + 128;
    float* total = small + 192;
    float* oacc  = small + 256;
    float* tr0   = small + 320;
    float* gsum  = small + 384;
    float* gsq   = small + 448;
    float* gtr   = small + 512;

    u16* arena = (u16*)(ws + 8192);          // bf16 conv weights, 43008 elements

    char* big = ws + BIG_OFF;
    u16* S0 = (u16*)(big + 0 * RSZ);
    u16* S1 = (u16*)(big + 1 * RSZ);
    u16* S2 = (u16*)(big + 2 * RSZ);
    u16* S3 = (u16*)(big + 3 * RSZ);
    float* Abuf = (float*)S2;                // fp32 staging, dead after finalize_u0

    hipMemsetAsync(small, 0, 4096, stream);
    hipMemsetAsync(Abuf, 0, (size_t)NN * 32 * 4, stream);

    cvt_weights<<<168, 256, 0, stream>>>((const float*)d_in[6], (const float*)d_in[8],
                                         (const float*)d_in[10], (const float*)d_in[12],
                                         (const float*)d_in[14], (const float*)d_in[16], arena);
    scatter_edges<<<2048, 256, 0, stream>>>(x, ei, Abuf);
    finalize_u0<<<1024, 256, 0, stream>>>(Abuf, S0, total);          // u0 cm -> S0
    trace_raw_cm<<<32, 256, 0, stream>>>(S0, tr0);
    extractor_acc<<<1, 64, 0, stream>>>(tr0, total, 32, np1w, np1b, np2w, np3w, oacc);

    // slot schedule: l0: U=S0 -> O1=S1,O2=S2 -> M=S3 -> R=S1
    //                l1: U=S1 -> O1=S0,O2=S2 -> M=S3 -> R=S0
    //                l2: U=S0 -> O1=S1,O2=S2 -> M=S3 -> R=S1
    u16* U[3]  = { S0, S1, S0 };
    u16* O1[3] = { S1, S0, S1 };
    u16* O2[3] = { S2, S2, S2 };
    u16* R[3]  = { S1, S0, S1 };

    const float *aff_s = nullptr, *aff_h = nullptr;

    for (int l = 0; l < 3; ++l) {
        int Cin = (l == 0) ? 32 : 64;
        const u16 *w1b, *w2b, *w4b;
        const float *b1, *b2, *b4;
        if (l == 0) {
            w1b = arena;            b1 = c0m1b;
            w2b = arena + 2048;     b2 = c0m2b;
            w4b = arena + 4096;     b4 = c0m4b;
        } else {
            int m = l - 1;
            w1b = arena + 10240 + m * 4096;  b1 = cm1b + m * 64;
            w2b = arena + 18432 + m * 4096;  b2 = cm2b + m * 64;
            w4b = arena + 26624 + m * 8192;  b4 = cm4b + m * 64;
        }
        conv12<<<2048, 256, 0, stream>>>(U[l], Cin, aff_s, aff_h,
                                         w1b, b1, w2b, b2, O1[l], O2[l]);
        bmm_mfma<<<dim3(16, 64), 256, 0, stream>>>(O1[l], O2[l], S3);
        conv4<<<2048, 256, 0, stream>>>(S3, U[l], Cin, aff_s, aff_h,
                                        w4b, b4, R[l], gsum, gsq, gtr);
        bn_finalize<<<1, 64, 0, stream>>>(gsum, gsq, gtr, bng + l * 64, bnb + l * 64,
                                          scl, shf, total, trace);
        extractor_acc<<<1, 64, 0, stream>>>(trace, total, 64,
                                            fe1w + l * 4096, fe1b + l * 64,
                                            fe2w + l * 4096, fe3w + l * 4096, oacc);
        aff_s = scl; aff_h = shf;
    }
    head<<<1, 64, 0, stream>>>(oacc, acw, acb, flw, flb, out);
}

// Round 9
// 524.105 us; speedup vs baseline: 2.1954x; 1.1768x over previous
//
#include <hip/hip_runtime.h>
#include <hip/hip_bf16.h>

// Problem dims (fixed)
#define Nn   512
#define NN   262144        // N*N positions
#define EDG  16384

typedef unsigned short u16;
typedef short v8s __attribute__((ext_vector_type(8)));   // 8 bf16 lanes (4 VGPR)
typedef float v4f __attribute__((ext_vector_type(4)));
typedef u16 u16x8 __attribute__((ext_vector_type(8)));

__device__ __forceinline__ float b2f(u16 u) {
    union { unsigned int i; float f; } v; v.i = ((unsigned int)u) << 16; return v.f;
}
__device__ __forceinline__ u16 f2b(float f) {
    union { float f; unsigned int i; } v; v.f = f;
    unsigned int r = (v.i + 0x7FFFu + ((v.i >> 16) & 1u)) >> 16;
    return (u16)r;
}

// ---------------------------------------------------------------------------
__global__ void sentinel_kernel(float* __restrict__ out, float val) {
    if (threadIdx.x < 10) out[threadIdx.x] = val;
}

// ---------------------------------------------------------------------------
// K0: convert the 6 conv weight tensors (fp32) into one bf16 arena.
__global__ void cvt_weights(const float* __restrict__ s0, const float* __restrict__ s1,
                            const float* __restrict__ s2, const float* __restrict__ s3,
                            const float* __restrict__ s4, const float* __restrict__ s5,
                            u16* __restrict__ dst) {
    int t = blockIdx.x * 256 + threadIdx.x;
    if (t >= 43008) return;
    float v;
    if      (t < 2048)  v = s0[t];
    else if (t < 4096)  v = s1[t - 2048];
    else if (t < 10240) v = s2[t - 4096];
    else if (t < 18432) v = s3[t - 10240];
    else if (t < 26624) v = s4[t - 18432];
    else                v = s5[t - 26624];
    dst[t] = f2b(v);
}

// ---------------------------------------------------------------------------
// K1: scatter edges into A (fp32, pos-major [p][32]); x is fp32 [512][16]
__global__ void scatter_edges(const float* __restrict__ x, const int* __restrict__ ei,
                              float* __restrict__ A) {
    int t = blockIdx.x * 256 + threadIdx.x;
    if (t >= EDG * 32) return;
    int e = t >> 5, c = t & 31;
    int s = ei[e], d = ei[EDG + e];
    float v = (c < 16) ? x[s * 16 + c] : x[d * 16 + (c - 16)];
    atomicAdd(A + ((size_t)s * Nn + d) * 32 + c, v);
}

// ---------------------------------------------------------------------------
// K2: A fp32 pos-major [p][32] -> u0 CHANNEL-MAJOR bf16 [32][NN]; per-channel totals.
__global__ __launch_bounds__(256) void finalize_u0(const float* __restrict__ A,
                                                   u16* __restrict__ u0,
                                                   float* __restrict__ total) {
    __shared__ u16 L[32 * 258];
    __shared__ float red[4][32];
    int t = threadIdx.x;
    int p0 = blockIdx.x * 256;
    const float* Ar = A + (size_t)(p0 + t) * 32;
    float v[32];
#pragma unroll
    for (int c = 0; c < 32; ++c) v[c] = Ar[c];
#pragma unroll
    for (int c = 0; c < 32; ++c) L[c * 258 + t] = f2b(v[c]);
    int wv = t >> 6;
#pragma unroll
    for (int c = 0; c < 32; ++c) {
        float r = v[c];
        for (int off = 32; off > 0; off >>= 1) r += __shfl_down(r, off);
        if ((t & 63) == 0) red[wv][c] = r;
    }
    __syncthreads();
    if (t < 32) atomicAdd(total + t, red[0][t] + red[1][t] + red[2][t] + red[3][t]);
    int off = (t & 31) * 8, rb = t >> 5;
#pragma unroll
    for (int pass = 0; pass < 4; ++pass) {
        int c = pass * 8 + rb;
        u16x8 w = *(const u16x8*)(L + c * 258 + off);
        *(u16x8*)(u0 + (size_t)c * NN + p0 + off) = w;
    }
}

// ---------------------------------------------------------------------------
// K3: trace of channel-major activation; grid = C blocks.
__global__ void trace_raw_cm(const u16* __restrict__ ucm, float* __restrict__ trraw) {
    int c = blockIdx.x, t = threadIdx.x;
    const u16* base = ucm + (size_t)c * NN;
    float s = b2f(base[(size_t)(2 * t) * 513]) + b2f(base[(size_t)(2 * t + 1) * 513]);
    for (int off = 32; off > 0; off >>= 1) s += __shfl_down(s, off);
    __shared__ float r[4];
    if ((t & 63) == 0) r[t >> 6] = s;
    __syncthreads();
    if (t == 0) trraw[c] = r[0] + r[1] + r[2] + r[3];
}

// ---------------------------------------------------------------------------
// K4: extractor MLP (fp32 weights), accumulate into out_acc[64]. 1 block, 64 threads.
__global__ void extractor_acc(const float* __restrict__ trace, const float* __restrict__ total,
                              int C, const float* __restrict__ w1, const float* __restrict__ b1,
                              const float* __restrict__ w2, const float* __restrict__ w3,
                              float* __restrict__ out_acc) {
    __shared__ float xo[64];
    int t = threadIdx.x;
    const float inv_n = 1.f / 512.f;
    const float inv_off = 1.f / (512.f * 511.f);
    float s1 = b1[t];
    for (int c = 0; c < C; ++c) s1 += (trace[c] * inv_n) * w1[t * C + c];
    float s2 = 0.f;
    for (int c = 0; c < C; ++c) s2 += ((total[c] - trace[c]) * inv_off) * w2[t * C + c];
    float o = s1 + s2;
    xo[t] = o;
    __syncthreads();
    float s3 = 0.f;
    for (int f = 0; f < 64; ++f) s3 += fmaxf(xo[f], 0.f) * w3[t * 64 + f];
    out_acc[t] += o + s3;
}

// ---------------------------------------------------------------------------
// K5: merged conv1+conv2, templated chunk count; ALL global staging loads
// issued upfront (misses overlap). Block = 128 positions.
template<int NCH>
__global__ __launch_bounds__(256) void conv12_t(
    const u16* __restrict__ src,
    const float* __restrict__ sc, const float* __restrict__ sh,
    const u16* __restrict__ w1, const float* __restrict__ b1,
    const u16* __restrict__ w2, const float* __restrict__ b2,
    u16* __restrict__ dst1, u16* __restrict__ dst2)
{
    __shared__ u16 LS[8320];   // 2 x [32][130] chunk bufs == [64][130] epilogue
    const int C = NCH * 32;
    const int t = threadIdx.x;
    const int P0 = blockIdx.x * 128;
    const int lane = t & 63, wave = t >> 6;
    const int l15 = lane & 15, quad = lane >> 4;
    const int pw = wave * 32;
    const int sr = t >> 4;          // 0..15
    const int so = (t & 15) * 8;

    u16x8 pf[NCH][2];
#pragma unroll
    for (int kc = 0; kc < NCH; ++kc)
#pragma unroll
        for (int ps = 0; ps < 2; ++ps)
            pf[kc][ps] = *(const u16x8*)(src + (size_t)(kc * 32 + ps * 16 + sr) * NN + P0 + so);

    v4f acc[2][4][2];
#pragma unroll
    for (int s = 0; s < 2; ++s)
#pragma unroll
        for (int mt = 0; mt < 4; ++mt)
#pragma unroll
            for (int nt = 0; nt < 2; ++nt) acc[s][mt][nt] = (v4f){0.f, 0.f, 0.f, 0.f};

    // stage chunk 0
    {
        u16* Ln = LS;
#pragma unroll
        for (int ps = 0; ps < 2; ++ps) {
            int c = ps * 16 + sr;
            u16x8 v = pf[0][ps];
            if (sc) {
                float s = sc[c], f = sh[c];
#pragma unroll
                for (int j = 0; j < 8; ++j) v[j] = f2b(b2f(v[j]) * s + f);
            }
            *(u16x8*)(Ln + c * 130 + so) = v;
        }
    }
    __syncthreads();
#pragma unroll
    for (int kc = 0; kc < NCH; ++kc) {
        if (kc + 1 < NCH) {
            u16* Ln = LS + ((kc + 1) & 1) * 4160;
#pragma unroll
            for (int ps = 0; ps < 2; ++ps) {
                int c = ps * 16 + sr;
                int cg = (kc + 1) * 32 + c;
                u16x8 v = pf[kc + 1][ps];
                if (sc) {
                    float s = sc[cg], f = sh[cg];
#pragma unroll
                    for (int j = 0; j < 8; ++j) v[j] = f2b(b2f(v[j]) * s + f);
                }
                *(u16x8*)(Ln + c * 130 + so) = v;
            }
        }
        v8s af1[4], af2[4];
#pragma unroll
        for (int mt = 0; mt < 4; ++mt) {
            af1[mt] = *(const v8s*)(w1 + (mt * 16 + l15) * C + kc * 32 + quad * 8);
            af2[mt] = *(const v8s*)(w2 + (mt * 16 + l15) * C + kc * 32 + quad * 8);
        }
        const u16* Lb = LS + (kc & 1) * 4160;
#pragma unroll
        for (int nt = 0; nt < 2; ++nt) {
            const int p = pw + nt * 16 + l15;
            v8s b;
#pragma unroll
            for (int j = 0; j < 8; ++j) b[j] = (short)Lb[(quad * 8 + j) * 130 + p];
#pragma unroll
            for (int mt = 0; mt < 4; ++mt) {
                acc[0][mt][nt] = __builtin_amdgcn_mfma_f32_16x16x32_bf16(af1[mt], b, acc[0][mt][nt], 0, 0, 0);
                acc[1][mt][nt] = __builtin_amdgcn_mfma_f32_16x16x32_bf16(af2[mt], b, acc[1][mt][nt], 0, 0, 0);
            }
        }
        if (kc + 1 < NCH) __syncthreads();
    }
#pragma unroll
    for (int s = 0; s < 2; ++s) {
        __syncthreads();
        const float* bb = s ? b2 : b1;
#pragma unroll
        for (int mt = 0; mt < 4; ++mt)
#pragma unroll
            for (int r = 0; r < 4; ++r) {
                const int h = mt * 16 + quad * 4 + r;
                const float bv = bb[h];
#pragma unroll
                for (int nt = 0; nt < 2; ++nt)
                    LS[h * 130 + pw + nt * 16 + l15] = f2b(acc[s][mt][nt][r] + bv);
            }
        __syncthreads();
        u16* dd = s ? dst2 : dst1;
#pragma unroll
        for (int ps = 0; ps < 4; ++ps) {
            int h = ps * 16 + sr;
            u16x8 v = *(const u16x8*)(LS + h * 130 + so);
            __builtin_nontemporal_store(v, (u16x8*)(dd + (size_t)h * NN + P0 + so));
        }
    }
}

// ---------------------------------------------------------------------------
// K6: m4 conv, templated; upfront loads; BN stats/trace as PER-BLOCK PARTIALS
// (no atomics): psum/psq[c*2048+blk], ptr[c*512+row] (diag block only, 1 writer).
template<int NCH>
__global__ __launch_bounds__(256) void conv4_t(
    const u16* __restrict__ mult, const u16* __restrict__ u,
    const float* __restrict__ sc, const float* __restrict__ sh,
    const u16* __restrict__ w, const float* __restrict__ bias,
    u16* __restrict__ dst,
    float* __restrict__ psum, float* __restrict__ psq, float* __restrict__ ptr)
{
    __shared__ u16 LS[8320];
    __shared__ float R1[64][4], R2[64][4];
    const int K = NCH * 32;
    const int t = threadIdx.x;
    const int P0 = blockIdx.x * 128;
    const int lane = t & 63, wave = t >> 6;
    const int l15 = lane & 15, quad = lane >> 4;
    const int pw = wave * 32;
    const int sr = t >> 4;
    const int so = (t & 15) * 8;

    u16x8 pf[NCH][2];
#pragma unroll
    for (int kc = 0; kc < NCH; ++kc)
#pragma unroll
        for (int ps = 0; ps < 2; ++ps) {
            int cg = kc * 32 + ps * 16 + sr;
            const u16* gp = (cg < 64) ? (mult + (size_t)cg * NN + P0 + so)
                                      : (u + (size_t)(cg - 64) * NN + P0 + so);
            pf[kc][ps] = *(const u16x8*)gp;
        }

    v4f acc[4][2];
#pragma unroll
    for (int mt = 0; mt < 4; ++mt)
#pragma unroll
        for (int nt = 0; nt < 2; ++nt) acc[mt][nt] = (v4f){0.f, 0.f, 0.f, 0.f};

#pragma unroll
    for (int ps = 0; ps < 2; ++ps)
        *(u16x8*)(LS + (ps * 16 + sr) * 130 + so) = pf[0][ps];   // chunk 0 = mult rows
    __syncthreads();
#pragma unroll
    for (int kc = 0; kc < NCH; ++kc) {
        if (kc + 1 < NCH) {
            u16* Ln = LS + ((kc + 1) & 1) * 4160;
#pragma unroll
            for (int ps = 0; ps < 2; ++ps) {
                int c = ps * 16 + sr;
                int cg = (kc + 1) * 32 + c;
                u16x8 v = pf[kc + 1][ps];
                if (cg >= 64 && sc) {
                    float s = sc[cg - 64], f = sh[cg - 64];
#pragma unroll
                    for (int j = 0; j < 8; ++j) v[j] = f2b(b2f(v[j]) * s + f);
                }
                *(u16x8*)(Ln + c * 130 + so) = v;
            }
        }
        v8s af[4];
#pragma unroll
        for (int mt = 0; mt < 4; ++mt)
            af[mt] = *(const v8s*)(w + (mt * 16 + l15) * K + kc * 32 + quad * 8);
        const u16* Lb = LS + (kc & 1) * 4160;
#pragma unroll
        for (int nt = 0; nt < 2; ++nt) {
            const int p = pw + nt * 16 + l15;
            v8s b;
#pragma unroll
            for (int j = 0; j < 8; ++j) b[j] = (short)Lb[(quad * 8 + j) * 130 + p];
#pragma unroll
            for (int mt = 0; mt < 4; ++mt)
                acc[mt][nt] = __builtin_amdgcn_mfma_f32_16x16x32_bf16(af[mt], b, acc[mt][nt], 0, 0, 0);
        }
        if (kc + 1 < NCH) __syncthreads();
    }
    __syncthreads();
#pragma unroll
    for (int mt = 0; mt < 4; ++mt)
#pragma unroll
        for (int r = 0; r < 4; ++r) {
            const int h = mt * 16 + quad * 4 + r;
            const float bv = bias[h];
#pragma unroll
            for (int nt = 0; nt < 2; ++nt)
                LS[h * 130 + pw + nt * 16 + l15] = f2b(acc[mt][nt][r] + bv);
        }
    __syncthreads();
    {   // fused stats partials
        int c = t >> 2, q = t & 3;
        const u16* row = LS + c * 130 + q * 32;
        float s = 0.f, s2 = 0.f;
#pragma unroll
        for (int i = 0; i < 32; ++i) { float v = b2f(row[i]); s += v; s2 += v * v; }
        R1[c][q] = s; R2[c][q] = s2;
    }
    __syncthreads();
    {
        int i = P0 >> 9, j0 = P0 & 511;
        int blk = blockIdx.x;
        if (t < 64) {
            psum[t * 2048 + blk] = R1[t][0] + R1[t][1] + R1[t][2] + R1[t][3];
            psq[t * 2048 + blk]  = R2[t][0] + R2[t][1] + R2[t][2] + R2[t][3];
            if (j0 <= i && i < j0 + 128) ptr[t * 512 + i] = b2f(LS[t * 130 + (i - j0)]);
        }
    }
#pragma unroll
    for (int ps = 0; ps < 4; ++ps) {
        int h = ps * 16 + sr;
        u16x8 v = *(const u16x8*)(LS + h * 130 + so);
        __builtin_nontemporal_store(v, (u16x8*)(dst + (size_t)h * NN + P0 + so));
    }
}

// ---------------------------------------------------------------------------
// K7: batched per-channel GEMM, B in natural cm layout [k][j] (r8, proven).
__global__ __launch_bounds__(256) void bmm_mfma(const u16* __restrict__ Aall,
                                                const u16* __restrict__ Ball,
                                                u16* __restrict__ Call) {
    __shared__ u16 LA[128 * 72];
    __shared__ u16 LB[64 * 130];
    const int h = blockIdx.y;
    const int tx = blockIdx.x & 3, ty = blockIdx.x >> 2;
    const int t = threadIdx.x;
    const int lane = t & 63, wave = t >> 6;
    const int wr = wave >> 1, wc = wave & 1;
    const int l15 = lane & 15, quad = lane >> 4;
    const u16* Ap = Aall + (size_t)h * NN + (size_t)ty * 128 * 512;
    const u16* Bp = Ball + (size_t)h * NN + tx * 128;

    const int srow = t >> 3;
    const int scol = (t & 7) * 8;
    const int bkr = t >> 4;
    const int bjg = (t & 15) * 8;

    v4f acc[4][4];
#pragma unroll
    for (int mt = 0; mt < 4; ++mt)
#pragma unroll
        for (int nt = 0; nt < 4; ++nt) acc[mt][nt] = (v4f){0.f, 0.f, 0.f, 0.f};

    v8s ra[4], rb[4];
#pragma unroll
    for (int i = 0; i < 4; ++i) {
        ra[i] = *(const v8s*)(Ap + (size_t)(i * 32 + srow) * 512 + scol);
        rb[i] = *(const v8s*)(Bp + (size_t)(i * 16 + bkr) * 512 + bjg);
    }

    for (int ck = 0; ck < 8; ++ck) {
#pragma unroll
        for (int i = 0; i < 4; ++i) {
            *(v8s*)(LA + (i * 32 + srow) * 72 + scol) = ra[i];
            *(v8s*)(LB + (i * 16 + bkr) * 130 + bjg) = rb[i];
        }
        __syncthreads();
        if (ck < 7) {
            const int k0 = (ck + 1) * 64;
#pragma unroll
            for (int i = 0; i < 4; ++i) {
                ra[i] = *(const v8s*)(Ap + (size_t)(i * 32 + srow) * 512 + k0 + scol);
                rb[i] = *(const v8s*)(Bp + (size_t)(k0 + i * 16 + bkr) * 512 + bjg);
            }
        }
#pragma unroll
        for (int kk = 0; kk < 2; ++kk) {
            v8s a[4], b[4];
#pragma unroll
            for (int mt = 0; mt < 4; ++mt)
                a[mt] = *(const v8s*)(LA + (wr * 64 + mt * 16 + l15) * 72 + kk * 32 + quad * 8);
#pragma unroll
            for (int nt = 0; nt < 4; ++nt) {
                const int j = wc * 64 + nt * 16 + l15;
#pragma unroll
                for (int jj = 0; jj < 8; ++jj)
                    b[nt][jj] = (short)LB[(kk * 32 + quad * 8 + jj) * 130 + j];
            }
#pragma unroll
            for (int mt = 0; mt < 4; ++mt)
#pragma unroll
                for (int nt = 0; nt < 4; ++nt)
                    acc[mt][nt] = __builtin_amdgcn_mfma_f32_16x16x32_bf16(a[mt], b[nt], acc[mt][nt], 0, 0, 0);
        }
        __syncthreads();
    }

    u16* Cp = Call + (size_t)h * NN;
#pragma unroll
    for (int mt = 0; mt < 4; ++mt)
#pragma unroll
        for (int r = 0; r < 4; ++r) {
            const int i = ty * 128 + wr * 64 + mt * 16 + quad * 4 + r;
#pragma unroll
            for (int nt = 0; nt < 4; ++nt) {
                const int j = tx * 128 + wc * 64 + nt * 16 + l15;
                Cp[i * 512 + j] = f2b(acc[mt][nt][r]);
            }
        }
}

// ---------------------------------------------------------------------------
// K11 v2: reduce per-block partials; BN scale/shift; analytic totals & trace.
// grid = 64 blocks (one per channel), 256 threads.
__global__ __launch_bounds__(256) void bn_finalize(
    const float* __restrict__ psum, const float* __restrict__ psq,
    const float* __restrict__ ptr,
    const float* __restrict__ g, const float* __restrict__ b,
    float* __restrict__ scale, float* __restrict__ shift,
    float* __restrict__ total, float* __restrict__ trace) {
    int c = blockIdx.x, t = threadIdx.x;
    float s = 0.f, q = 0.f, tr = 0.f;
    for (int k = t; k < 2048; k += 256) { s += psum[c * 2048 + k]; q += psq[c * 2048 + k]; }
    if (t < 512 || true) for (int k = t; k < 512; k += 256) tr += ptr[c * 512 + k];
    for (int off = 32; off > 0; off >>= 1) {
        s += __shfl_down(s, off); q += __shfl_down(q, off); tr += __shfl_down(tr, off);
    }
    __shared__ float r1[4], r2[4], r3[4];
    if ((t & 63) == 0) { r1[t >> 6] = s; r2[t >> 6] = q; r3[t >> 6] = tr; }
    __syncthreads();
    if (t == 0) {
        s = r1[0] + r1[1] + r1[2] + r1[3];
        q = r2[0] + r2[1] + r2[2] + r2[3];
        tr = r3[0] + r3[1] + r3[2] + r3[3];
        float mean = s * (1.f / 262144.f);
        float var = q * (1.f / 262144.f) - mean * mean;
        float sc = g[c] * rsqrtf(fmaxf(var, 0.f) + 1e-5f);
        float sh = b[c] - mean * sc;
        scale[c] = sc;
        shift[c] = sh;
        total[c] = sc * s + 262144.f * sh;
        trace[c] = sc * tr + 512.f * sh;
    }
}

// ---------------------------------------------------------------------------
// K12: head (fp32 weights/out)
__global__ void head(const float* __restrict__ out_acc, const float* __restrict__ acw,
                     const float* __restrict__ acb, const float* __restrict__ flw,
                     const float* __restrict__ flb, float* __restrict__ out) {
    __shared__ float x[64], x2[64], l[10];
    int t = threadIdx.x;  // 64
    x[t] = fmaxf(out_acc[t], 0.f) * (1.f / 3.f);
    __syncthreads();
    float y = acb[t];
    for (int f = 0; f < 64; ++f) y += x[f] * acw[t * 64 + f];
    x2[t] = x[t] + fmaxf(y, 0.f);
    __syncthreads();
    if (t < 10) {
        float s = flb[t];
        for (int f = 0; f < 64; ++f) s += x2[f] * flw[t * 64 + f];
        l[t] = s;
    }
    __syncthreads();
    if (t == 0) {
        float m = l[0];
        for (int i = 1; i < 10; ++i) m = fmaxf(m, l[i]);
        float se = 0.f;
        for (int i = 0; i < 10; ++i) se += expf(l[i] - m);
        float ls = m + logf(se);
        for (int i = 0; i < 10; ++i) out[i] = l[i] - ls;
    }
}

// ---------------------------------------------------------------------------
extern "C" void kernel_launch(void* const* d_in, const int* in_sizes, int n_in,
                              void* d_out, int out_size, void* d_ws, size_t ws_size,
                              hipStream_t stream) {
    float* out = (float*)d_out;

    static const int exp_sizes[28] = {
        8192, 32768,
        2048, 64, 2048, 4096,
        2048, 64, 2048, 64, 6144, 64,
        8192, 128, 8192, 128, 16384, 128,
        192, 192,
        12288, 192, 12288, 12288,
        4096, 64, 640, 10
    };
    bool ok = (n_in == 28);
    if (ok) for (int i = 0; i < 28; ++i) if (in_sizes[i] != exp_sizes[i]) ok = false;
    if (!ok) { sentinel_kernel<<<1, 64, 0, stream>>>(out, -5.0f); return; }

    const size_t RSZ = (size_t)NN * 64 * 2;            // 33.55 MB per region
    const size_t BIG_OFF = 8192 + 90112;               // control (8KB) + bf16 weight arena
    if (ws_size < BIG_OFF + 4 * RSZ) {
        sentinel_kernel<<<1, 64, 0, stream>>>(out, -7.0f);
        return;
    }

    const float* x     = (const float*)d_in[0];
    const int*   ei    = (const int*)d_in[1];
    const float* np1w  = (const float*)d_in[2];
    const float* np1b  = (const float*)d_in[3];
    const float* np2w  = (const float*)d_in[4];
    const float* np3w  = (const float*)d_in[5];
    const float* c0m1b = (const float*)d_in[7];
    const float* c0m2b = (const float*)d_in[9];
    const float* c0m4b = (const float*)d_in[11];
    const float* cm1b  = (const float*)d_in[13];
    const float* cm2b  = (const float*)d_in[15];
    const float* cm4b  = (const float*)d_in[17];
    const float* bng   = (const float*)d_in[18];
    const float* bnb   = (const float*)d_in[19];
    const float* fe1w  = (const float*)d_in[20];
    const float* fe1b  = (const float*)d_in[21];
    const float* fe2w  = (const float*)d_in[22];
    const float* fe3w  = (const float*)d_in[23];
    const float* acw   = (const float*)d_in[24];
    const float* acb   = (const float*)d_in[25];
    const float* flw   = (const float*)d_in[26];
    const float* flb   = (const float*)d_in[27];

    char* ws = (char*)d_ws;
    float* small = (float*)ws;
    float* scl   = small;          // 64
    float* shf   = small + 64;
    float* trace = small + 128;
    float* total = small + 192;
    float* oacc  = small + 256;
    float* tr0   = small + 320;

    u16* arena = (u16*)(ws + 8192);          // bf16 conv weights, 43008 elements

    char* big = ws + BIG_OFF;
    u16* S0 = (u16*)(big + 0 * RSZ);
    u16* S1 = (u16*)(big + 1 * RSZ);
    u16* S2 = (u16*)(big + 2 * RSZ);
    u16* S3 = (u16*)(big + 3 * RSZ);
    float* Abuf = (float*)S2;                // fp32 staging, dead after finalize_u0

    // BN partial buffers live in S2 (o2 slot) — o2 is dead once bmm has run,
    // and S2 is not rewritten until the NEXT layer's conv12.
    float* psum = (float*)S2;                          // 64*2048
    float* psq  = psum + 64 * 2048;                    // 64*2048
    float* ptr  = psq + 64 * 2048;                     // 64*512

    hipMemsetAsync(small, 0, 4096, stream);
    hipMemsetAsync(Abuf, 0, (size_t)NN * 32 * 4, stream);

    cvt_weights<<<168, 256, 0, stream>>>((const float*)d_in[6], (const float*)d_in[8],
                                         (const float*)d_in[10], (const float*)d_in[12],
                                         (const float*)d_in[14], (const float*)d_in[16], arena);
    scatter_edges<<<2048, 256, 0, stream>>>(x, ei, Abuf);
    finalize_u0<<<1024, 256, 0, stream>>>(Abuf, S0, total);          // u0 cm -> S0
    trace_raw_cm<<<32, 256, 0, stream>>>(S0, tr0);
    extractor_acc<<<1, 64, 0, stream>>>(tr0, total, 32, np1w, np1b, np2w, np3w, oacc);

    // slot schedule: l0: U=S0 -> O1=S1,O2=S2 -> M=S3 -> R=S1
    //                l1: U=S1 -> O1=S0,O2=S2 -> M=S3 -> R=S0
    //                l2: U=S0 -> O1=S1,O2=S2 -> M=S3 -> R=S1
    u16* U[3]  = { S0, S1, S0 };
    u16* O1[3] = { S1, S0, S1 };
    u16* O2[3] = { S2, S2, S2 };
    u16* R[3]  = { S1, S0, S1 };

    const float *aff_s = nullptr, *aff_h = nullptr;

    for (int l = 0; l < 3; ++l) {
        int Cin = (l == 0) ? 32 : 64;
        const u16 *w1b, *w2b, *w4b;
        const float *b1, *b2, *b4;
        if (l == 0) {
            w1b = arena;            b1 = c0m1b;
            w2b = arena + 2048;     b2 = c0m2b;
            w4b = arena + 4096;     b4 = c0m4b;
        } else {
            int m = l - 1;
            w1b = arena + 10240 + m * 4096;  b1 = cm1b + m * 64;
            w2b = arena + 18432 + m * 4096;  b2 = cm2b + m * 64;
            w4b = arena + 26624 + m * 8192;  b4 = cm4b + m * 64;
        }
        if (Cin == 32)
            conv12_t<1><<<2048, 256, 0, stream>>>(U[l], aff_s, aff_h, w1b, b1, w2b, b2, O1[l], O2[l]);
        else
            conv12_t<2><<<2048, 256, 0, stream>>>(U[l], aff_s, aff_h, w1b, b1, w2b, b2, O1[l], O2[l]);
        bmm_mfma<<<dim3(16, 64), 256, 0, stream>>>(O1[l], O2[l], S3);
        if (Cin == 32)
            conv4_t<3><<<2048, 256, 0, stream>>>(S3, U[l], aff_s, aff_h, w4b, b4, R[l], psum, psq, ptr);
        else
            conv4_t<4><<<2048, 256, 0, stream>>>(S3, U[l], aff_s, aff_h, w4b, b4, R[l], psum, psq, ptr);
        bn_finalize<<<64, 256, 0, stream>>>(psum, psq, ptr, bng + l * 64, bnb + l * 64,
                                            scl, shf, total, trace);
        extractor_acc<<<1, 64, 0, stream>>>(trace, total, 64,
                                            fe1w + l * 4096, fe1b + l * 64,
                                            fe2w + l * 4096, fe3w + l * 4096, oacc);
        aff_s = scl; aff_h = shf;
    }
    head<<<1, 64, 0, stream>>>(oacc, acw, acb, flw, flb, out);
}

// Round 10
// 512.377 us; speedup vs baseline: 2.2457x; 1.0229x over previous
//
#include <hip/hip_runtime.h>
#include <hip/hip_bf16.h>

// Problem dims (fixed)
#define Nn   512
#define NN   262144        // N*N positions
#define EDG  16384

typedef unsigned short u16;
typedef short v8s __attribute__((ext_vector_type(8)));   // 8 bf16 lanes (4 VGPR)
typedef float v4f __attribute__((ext_vector_type(4)));
typedef u16 u16x8 __attribute__((ext_vector_type(8)));

__device__ __forceinline__ float b2f(u16 u) {
    union { unsigned int i; float f; } v; v.i = ((unsigned int)u) << 16; return v.f;
}
__device__ __forceinline__ u16 f2b(float f) {
    union { float f; unsigned int i; } v; v.f = f;
    unsigned int r = (v.i + 0x7FFFu + ((v.i >> 16) & 1u)) >> 16;
    return (u16)r;
}

// ---------------------------------------------------------------------------
__global__ void sentinel_kernel(float* __restrict__ out, float val) {
    if (threadIdx.x < 10) out[threadIdx.x] = val;
}

// ---------------------------------------------------------------------------
// K0: convert the 6 conv weight tensors (fp32) into one bf16 arena.
__global__ void cvt_weights(const float* __restrict__ s0, const float* __restrict__ s1,
                            const float* __restrict__ s2, const float* __restrict__ s3,
                            const float* __restrict__ s4, const float* __restrict__ s5,
                            u16* __restrict__ dst) {
    int t = blockIdx.x * 256 + threadIdx.x;
    if (t >= 43008) return;
    float v;
    if      (t < 2048)  v = s0[t];
    else if (t < 4096)  v = s1[t - 2048];
    else if (t < 10240) v = s2[t - 4096];
    else if (t < 18432) v = s3[t - 10240];
    else if (t < 26624) v = s4[t - 18432];
    else                v = s5[t - 26624];
    dst[t] = f2b(v);
}

// ---------------------------------------------------------------------------
// K1: scatter edges into A (fp32, pos-major [p][32]); x is fp32 [512][16]
__global__ void scatter_edges(const float* __restrict__ x, const int* __restrict__ ei,
                              float* __restrict__ A) {
    int t = blockIdx.x * 256 + threadIdx.x;
    if (t >= EDG * 32) return;
    int e = t >> 5, c = t & 31;
    int s = ei[e], d = ei[EDG + e];
    float v = (c < 16) ? x[s * 16 + c] : x[d * 16 + (c - 16)];
    atomicAdd(A + ((size_t)s * Nn + d) * 32 + c, v);
}

// ---------------------------------------------------------------------------
// K2: A fp32 pos-major [p][32] -> u0 CHANNEL-MAJOR bf16 [32][NN]; totals into tt0[64..]
__global__ __launch_bounds__(256) void finalize_u0(const float* __restrict__ A,
                                                   u16* __restrict__ u0,
                                                   float* __restrict__ total) {
    __shared__ u16 L[32 * 258];
    __shared__ float red[4][32];
    int t = threadIdx.x;
    int p0 = blockIdx.x * 256;
    const float* Ar = A + (size_t)(p0 + t) * 32;
    float v[32];
#pragma unroll
    for (int c = 0; c < 32; ++c) v[c] = Ar[c];
#pragma unroll
    for (int c = 0; c < 32; ++c) L[c * 258 + t] = f2b(v[c]);
    int wv = t >> 6;
#pragma unroll
    for (int c = 0; c < 32; ++c) {
        float r = v[c];
        for (int off = 32; off > 0; off >>= 1) r += __shfl_down(r, off);
        if ((t & 63) == 0) red[wv][c] = r;
    }
    __syncthreads();
    if (t < 32) atomicAdd(total + t, red[0][t] + red[1][t] + red[2][t] + red[3][t]);
    int off = (t & 31) * 8, rb = t >> 5;
#pragma unroll
    for (int pass = 0; pass < 4; ++pass) {
        int c = pass * 8 + rb;
        u16x8 w = *(const u16x8*)(L + c * 258 + off);
        *(u16x8*)(u0 + (size_t)c * NN + p0 + off) = w;
    }
}

// ---------------------------------------------------------------------------
// K3: trace of channel-major activation; grid = C blocks.
__global__ void trace_raw_cm(const u16* __restrict__ ucm, float* __restrict__ trraw) {
    int c = blockIdx.x, t = threadIdx.x;
    const u16* base = ucm + (size_t)c * NN;
    float s = b2f(base[(size_t)(2 * t) * 513]) + b2f(base[(size_t)(2 * t + 1) * 513]);
    for (int off = 32; off > 0; off >>= 1) s += __shfl_down(s, off);
    __shared__ float r[4];
    if ((t & 63) == 0) r[t >> 6] = s;
    __syncthreads();
    if (t == 0) trraw[c] = r[0] + r[1] + r[2] + r[3];
}

// ---------------------------------------------------------------------------
// K5: merged conv1+conv2 (r9, proven). Block = 128 positions.
template<int NCH>
__global__ __launch_bounds__(256) void conv12_t(
    const u16* __restrict__ src,
    const float* __restrict__ sc, const float* __restrict__ sh,
    const u16* __restrict__ w1, const float* __restrict__ b1,
    const u16* __restrict__ w2, const float* __restrict__ b2,
    u16* __restrict__ dst1, u16* __restrict__ dst2)
{
    __shared__ u16 LS[8320];
    const int C = NCH * 32;
    const int t = threadIdx.x;
    const int P0 = blockIdx.x * 128;
    const int lane = t & 63, wave = t >> 6;
    const int l15 = lane & 15, quad = lane >> 4;
    const int pw = wave * 32;
    const int sr = t >> 4;
    const int so = (t & 15) * 8;

    u16x8 pf[NCH][2];
#pragma unroll
    for (int kc = 0; kc < NCH; ++kc)
#pragma unroll
        for (int ps = 0; ps < 2; ++ps)
            pf[kc][ps] = *(const u16x8*)(src + (size_t)(kc * 32 + ps * 16 + sr) * NN + P0 + so);

    v4f acc[2][4][2];
#pragma unroll
    for (int s = 0; s < 2; ++s)
#pragma unroll
        for (int mt = 0; mt < 4; ++mt)
#pragma unroll
            for (int nt = 0; nt < 2; ++nt) acc[s][mt][nt] = (v4f){0.f, 0.f, 0.f, 0.f};

    {
        u16* Ln = LS;
#pragma unroll
        for (int ps = 0; ps < 2; ++ps) {
            int c = ps * 16 + sr;
            u16x8 v = pf[0][ps];
            if (sc) {
                float s = sc[c], f = sh[c];
#pragma unroll
                for (int j = 0; j < 8; ++j) v[j] = f2b(b2f(v[j]) * s + f);
            }
            *(u16x8*)(Ln + c * 130 + so) = v;
        }
    }
    __syncthreads();
#pragma unroll
    for (int kc = 0; kc < NCH; ++kc) {
        if (kc + 1 < NCH) {
            u16* Ln = LS + ((kc + 1) & 1) * 4160;
#pragma unroll
            for (int ps = 0; ps < 2; ++ps) {
                int c = ps * 16 + sr;
                int cg = (kc + 1) * 32 + c;
                u16x8 v = pf[kc + 1][ps];
                if (sc) {
                    float s = sc[cg], f = sh[cg];
#pragma unroll
                    for (int j = 0; j < 8; ++j) v[j] = f2b(b2f(v[j]) * s + f);
                }
                *(u16x8*)(Ln + c * 130 + so) = v;
            }
        }
        v8s af1[4], af2[4];
#pragma unroll
        for (int mt = 0; mt < 4; ++mt) {
            af1[mt] = *(const v8s*)(w1 + (mt * 16 + l15) * C + kc * 32 + quad * 8);
            af2[mt] = *(const v8s*)(w2 + (mt * 16 + l15) * C + kc * 32 + quad * 8);
        }
        const u16* Lb = LS + (kc & 1) * 4160;
#pragma unroll
        for (int nt = 0; nt < 2; ++nt) {
            const int p = pw + nt * 16 + l15;
            v8s b;
#pragma unroll
            for (int j = 0; j < 8; ++j) b[j] = (short)Lb[(quad * 8 + j) * 130 + p];
#pragma unroll
            for (int mt = 0; mt < 4; ++mt) {
                acc[0][mt][nt] = __builtin_amdgcn_mfma_f32_16x16x32_bf16(af1[mt], b, acc[0][mt][nt], 0, 0, 0);
                acc[1][mt][nt] = __builtin_amdgcn_mfma_f32_16x16x32_bf16(af2[mt], b, acc[1][mt][nt], 0, 0, 0);
            }
        }
        if (kc + 1 < NCH) __syncthreads();
    }
#pragma unroll
    for (int s = 0; s < 2; ++s) {
        __syncthreads();
        const float* bb = s ? b2 : b1;
#pragma unroll
        for (int mt = 0; mt < 4; ++mt)
#pragma unroll
            for (int r = 0; r < 4; ++r) {
                const int h = mt * 16 + quad * 4 + r;
                const float bv = bb[h];
#pragma unroll
                for (int nt = 0; nt < 2; ++nt)
                    LS[h * 130 + pw + nt * 16 + l15] = f2b(acc[s][mt][nt][r] + bv);
            }
        __syncthreads();
        u16* dd = s ? dst2 : dst1;
#pragma unroll
        for (int ps = 0; ps < 4; ++ps) {
            int h = ps * 16 + sr;
            u16x8 v = *(const u16x8*)(LS + h * 130 + so);
            __builtin_nontemporal_store(v, (u16x8*)(dd + (size_t)h * NN + P0 + so));
        }
    }
}

// ---------------------------------------------------------------------------
// K6: m4 conv (r9, proven): per-block BN stat/trace partials, no atomics.
template<int NCH>
__global__ __launch_bounds__(256) void conv4_t(
    const u16* __restrict__ mult, const u16* __restrict__ u,
    const float* __restrict__ sc, const float* __restrict__ sh,
    const u16* __restrict__ w, const float* __restrict__ bias,
    u16* __restrict__ dst,
    float* __restrict__ psum, float* __restrict__ psq, float* __restrict__ ptr)
{
    __shared__ u16 LS[8320];
    __shared__ float R1[64][4], R2[64][4];
    const int K = NCH * 32;
    const int t = threadIdx.x;
    const int P0 = blockIdx.x * 128;
    const int lane = t & 63, wave = t >> 6;
    const int l15 = lane & 15, quad = lane >> 4;
    const int pw = wave * 32;
    const int sr = t >> 4;
    const int so = (t & 15) * 8;

    u16x8 pf[NCH][2];
#pragma unroll
    for (int kc = 0; kc < NCH; ++kc)
#pragma unroll
        for (int ps = 0; ps < 2; ++ps) {
            int cg = kc * 32 + ps * 16 + sr;
            const u16* gp = (cg < 64) ? (mult + (size_t)cg * NN + P0 + so)
                                      : (u + (size_t)(cg - 64) * NN + P0 + so);
            pf[kc][ps] = *(const u16x8*)gp;
        }

    v4f acc[4][2];
#pragma unroll
    for (int mt = 0; mt < 4; ++mt)
#pragma unroll
        for (int nt = 0; nt < 2; ++nt) acc[mt][nt] = (v4f){0.f, 0.f, 0.f, 0.f};

#pragma unroll
    for (int ps = 0; ps < 2; ++ps)
        *(u16x8*)(LS + (ps * 16 + sr) * 130 + so) = pf[0][ps];
    __syncthreads();
#pragma unroll
    for (int kc = 0; kc < NCH; ++kc) {
        if (kc + 1 < NCH) {
            u16* Ln = LS + ((kc + 1) & 1) * 4160;
#pragma unroll
            for (int ps = 0; ps < 2; ++ps) {
                int c = ps * 16 + sr;
                int cg = (kc + 1) * 32 + c;
                u16x8 v = pf[kc + 1][ps];
                if (cg >= 64 && sc) {
                    float s = sc[cg - 64], f = sh[cg - 64];
#pragma unroll
                    for (int j = 0; j < 8; ++j) v[j] = f2b(b2f(v[j]) * s + f);
                }
                *(u16x8*)(Ln + c * 130 + so) = v;
            }
        }
        v8s af[4];
#pragma unroll
        for (int mt = 0; mt < 4; ++mt)
            af[mt] = *(const v8s*)(w + (mt * 16 + l15) * K + kc * 32 + quad * 8);
        const u16* Lb = LS + (kc & 1) * 4160;
#pragma unroll
        for (int nt = 0; nt < 2; ++nt) {
            const int p = pw + nt * 16 + l15;
            v8s b;
#pragma unroll
            for (int j = 0; j < 8; ++j) b[j] = (short)Lb[(quad * 8 + j) * 130 + p];
#pragma unroll
            for (int mt = 0; mt < 4; ++mt)
                acc[mt][nt] = __builtin_amdgcn_mfma_f32_16x16x32_bf16(af[mt], b, acc[mt][nt], 0, 0, 0);
        }
        if (kc + 1 < NCH) __syncthreads();
    }
    __syncthreads();
#pragma unroll
    for (int mt = 0; mt < 4; ++mt)
#pragma unroll
        for (int r = 0; r < 4; ++r) {
            const int h = mt * 16 + quad * 4 + r;
            const float bv = bias[h];
#pragma unroll
            for (int nt = 0; nt < 2; ++nt)
                LS[h * 130 + pw + nt * 16 + l15] = f2b(acc[mt][nt][r] + bv);
        }
    __syncthreads();
    {
        int c = t >> 2, q = t & 3;
        const u16* row = LS + c * 130 + q * 32;
        float s = 0.f, s2 = 0.f;
#pragma unroll
        for (int i = 0; i < 32; ++i) { float v = b2f(row[i]); s += v; s2 += v * v; }
        R1[c][q] = s; R2[c][q] = s2;
    }
    __syncthreads();
    {
        int i = P0 >> 9, j0 = P0 & 511;
        int blk = blockIdx.x;
        if (t < 64) {
            psum[t * 2048 + blk] = R1[t][0] + R1[t][1] + R1[t][2] + R1[t][3];
            psq[t * 2048 + blk]  = R2[t][0] + R2[t][1] + R2[t][2] + R2[t][3];
            if (j0 <= i && i < j0 + 128) ptr[t * 512 + i] = b2f(LS[t * 130 + (i - j0)]);
        }
    }
#pragma unroll
    for (int ps = 0; ps < 4; ++ps) {
        int h = ps * 16 + sr;
        u16x8 v = *(const u16x8*)(LS + h * 130 + so);
        __builtin_nontemporal_store(v, (u16x8*)(dst + (size_t)h * NN + P0 + so));
    }
}

// ---------------------------------------------------------------------------
// K7 v4: batched per-channel GEMM. Wave tile = 128i x 32j (waves partition j):
// each LB element gathered by exactly ONE wave (halves scalar LDS reads).
__global__ __launch_bounds__(256) void bmm_mfma(const u16* __restrict__ Aall,
                                                const u16* __restrict__ Ball,
                                                u16* __restrict__ Call) {
    __shared__ u16 LA[128 * 72];
    __shared__ u16 LB[64 * 130];
    const int h = blockIdx.y;
    const int tx = blockIdx.x & 3, ty = blockIdx.x >> 2;
    const int t = threadIdx.x;
    const int lane = t & 63, wave = t >> 6;
    const int l15 = lane & 15, quad = lane >> 4;
    const int jb = wave * 32;                       // wave's 32-wide j slice
    const u16* Ap = Aall + (size_t)h * NN + (size_t)ty * 128 * 512;
    const u16* Bp = Ball + (size_t)h * NN + tx * 128;

    const int srow = t >> 3;
    const int scol = (t & 7) * 8;
    const int bkr = t >> 4;
    const int bjg = (t & 15) * 8;

    v4f acc[8][2];
#pragma unroll
    for (int mt = 0; mt < 8; ++mt)
#pragma unroll
        for (int nt = 0; nt < 2; ++nt) acc[mt][nt] = (v4f){0.f, 0.f, 0.f, 0.f};

    v8s ra[4], rb[4];
#pragma unroll
    for (int i = 0; i < 4; ++i) {
        ra[i] = *(const v8s*)(Ap + (size_t)(i * 32 + srow) * 512 + scol);
        rb[i] = *(const v8s*)(Bp + (size_t)(i * 16 + bkr) * 512 + bjg);
    }

    for (int ck = 0; ck < 8; ++ck) {
#pragma unroll
        for (int i = 0; i < 4; ++i) {
            *(v8s*)(LA + (i * 32 + srow) * 72 + scol) = ra[i];
            *(v8s*)(LB + (i * 16 + bkr) * 130 + bjg) = rb[i];
        }
        __syncthreads();
        if (ck < 7) {
            const int k0 = (ck + 1) * 64;
#pragma unroll
            for (int i = 0; i < 4; ++i) {
                ra[i] = *(const v8s*)(Ap + (size_t)(i * 32 + srow) * 512 + k0 + scol);
                rb[i] = *(const v8s*)(Bp + (size_t)(k0 + i * 16 + bkr) * 512 + bjg);
            }
        }
#pragma unroll
        for (int kk = 0; kk < 2; ++kk) {
            v8s b[2];
#pragma unroll
            for (int nt = 0; nt < 2; ++nt) {
                const int j = jb + nt * 16 + l15;
#pragma unroll
                for (int jj = 0; jj < 8; ++jj)
                    b[nt][jj] = (short)LB[(kk * 32 + quad * 8 + jj) * 130 + j];
            }
#pragma unroll
            for (int mh = 0; mh < 2; ++mh) {
                v8s a[4];
#pragma unroll
                for (int m = 0; m < 4; ++m)
                    a[m] = *(const v8s*)(LA + ((mh * 4 + m) * 16 + l15) * 72 + kk * 32 + quad * 8);
#pragma unroll
                for (int m = 0; m < 4; ++m)
#pragma unroll
                    for (int nt = 0; nt < 2; ++nt)
                        acc[mh * 4 + m][nt] = __builtin_amdgcn_mfma_f32_16x16x32_bf16(a[m], b[nt], acc[mh * 4 + m][nt], 0, 0, 0);
            }
        }
        __syncthreads();
    }

    u16* Cp = Call + (size_t)h * NN;
#pragma unroll
    for (int mt = 0; mt < 8; ++mt)
#pragma unroll
        for (int r = 0; r < 4; ++r) {
            const int i = ty * 128 + mt * 16 + quad * 4 + r;
#pragma unroll
            for (int nt = 0; nt < 2; ++nt) {
                const int j = tx * 128 + jb + nt * 16 + l15;
                Cp[i * 512 + j] = f2b(acc[mt][nt][r]);
            }
        }
}

// ---------------------------------------------------------------------------
// K11: reduce per-block partials; BN scale/shift; normalized totals & trace
// into the layer's trace/total slot (ttl[0..63]=trace, ttl[64..127]=total).
__global__ __launch_bounds__(256) void bn_finalize(
    const float* __restrict__ psum, const float* __restrict__ psq,
    const float* __restrict__ ptr,
    const float* __restrict__ g, const float* __restrict__ b,
    float* __restrict__ scale, float* __restrict__ shift,
    float* __restrict__ ttl) {
    int c = blockIdx.x, t = threadIdx.x;
    float s = 0.f, q = 0.f, tr = 0.f;
    for (int k = t; k < 2048; k += 256) { s += psum[c * 2048 + k]; q += psq[c * 2048 + k]; }
    for (int k = t; k < 512; k += 256) tr += ptr[c * 512 + k];
    for (int off = 32; off > 0; off >>= 1) {
        s += __shfl_down(s, off); q += __shfl_down(q, off); tr += __shfl_down(tr, off);
    }
    __shared__ float r1[4], r2[4], r3[4];
    if ((t & 63) == 0) { r1[t >> 6] = s; r2[t >> 6] = q; r3[t >> 6] = tr; }
    __syncthreads();
    if (t == 0) {
        s = r1[0] + r1[1] + r1[2] + r1[3];
        q = r2[0] + r2[1] + r2[2] + r2[3];
        tr = r3[0] + r3[1] + r3[2] + r3[3];
        float mean = s * (1.f / 262144.f);
        float var = q * (1.f / 262144.f) - mean * mean;
        float sc = g[c] * rsqrtf(fmaxf(var, 0.f) + 1e-5f);
        float sh = b[c] - mean * sc;
        scale[c] = sc;
        shift[c] = sh;
        ttl[64 + c] = sc * s + 262144.f * sh;   // total
        ttl[c]      = sc * tr + 512.f * sh;     // trace
    }
}

// ---------------------------------------------------------------------------
// K12: all 4 extractors + head in one kernel. tt = [4][128] (trace|total).
__global__ void tail_kernel(const float* __restrict__ tt,
                            const float* __restrict__ np1w, const float* __restrict__ np1b,
                            const float* __restrict__ np2w, const float* __restrict__ np3w,
                            const float* __restrict__ fe1w, const float* __restrict__ fe1b,
                            const float* __restrict__ fe2w, const float* __restrict__ fe3w,
                            const float* __restrict__ acw, const float* __restrict__ acb,
                            const float* __restrict__ flw, const float* __restrict__ flb,
                            float* __restrict__ out) {
    __shared__ float xo[64], x[64], x2[64], l[10];
    int t = threadIdx.x;  // 64
    float oa = 0.f;
    for (int li = 0; li < 4; ++li) {
        int C = (li == 0) ? 32 : 64;
        const float* w1 = (li == 0) ? np1w : fe1w + (li - 1) * 4096;
        const float* b1 = (li == 0) ? np1b : fe1b + (li - 1) * 64;
        const float* w2 = (li == 0) ? np2w : fe2w + (li - 1) * 4096;
        const float* w3 = (li == 0) ? np3w : fe3w + (li - 1) * 4096;
        const float* tr = tt + li * 128;
        const float* to = tt + li * 128 + 64;
        float s1 = b1[t];
        for (int c = 0; c < C; ++c) s1 += (tr[c] * (1.f / 512.f)) * w1[t * C + c];
        float s2 = 0.f;
        for (int c = 0; c < C; ++c) s2 += ((to[c] - tr[c]) * (1.f / (512.f * 511.f))) * w2[t * C + c];
        float o = s1 + s2;
        xo[t] = o;
        __syncthreads();
        float s3 = 0.f;
        for (int f = 0; f < 64; ++f) s3 += fmaxf(xo[f], 0.f) * w3[t * 64 + f];
        oa += o + s3;
        __syncthreads();
    }
    x[t] = fmaxf(oa, 0.f) * (1.f / 3.f);
    __syncthreads();
    float y = acb[t];
    for (int f = 0; f < 64; ++f) y += x[f] * acw[t * 64 + f];
    x2[t] = x[t] + fmaxf(y, 0.f);
    __syncthreads();
    if (t < 10) {
        float s = flb[t];
        for (int f = 0; f < 64; ++f) s += x2[f] * flw[t * 64 + f];
        l[t] = s;
    }
    __syncthreads();
    if (t == 0) {
        float m = l[0];
        for (int i = 1; i < 10; ++i) m = fmaxf(m, l[i]);
        float se = 0.f;
        for (int i = 0; i < 10; ++i) se += expf(l[i] - m);
        float ls = m + logf(se);
        for (int i = 0; i < 10; ++i) out[i] = l[i] - ls;
    }
}

// ---------------------------------------------------------------------------
extern "C" void kernel_launch(void* const* d_in, const int* in_sizes, int n_in,
                              void* d_out, int out_size, void* d_ws, size_t ws_size,
                              hipStream_t stream) {
    float* out = (float*)d_out;

    static const int exp_sizes[28] = {
        8192, 32768,
        2048, 64, 2048, 4096,
        2048, 64, 2048, 64, 6144, 64,
        8192, 128, 8192, 128, 16384, 128,
        192, 192,
        12288, 192, 12288, 12288,
        4096, 64, 640, 10
    };
    bool ok = (n_in == 28);
    if (ok) for (int i = 0; i < 28; ++i) if (in_sizes[i] != exp_sizes[i]) ok = false;
    if (!ok) { sentinel_kernel<<<1, 64, 0, stream>>>(out, -5.0f); return; }

    const size_t RSZ = (size_t)NN * 64 * 2;            // 33.55 MB per region
    const size_t BIG_OFF = 8192 + 90112;               // control (8KB) + bf16 weight arena
    if (ws_size < BIG_OFF + 4 * RSZ) {
        sentinel_kernel<<<1, 64, 0, stream>>>(out, -7.0f);
        return;
    }

    const float* x     = (const float*)d_in[0];
    const int*   ei    = (const int*)d_in[1];
    const float* np1w  = (const float*)d_in[2];
    const float* np1b  = (const float*)d_in[3];
    const float* np2w  = (const float*)d_in[4];
    const float* np3w  = (const float*)d_in[5];
    const float* c0m1b = (const float*)d_in[7];
    const float* c0m2b = (const float*)d_in[9];
    const float* c0m4b = (const float*)d_in[11];
    const float* cm1b  = (const float*)d_in[13];
    const float* cm2b  = (const float*)d_in[15];
    const float* cm4b  = (const float*)d_in[17];
    const float* bng   = (const float*)d_in[18];
    const float* bnb   = (const float*)d_in[19];
    const float* fe1w  = (const float*)d_in[20];
    const float* fe1b  = (const float*)d_in[21];
    const float* fe2w  = (const float*)d_in[22];
    const float* fe3w  = (const float*)d_in[23];
    const float* acw   = (const float*)d_in[24];
    const float* acb   = (const float*)d_in[25];
    const float* flw   = (const float*)d_in[26];
    const float* flb   = (const float*)d_in[27];

    char* ws = (char*)d_ws;
    float* small = (float*)ws;
    float* tt    = small;          // [4][128]: per-layer trace(64)|total(64)
    float* scl   = small + 512;
    float* shf   = small + 576;

    u16* arena = (u16*)(ws + 8192);          // bf16 conv weights, 43008 elements

    char* big = ws + BIG_OFF;
    u16* S0 = (u16*)(big + 0 * RSZ);
    u16* S1 = (u16*)(big + 1 * RSZ);
    u16* S2 = (u16*)(big + 2 * RSZ);
    u16* S3 = (u16*)(big + 3 * RSZ);
    float* Abuf = (float*)S2;                // fp32 staging, dead after finalize_u0

    // BN partial buffers live in S2 (o2 slot) — dead between bmm and next conv12.
    float* psum = (float*)S2;                          // 64*2048
    float* psq  = psum + 64 * 2048;                    // 64*2048
    float* ptr  = psq + 64 * 2048;                     // 64*512

    hipMemsetAsync(small, 0, 4096, stream);
    hipMemsetAsync(Abuf, 0, (size_t)NN * 32 * 4, stream);

    cvt_weights<<<168, 256, 0, stream>>>((const float*)d_in[6], (const float*)d_in[8],
                                         (const float*)d_in[10], (const float*)d_in[12],
                                         (const float*)d_in[14], (const float*)d_in[16], arena);
    scatter_edges<<<2048, 256, 0, stream>>>(x, ei, Abuf);
    finalize_u0<<<1024, 256, 0, stream>>>(Abuf, S0, tt + 64);        // total -> tt[0][64..]
    trace_raw_cm<<<32, 256, 0, stream>>>(S0, tt);                    // trace -> tt[0][0..31]

    u16* U[3]  = { S0, S1, S0 };
    u16* O1[3] = { S1, S0, S1 };
    u16* O2[3] = { S2, S2, S2 };
    u16* R[3]  = { S1, S0, S1 };

    const float *aff_s = nullptr, *aff_h = nullptr;

    for (int l = 0; l < 3; ++l) {
        int Cin = (l == 0) ? 32 : 64;
        const u16 *w1b, *w2b, *w4b;
        const float *b1, *b2, *b4;
        if (l == 0) {
            w1b = arena;            b1 = c0m1b;
            w2b = arena + 2048;     b2 = c0m2b;
            w4b = arena + 4096;     b4 = c0m4b;
        } else {
            int m = l - 1;
            w1b = arena + 10240 + m * 4096;  b1 = cm1b + m * 64;
            w2b = arena + 18432 + m * 4096;  b2 = cm2b + m * 64;
            w4b = arena + 26624 + m * 8192;  b4 = cm4b + m * 64;
        }
        if (Cin == 32)
            conv12_t<1><<<2048, 256, 0, stream>>>(U[l], aff_s, aff_h, w1b, b1, w2b, b2, O1[l], O2[l]);
        else
            conv12_t<2><<<2048, 256, 0, stream>>>(U[l], aff_s, aff_h, w1b, b1, w2b, b2, O1[l], O2[l]);
        bmm_mfma<<<dim3(16, 64), 256, 0, stream>>>(O1[l], O2[l], S3);
        if (Cin == 32)
            conv4_t<3><<<2048, 256, 0, stream>>>(S3, U[l], aff_s, aff_h, w4b, b4, R[l], psum, psq, ptr);
        else
            conv4_t<4><<<2048, 256, 0, stream>>>(S3, U[l], aff_s, aff_h, w4b, b4, R[l], psum, psq, ptr);
        bn_finalize<<<64, 256, 0, stream>>>(psum, psq, ptr, bng + l * 64, bnb + l * 64,
                                            scl, shf, tt + (l + 1) * 128);
        aff_s = scl; aff_h = shf;
    }
    tail_kernel<<<1, 64, 0, stream>>>(tt, np1w, np1b, np2w, np3w,
                                      fe1w, fe1b, fe2w, fe3w,
                                      acw, acb, flw, flb, out);
}

// Round 11
// 470.999 us; speedup vs baseline: 2.4429x; 1.0879x over previous
//
#include <hip/hip_runtime.h>
#include <hip/hip_bf16.h>

// Problem dims (fixed)
#define Nn   512
#define NN   262144        // N*N positions
#define EDG  16384

typedef unsigned short u16;
typedef short v8s __attribute__((ext_vector_type(8)));   // 8 bf16 lanes (4 VGPR)
typedef float v4f __attribute__((ext_vector_type(4)));
typedef u16 u16x8 __attribute__((ext_vector_type(8)));

__device__ __forceinline__ float b2f(u16 u) {
    union { unsigned int i; float f; } v; v.i = ((unsigned int)u) << 16; return v.f;
}
__device__ __forceinline__ u16 f2b(float f) {
    union { float f; unsigned int i; } v; v.f = f;
    unsigned int r = (v.i + 0x7FFFu + ((v.i >> 16) & 1u)) >> 16;
    return (u16)r;
}

// ---------------------------------------------------------------------------
__global__ void sentinel_kernel(float* __restrict__ out, float val) {
    if (threadIdx.x < 10) out[threadIdx.x] = val;
}

// ---------------------------------------------------------------------------
// K0: convert the 6 conv weight tensors (fp32) into one bf16 arena.
__global__ void cvt_weights(const float* __restrict__ s0, const float* __restrict__ s1,
                            const float* __restrict__ s2, const float* __restrict__ s3,
                            const float* __restrict__ s4, const float* __restrict__ s5,
                            u16* __restrict__ dst) {
    int t = blockIdx.x * 256 + threadIdx.x;
    if (t >= 43008) return;
    float v;
    if      (t < 2048)  v = s0[t];
    else if (t < 4096)  v = s1[t - 2048];
    else if (t < 10240) v = s2[t - 4096];
    else if (t < 18432) v = s3[t - 10240];
    else if (t < 26624) v = s4[t - 18432];
    else                v = s5[t - 26624];
    dst[t] = f2b(v);
}

// ---------------------------------------------------------------------------
// K1: scatter edges into A (fp32, pos-major [p][32]); x is fp32 [512][16]
__global__ void scatter_edges(const float* __restrict__ x, const int* __restrict__ ei,
                              float* __restrict__ A) {
    int t = blockIdx.x * 256 + threadIdx.x;
    if (t >= EDG * 32) return;
    int e = t >> 5, c = t & 31;
    int s = ei[e], d = ei[EDG + e];
    float v = (c < 16) ? x[s * 16 + c] : x[d * 16 + (c - 16)];
    atomicAdd(A + ((size_t)s * Nn + d) * 32 + c, v);
}

// ---------------------------------------------------------------------------
// K2: A fp32 pos-major [p][32] -> u0 CHANNEL-MAJOR bf16 [32][NN]; totals into tt0[64..]
__global__ __launch_bounds__(256) void finalize_u0(const float* __restrict__ A,
                                                   u16* __restrict__ u0,
                                                   float* __restrict__ total) {
    __shared__ u16 L[32 * 258];
    __shared__ float red[4][32];
    int t = threadIdx.x;
    int p0 = blockIdx.x * 256;
    const float* Ar = A + (size_t)(p0 + t) * 32;
    float v[32];
#pragma unroll
    for (int c = 0; c < 32; ++c) v[c] = Ar[c];
#pragma unroll
    for (int c = 0; c < 32; ++c) L[c * 258 + t] = f2b(v[c]);
    int wv = t >> 6;
#pragma unroll
    for (int c = 0; c < 32; ++c) {
        float r = v[c];
        for (int off = 32; off > 0; off >>= 1) r += __shfl_down(r, off);
        if ((t & 63) == 0) red[wv][c] = r;
    }
    __syncthreads();
    if (t < 32) atomicAdd(total + t, red[0][t] + red[1][t] + red[2][t] + red[3][t]);
    int off = (t & 31) * 8, rb = t >> 5;
#pragma unroll
    for (int pass = 0; pass < 4; ++pass) {
        int c = pass * 8 + rb;
        u16x8 w = *(const u16x8*)(L + c * 258 + off);
        *(u16x8*)(u0 + (size_t)c * NN + p0 + off) = w;
    }
}

// ---------------------------------------------------------------------------
// K3: trace of channel-major activation; grid = C blocks.
__global__ void trace_raw_cm(const u16* __restrict__ ucm, float* __restrict__ trraw) {
    int c = blockIdx.x, t = threadIdx.x;
    const u16* base = ucm + (size_t)c * NN;
    float s = b2f(base[(size_t)(2 * t) * 513]) + b2f(base[(size_t)(2 * t + 1) * 513]);
    for (int off = 32; off > 0; off >>= 1) s += __shfl_down(s, off);
    __shared__ float r[4];
    if ((t & 63) == 0) r[t >> 6] = s;
    __syncthreads();
    if (t == 0) trraw[c] = r[0] + r[1] + r[2] + r[3];
}

// ---------------------------------------------------------------------------
// K5: merged conv1+conv2 (r9, proven). Block = 128 positions.
template<int NCH>
__global__ __launch_bounds__(256) void conv12_t(
    const u16* __restrict__ src,
    const float* __restrict__ sc, const float* __restrict__ sh,
    const u16* __restrict__ w1, const float* __restrict__ b1,
    const u16* __restrict__ w2, const float* __restrict__ b2,
    u16* __restrict__ dst1, u16* __restrict__ dst2)
{
    __shared__ u16 LS[8320];
    const int C = NCH * 32;
    const int t = threadIdx.x;
    const int P0 = blockIdx.x * 128;
    const int lane = t & 63, wave = t >> 6;
    const int l15 = lane & 15, quad = lane >> 4;
    const int pw = wave * 32;
    const int sr = t >> 4;
    const int so = (t & 15) * 8;

    u16x8 pf[NCH][2];
#pragma unroll
    for (int kc = 0; kc < NCH; ++kc)
#pragma unroll
        for (int ps = 0; ps < 2; ++ps)
            pf[kc][ps] = *(const u16x8*)(src + (size_t)(kc * 32 + ps * 16 + sr) * NN + P0 + so);

    v4f acc[2][4][2];
#pragma unroll
    for (int s = 0; s < 2; ++s)
#pragma unroll
        for (int mt = 0; mt < 4; ++mt)
#pragma unroll
            for (int nt = 0; nt < 2; ++nt) acc[s][mt][nt] = (v4f){0.f, 0.f, 0.f, 0.f};

    {
        u16* Ln = LS;
#pragma unroll
        for (int ps = 0; ps < 2; ++ps) {
            int c = ps * 16 + sr;
            u16x8 v = pf[0][ps];
            if (sc) {
                float s = sc[c], f = sh[c];
#pragma unroll
                for (int j = 0; j < 8; ++j) v[j] = f2b(b2f(v[j]) * s + f);
            }
            *(u16x8*)(Ln + c * 130 + so) = v;
        }
    }
    __syncthreads();
#pragma unroll
    for (int kc = 0; kc < NCH; ++kc) {
        if (kc + 1 < NCH) {
            u16* Ln = LS + ((kc + 1) & 1) * 4160;
#pragma unroll
            for (int ps = 0; ps < 2; ++ps) {
                int c = ps * 16 + sr;
                int cg = (kc + 1) * 32 + c;
                u16x8 v = pf[kc + 1][ps];
                if (sc) {
                    float s = sc[cg], f = sh[cg];
#pragma unroll
                    for (int j = 0; j < 8; ++j) v[j] = f2b(b2f(v[j]) * s + f);
                }
                *(u16x8*)(Ln + c * 130 + so) = v;
            }
        }
        v8s af1[4], af2[4];
#pragma unroll
        for (int mt = 0; mt < 4; ++mt) {
            af1[mt] = *(const v8s*)(w1 + (mt * 16 + l15) * C + kc * 32 + quad * 8);
            af2[mt] = *(const v8s*)(w2 + (mt * 16 + l15) * C + kc * 32 + quad * 8);
        }
        const u16* Lb = LS + (kc & 1) * 4160;
#pragma unroll
        for (int nt = 0; nt < 2; ++nt) {
            const int p = pw + nt * 16 + l15;
            v8s b;
#pragma unroll
            for (int j = 0; j < 8; ++j) b[j] = (short)Lb[(quad * 8 + j) * 130 + p];
#pragma unroll
            for (int mt = 0; mt < 4; ++mt) {
                acc[0][mt][nt] = __builtin_amdgcn_mfma_f32_16x16x32_bf16(af1[mt], b, acc[0][mt][nt], 0, 0, 0);
                acc[1][mt][nt] = __builtin_amdgcn_mfma_f32_16x16x32_bf16(af2[mt], b, acc[1][mt][nt], 0, 0, 0);
            }
        }
        if (kc + 1 < NCH) __syncthreads();
    }
#pragma unroll
    for (int s = 0; s < 2; ++s) {
        __syncthreads();
        const float* bb = s ? b2 : b1;
#pragma unroll
        for (int mt = 0; mt < 4; ++mt)
#pragma unroll
            for (int r = 0; r < 4; ++r) {
                const int h = mt * 16 + quad * 4 + r;
                const float bv = bb[h];
#pragma unroll
                for (int nt = 0; nt < 2; ++nt)
                    LS[h * 130 + pw + nt * 16 + l15] = f2b(acc[s][mt][nt][r] + bv);
            }
        __syncthreads();
        u16* dd = s ? dst2 : dst1;
#pragma unroll
        for (int ps = 0; ps < 4; ++ps) {
            int h = ps * 16 + sr;
            u16x8 v = *(const u16x8*)(LS + h * 130 + so);
            __builtin_nontemporal_store(v, (u16x8*)(dd + (size_t)h * NN + P0 + so));
        }
    }
}

// ---------------------------------------------------------------------------
// K6: m4 conv (r9, proven): per-block BN stat/trace partials, no atomics.
template<int NCH>
__global__ __launch_bounds__(256) void conv4_t(
    const u16* __restrict__ mult, const u16* __restrict__ u,
    const float* __restrict__ sc, const float* __restrict__ sh,
    const u16* __restrict__ w, const float* __restrict__ bias,
    u16* __restrict__ dst,
    float* __restrict__ psum, float* __restrict__ psq, float* __restrict__ ptr)
{
    __shared__ u16 LS[8320];
    __shared__ float R1[64][4], R2[64][4];
    const int K = NCH * 32;
    const int t = threadIdx.x;
    const int P0 = blockIdx.x * 128;
    const int lane = t & 63, wave = t >> 6;
    const int l15 = lane & 15, quad = lane >> 4;
    const int pw = wave * 32;
    const int sr = t >> 4;
    const int so = (t & 15) * 8;

    u16x8 pf[NCH][2];
#pragma unroll
    for (int kc = 0; kc < NCH; ++kc)
#pragma unroll
        for (int ps = 0; ps < 2; ++ps) {
            int cg = kc * 32 + ps * 16 + sr;
            const u16* gp = (cg < 64) ? (mult + (size_t)cg * NN + P0 + so)
                                      : (u + (size_t)(cg - 64) * NN + P0 + so);
            pf[kc][ps] = *(const u16x8*)gp;
        }

    v4f acc[4][2];
#pragma unroll
    for (int mt = 0; mt < 4; ++mt)
#pragma unroll
        for (int nt = 0; nt < 2; ++nt) acc[mt][nt] = (v4f){0.f, 0.f, 0.f, 0.f};

#pragma unroll
    for (int ps = 0; ps < 2; ++ps)
        *(u16x8*)(LS + (ps * 16 + sr) * 130 + so) = pf[0][ps];
    __syncthreads();
#pragma unroll
    for (int kc = 0; kc < NCH; ++kc) {
        if (kc + 1 < NCH) {
            u16* Ln = LS + ((kc + 1) & 1) * 4160;
#pragma unroll
            for (int ps = 0; ps < 2; ++ps) {
                int c = ps * 16 + sr;
                int cg = (kc + 1) * 32 + c;
                u16x8 v = pf[kc + 1][ps];
                if (cg >= 64 && sc) {
                    float s = sc[cg - 64], f = sh[cg - 64];
#pragma unroll
                    for (int j = 0; j < 8; ++j) v[j] = f2b(b2f(v[j]) * s + f);
                }
                *(u16x8*)(Ln + c * 130 + so) = v;
            }
        }
        v8s af[4];
#pragma unroll
        for (int mt = 0; mt < 4; ++mt)
            af[mt] = *(const v8s*)(w + (mt * 16 + l15) * K + kc * 32 + quad * 8);
        const u16* Lb = LS + (kc & 1) * 4160;
#pragma unroll
        for (int nt = 0; nt < 2; ++nt) {
            const int p = pw + nt * 16 + l15;
            v8s b;
#pragma unroll
            for (int j = 0; j < 8; ++j) b[j] = (short)Lb[(quad * 8 + j) * 130 + p];
#pragma unroll
            for (int mt = 0; mt < 4; ++mt)
                acc[mt][nt] = __builtin_amdgcn_mfma_f32_16x16x32_bf16(af[mt], b, acc[mt][nt], 0, 0, 0);
        }
        if (kc + 1 < NCH) __syncthreads();
    }
    __syncthreads();
#pragma unroll
    for (int mt = 0; mt < 4; ++mt)
#pragma unroll
        for (int r = 0; r < 4; ++r) {
            const int h = mt * 16 + quad * 4 + r;
            const float bv = bias[h];
#pragma unroll
            for (int nt = 0; nt < 2; ++nt)
                LS[h * 130 + pw + nt * 16 + l15] = f2b(acc[mt][nt][r] + bv);
        }
    __syncthreads();
    {
        int c = t >> 2, q = t & 3;
        const u16* row = LS + c * 130 + q * 32;
        float s = 0.f, s2 = 0.f;
#pragma unroll
        for (int i = 0; i < 32; ++i) { float v = b2f(row[i]); s += v; s2 += v * v; }
        R1[c][q] = s; R2[c][q] = s2;
    }
    __syncthreads();
    {
        int i = P0 >> 9, j0 = P0 & 511;
        int blk = blockIdx.x;
        if (t < 64) {
            psum[t * 2048 + blk] = R1[t][0] + R1[t][1] + R1[t][2] + R1[t][3];
            psq[t * 2048 + blk]  = R2[t][0] + R2[t][1] + R2[t][2] + R2[t][3];
            if (j0 <= i && i < j0 + 128) ptr[t * 512 + i] = b2f(LS[t * 130 + (i - j0)]);
        }
    }
#pragma unroll
    for (int ps = 0; ps < 4; ++ps) {
        int h = ps * 16 + sr;
        u16x8 v = *(const u16x8*)(LS + h * 130 + so);
        __builtin_nontemporal_store(v, (u16x8*)(dst + (size_t)h * NN + P0 + so));
    }
}

// ---------------------------------------------------------------------------
// K7 v4: batched per-channel GEMM (r10, proven). Wave tile = 128i x 32j.
__global__ __launch_bounds__(256) void bmm_mfma(const u16* __restrict__ Aall,
                                                const u16* __restrict__ Ball,
                                                u16* __restrict__ Call) {
    __shared__ u16 LA[128 * 72];
    __shared__ u16 LB[64 * 130];
    const int h = blockIdx.y;
    const int tx = blockIdx.x & 3, ty = blockIdx.x >> 2;
    const int t = threadIdx.x;
    const int lane = t & 63, wave = t >> 6;
    const int l15 = lane & 15, quad = lane >> 4;
    const int jb = wave * 32;
    const u16* Ap = Aall + (size_t)h * NN + (size_t)ty * 128 * 512;
    const u16* Bp = Ball + (size_t)h * NN + tx * 128;

    const int srow = t >> 3;
    const int scol = (t & 7) * 8;
    const int bkr = t >> 4;
    const int bjg = (t & 15) * 8;

    v4f acc[8][2];
#pragma unroll
    for (int mt = 0; mt < 8; ++mt)
#pragma unroll
        for (int nt = 0; nt < 2; ++nt) acc[mt][nt] = (v4f){0.f, 0.f, 0.f, 0.f};

    v8s ra[4], rb[4];
#pragma unroll
    for (int i = 0; i < 4; ++i) {
        ra[i] = *(const v8s*)(Ap + (size_t)(i * 32 + srow) * 512 + scol);
        rb[i] = *(const v8s*)(Bp + (size_t)(i * 16 + bkr) * 512 + bjg);
    }

    for (int ck = 0; ck < 8; ++ck) {
#pragma unroll
        for (int i = 0; i < 4; ++i) {
            *(v8s*)(LA + (i * 32 + srow) * 72 + scol) = ra[i];
            *(v8s*)(LB + (i * 16 + bkr) * 130 + bjg) = rb[i];
        }
        __syncthreads();
        if (ck < 7) {
            const int k0 = (ck + 1) * 64;
#pragma unroll
            for (int i = 0; i < 4; ++i) {
                ra[i] = *(const v8s*)(Ap + (size_t)(i * 32 + srow) * 512 + k0 + scol);
                rb[i] = *(const v8s*)(Bp + (size_t)(k0 + i * 16 + bkr) * 512 + bjg);
            }
        }
#pragma unroll
        for (int kk = 0; kk < 2; ++kk) {
            v8s b[2];
#pragma unroll
            for (int nt = 0; nt < 2; ++nt) {
                const int j = jb + nt * 16 + l15;
#pragma unroll
                for (int jj = 0; jj < 8; ++jj)
                    b[nt][jj] = (short)LB[(kk * 32 + quad * 8 + jj) * 130 + j];
            }
#pragma unroll
            for (int mh = 0; mh < 2; ++mh) {
                v8s a[4];
#pragma unroll
                for (int m = 0; m < 4; ++m)
                    a[m] = *(const v8s*)(LA + ((mh * 4 + m) * 16 + l15) * 72 + kk * 32 + quad * 8);
#pragma unroll
                for (int m = 0; m < 4; ++m)
#pragma unroll
                    for (int nt = 0; nt < 2; ++nt)
                        acc[mh * 4 + m][nt] = __builtin_amdgcn_mfma_f32_16x16x32_bf16(a[m], b[nt], acc[mh * 4 + m][nt], 0, 0, 0);
            }
        }
        __syncthreads();
    }

    u16* Cp = Call + (size_t)h * NN;
#pragma unroll
    for (int mt = 0; mt < 8; ++mt)
#pragma unroll
        for (int r = 0; r < 4; ++r) {
            const int i = ty * 128 + mt * 16 + quad * 4 + r;
#pragma unroll
            for (int nt = 0; nt < 2; ++nt) {
                const int j = tx * 128 + jb + nt * 16 + l15;
                Cp[i * 512 + j] = f2b(acc[mt][nt][r]);
            }
        }
}

// ---------------------------------------------------------------------------
// K11: reduce per-block partials; BN scale/shift; normalized totals & trace.
__global__ __launch_bounds__(256) void bn_finalize(
    const float* __restrict__ psum, const float* __restrict__ psq,
    const float* __restrict__ ptr,
    const float* __restrict__ g, const float* __restrict__ b,
    float* __restrict__ scale, float* __restrict__ shift,
    float* __restrict__ ttl) {
    int c = blockIdx.x, t = threadIdx.x;
    float s = 0.f, q = 0.f, tr = 0.f;
    for (int k = t; k < 2048; k += 256) { s += psum[c * 2048 + k]; q += psq[c * 2048 + k]; }
    for (int k = t; k < 512; k += 256) tr += ptr[c * 512 + k];
    for (int off = 32; off > 0; off >>= 1) {
        s += __shfl_down(s, off); q += __shfl_down(q, off); tr += __shfl_down(tr, off);
    }
    __shared__ float r1[4], r2[4], r3[4];
    if ((t & 63) == 0) { r1[t >> 6] = s; r2[t >> 6] = q; r3[t >> 6] = tr; }
    __syncthreads();
    if (t == 0) {
        s = r1[0] + r1[1] + r1[2] + r1[3];
        q = r2[0] + r2[1] + r2[2] + r2[3];
        tr = r3[0] + r3[1] + r3[2] + r3[3];
        float mean = s * (1.f / 262144.f);
        float var = q * (1.f / 262144.f) - mean * mean;
        float sc = g[c] * rsqrtf(fmaxf(var, 0.f) + 1e-5f);
        float sh = b[c] - mean * sc;
        scale[c] = sc;
        shift[c] = sh;
        ttl[64 + c] = sc * s + 262144.f * sh;   // total
        ttl[c]      = sc * tr + 512.f * sh;     // trace
    }
}

// ---------------------------------------------------------------------------
// K12a: one extractor per block (4 blocks, 256 thr). thread=(h,q): q = c-quarter.
__global__ __launch_bounds__(256) void extractor_par(
    const float* __restrict__ tt,
    const float* __restrict__ np1w, const float* __restrict__ np1b,
    const float* __restrict__ np2w, const float* __restrict__ np3w,
    const float* __restrict__ fe1w, const float* __restrict__ fe1b,
    const float* __restrict__ fe2w, const float* __restrict__ fe3w,
    float* __restrict__ oacc_part) {
    __shared__ float red[64][4];
    __shared__ float xo[64];
    const int li = blockIdx.x;
    const int t = threadIdx.x;
    const int h = t >> 2, q = t & 3;
    const int C = (li == 0) ? 32 : 64;
    const float* w1 = (li == 0) ? np1w : fe1w + (li - 1) * 4096;
    const float* b1 = (li == 0) ? np1b : fe1b + (li - 1) * 64;
    const float* w2 = (li == 0) ? np2w : fe2w + (li - 1) * 4096;
    const float* w3 = (li == 0) ? np3w : fe3w + (li - 1) * 4096;
    const float* tr = tt + li * 128;
    const float* to = tr + 64;
    const int cpq = C >> 2;
    float p = 0.f;
    for (int i = 0; i < cpq; ++i) {
        int c = q * cpq + i;
        p += (tr[c] * (1.f / 512.f)) * w1[h * C + c]
           + ((to[c] - tr[c]) * (1.f / (512.f * 511.f))) * w2[h * C + c];
    }
    red[h][q] = p;
    __syncthreads();
    if (q == 0) xo[h] = b1[h] + red[h][0] + red[h][1] + red[h][2] + red[h][3];
    __syncthreads();
    float o = xo[h];
    float p3 = 0.f;
    for (int i = 0; i < 16; ++i) {
        int f = q * 16 + i;
        p3 += fmaxf(xo[f], 0.f) * w3[h * 64 + f];
    }
    __syncthreads();
    red[h][q] = p3;
    __syncthreads();
    if (q == 0) oacc_part[li * 64 + h] = o + red[h][0] + red[h][1] + red[h][2] + red[h][3];
}

// ---------------------------------------------------------------------------
// K12b: head, 256 threads, 4-way split per output.
__global__ __launch_bounds__(256) void head_par(
    const float* __restrict__ oacc_part,
    const float* __restrict__ acw, const float* __restrict__ acb,
    const float* __restrict__ flw, const float* __restrict__ flb,
    float* __restrict__ out) {
    __shared__ float x[64], x2[64], red[64][4], l[10];
    const int t = threadIdx.x;
    const int h = t >> 2, q = t & 3;
    if (q == 0) {
        float oa = oacc_part[h] + oacc_part[64 + h] + oacc_part[128 + h] + oacc_part[192 + h];
        x[h] = fmaxf(oa, 0.f) * (1.f / 3.f);
    }
    __syncthreads();
    float p = 0.f;
    for (int i = 0; i < 16; ++i) { int f = q * 16 + i; p += x[f] * acw[h * 64 + f]; }
    red[h][q] = p;
    __syncthreads();
    if (q == 0) {
        float y = acb[h] + red[h][0] + red[h][1] + red[h][2] + red[h][3];
        x2[h] = x[h] + fmaxf(y, 0.f);
    }
    __syncthreads();
    if (t < 40) {
        int hh = t >> 2, qq = t & 3;
        float p2 = 0.f;
        for (int i = 0; i < 16; ++i) { int f = qq * 16 + i; p2 += x2[f] * flw[hh * 64 + f]; }
        red[hh][qq] = p2;
    }
    __syncthreads();
    if (t < 10) l[t] = flb[t] + red[t][0] + red[t][1] + red[t][2] + red[t][3];
    __syncthreads();
    if (t == 0) {
        float m = l[0];
        for (int i = 1; i < 10; ++i) m = fmaxf(m, l[i]);
        float se = 0.f;
        for (int i = 0; i < 10; ++i) se += expf(l[i] - m);
        float ls = m + logf(se);
        for (int i = 0; i < 10; ++i) out[i] = l[i] - ls;
    }
}

// ---------------------------------------------------------------------------
extern "C" void kernel_launch(void* const* d_in, const int* in_sizes, int n_in,
                              void* d_out, int out_size, void* d_ws, size_t ws_size,
                              hipStream_t stream) {
    float* out = (float*)d_out;

    static const int exp_sizes[28] = {
        8192, 32768,
        2048, 64, 2048, 4096,
        2048, 64, 2048, 64, 6144, 64,
        8192, 128, 8192, 128, 16384, 128,
        192, 192,
        12288, 192, 12288, 12288,
        4096, 64, 640, 10
    };
    bool ok = (n_in == 28);
    if (ok) for (int i = 0; i < 28; ++i) if (in_sizes[i] != exp_sizes[i]) ok = false;
    if (!ok) { sentinel_kernel<<<1, 64, 0, stream>>>(out, -5.0f); return; }

    const size_t RSZ = (size_t)NN * 64 * 2;            // 33.55 MB per region
    const size_t BIG_OFF = 8192 + 90112;               // control (8KB) + bf16 weight arena
    if (ws_size < BIG_OFF + 4 * RSZ) {
        sentinel_kernel<<<1, 64, 0, stream>>>(out, -7.0f);
        return;
    }

    const float* x     = (const float*)d_in[0];
    const int*   ei    = (const int*)d_in[1];
    const float* np1w  = (const float*)d_in[2];
    const float* np1b  = (const float*)d_in[3];
    const float* np2w  = (const float*)d_in[4];
    const float* np3w  = (const float*)d_in[5];
    const float* c0m1b = (const float*)d_in[7];
    const float* c0m2b = (const float*)d_in[9];
    const float* c0m4b = (const float*)d_in[11];
    const float* cm1b  = (const float*)d_in[13];
    const float* cm2b  = (const float*)d_in[15];
    const float* cm4b  = (const float*)d_in[17];
    const float* bng   = (const float*)d_in[18];
    const float* bnb   = (const float*)d_in[19];
    const float* fe1w  = (const float*)d_in[20];
    const float* fe1b  = (const float*)d_in[21];
    const float* fe2w  = (const float*)d_in[22];
    const float* fe3w  = (const float*)d_in[23];
    const float* acw   = (const float*)d_in[24];
    const float* acb   = (const float*)d_in[25];
    const float* flw   = (const float*)d_in[26];
    const float* flb   = (const float*)d_in[27];

    char* ws = (char*)d_ws;
    float* small = (float*)ws;
    float* tt    = small;          // [4][128]: per-layer trace(64)|total(64)
    float* scl   = small + 512;
    float* shf   = small + 576;
    float* oaccp = small + 640;    // [4][64] extractor partials

    u16* arena = (u16*)(ws + 8192);          // bf16 conv weights, 43008 elements

    char* big = ws + BIG_OFF;
    u16* S0 = (u16*)(big + 0 * RSZ);
    u16* S1 = (u16*)(big + 1 * RSZ);
    u16* S2 = (u16*)(big + 2 * RSZ);
    u16* S3 = (u16*)(big + 3 * RSZ);
    float* Abuf = (float*)S2;                // fp32 staging, dead after finalize_u0

    // BN partial buffers live in S2 (o2 slot) — dead between bmm and next conv12.
    float* psum = (float*)S2;                          // 64*2048
    float* psq  = psum + 64 * 2048;                    // 64*2048
    float* ptr  = psq + 64 * 2048;                     // 64*512

    hipMemsetAsync(small, 0, 4096, stream);
    hipMemsetAsync(Abuf, 0, (size_t)NN * 32 * 4, stream);

    cvt_weights<<<168, 256, 0, stream>>>((const float*)d_in[6], (const float*)d_in[8],
                                         (const float*)d_in[10], (const float*)d_in[12],
                                         (const float*)d_in[14], (const float*)d_in[16], arena);
    scatter_edges<<<2048, 256, 0, stream>>>(x, ei, Abuf);
    finalize_u0<<<1024, 256, 0, stream>>>(Abuf, S0, tt + 64);        // total -> tt[0][64..]
    trace_raw_cm<<<32, 256, 0, stream>>>(S0, tt);                    // trace -> tt[0][0..31]

    u16* U[3]  = { S0, S1, S0 };
    u16* O1[3] = { S1, S0, S1 };
    u16* R[3]  = { S1, S0, S1 };

    const float *aff_s = nullptr, *aff_h = nullptr;

    for (int l = 0; l < 3; ++l) {
        int Cin = (l == 0) ? 32 : 64;
        const u16 *w1b, *w2b, *w4b;
        const float *b1, *b2, *b4;
        if (l == 0) {
            w1b = arena;            b1 = c0m1b;
            w2b = arena + 2048;     b2 = c0m2b;
            w4b = arena + 4096;     b4 = c0m4b;
        } else {
            int m = l - 1;
            w1b = arena + 10240 + m * 4096;  b1 = cm1b + m * 64;
            w2b = arena + 18432 + m * 4096;  b2 = cm2b + m * 64;
            w4b = arena + 26624 + m * 8192;  b4 = cm4b + m * 64;
        }
        if (Cin == 32)
            conv12_t<1><<<2048, 256, 0, stream>>>(U[l], aff_s, aff_h, w1b, b1, w2b, b2, O1[l], S2);
        else
            conv12_t<2><<<2048, 256, 0, stream>>>(U[l], aff_s, aff_h, w1b, b1, w2b, b2, O1[l], S2);
        bmm_mfma<<<dim3(16, 64), 256, 0, stream>>>(O1[l], S2, S3);
        if (Cin == 32)
            conv4_t<3><<<2048, 256, 0, stream>>>(S3, U[l], aff_s, aff_h, w4b, b4, R[l], psum, psq, ptr);
        else
            conv4_t<4><<<2048, 256, 0, stream>>>(S3, U[l], aff_s, aff_h, w4b, b4, R[l], psum, psq, ptr);
        bn_finalize<<<64, 256, 0, stream>>>(psum, psq, ptr, bng + l * 64, bnb + l * 64,
                                            scl, shf, tt + (l + 1) * 128);
        aff_s = scl; aff_h = shf;
    }
    extractor_par<<<4, 256, 0, stream>>>(tt, np1w, np1b, np2w, np3w,
                                         fe1w, fe1b, fe2w, fe3w, oaccp);
    head_par<<<1, 256, 0, stream>>>(oaccp, acw, acb, flw, flb, out);
}